// Round 3
// baseline (1798.320 us; speedup 1.0000x reference)
//
#include <hip/hip_runtime.h>
#include <hip/hip_fp16.h>
#include <math.h>

#define BB 2
#define SS 4096
#define DD 1024
#define HH 8
#define DH 128
#define RR 2
#define CC 64
#define NBUCK 128
#define LL 2
#define FFD 4096
#define VV 258
#define VP 384            // padded vocab for head GEMM (multiple of 128)
#define RS (RR*SS)        // 8192
#define NC (RS/CC)        // 128
#define BH (BB*HH)        // 16
#define MROWS (BB*SS)     // 8192

// scale 2^8 on both operand splits; descale 2^-16 in epilogue (fp16 denorm guard)
#define SCF 256.0f
#define DSCF (1.0f/65536.0f)

typedef __attribute__((ext_vector_type(8))) _Float16 v8h;
typedef __attribute__((ext_vector_type(4))) _Float16 v4h;
typedef __attribute__((ext_vector_type(4))) float v4f;

// ---------------------------------------------------------------------------
__device__ __forceinline__ void gld16(const void* g, void* l) {
  __builtin_amdgcn_global_load_lds((const __attribute__((address_space(1))) void*)g,
                                   (__attribute__((address_space(3))) void*)l, 16, 0, 0);
}

// ---------------------------------------------------------------------------
__device__ __forceinline__ void block_sum2(float& s, float& s2) {
  #pragma unroll
  for (int o = 1; o < 64; o <<= 1) { s += __shfl_xor(s, o); s2 += __shfl_xor(s2, o); }
  __shared__ float rs[4], rq[4];
  int wave = threadIdx.x >> 6;
  if ((threadIdx.x & 63) == 0) { rs[wave] = s; rq[wave] = s2; }
  __syncthreads();
  s  = rs[0] + rs[1] + rs[2] + rs[3];
  s2 = rq[0] + rq[1] + rq[2] + rq[3];
}

// ---------------------------------------------------------------------------
__global__ __launch_bounds__(256) void init_x_kernel(const float* __restrict__ x,
                                                     float* __restrict__ x1,
                                                     float* __restrict__ x2) {
  size_t i = (size_t)blockIdx.x * 256 + threadIdx.x;
  float v = x[i];
  x1[i] = v; x2[i] = v;
}

// ---------------------------------------------------------------------------
// LayerNorm over D=1024 -> scaled fp16 2-plane split (plane stride MROWS*DD)
__global__ __launch_bounds__(256) void ln_split_kernel(const float* __restrict__ x,
                                                       const float* __restrict__ g,
                                                       const float* __restrict__ bta,
                                                       _Float16* __restrict__ out) {
  int row = blockIdx.x;
  int t = threadIdx.x;
  float4 xv = ((const float4*)(x + (size_t)row * DD))[t];
  float s  = xv.x + xv.y + xv.z + xv.w;
  float s2 = xv.x*xv.x + xv.y*xv.y + xv.z*xv.z + xv.w*xv.w;
  block_sum2(s, s2);
  float mu   = s * (1.0f / DD);
  float var  = fmaxf(s2 * (1.0f / DD) - mu * mu, 0.0f);
  float rstd = rsqrtf(var + 1e-12f);
  float4 gv = ((const float4*)g)[t];
  float4 bv = ((const float4*)bta)[t];
  float4 sv;
  sv.x = ((xv.x - mu) * rstd * gv.x + bv.x) * SCF;
  sv.y = ((xv.y - mu) * rstd * gv.y + bv.y) * SCF;
  sv.z = ((xv.z - mu) * rstd * gv.z + bv.z) * SCF;
  sv.w = ((xv.w - mu) * rstd * gv.w + bv.w) * SCF;
  v4h h0, h1;
  h0[0]=(_Float16)sv.x; h0[1]=(_Float16)sv.y; h0[2]=(_Float16)sv.z; h0[3]=(_Float16)sv.w;
  h1[0]=(_Float16)(sv.x-(float)h0[0]); h1[1]=(_Float16)(sv.y-(float)h0[1]);
  h1[2]=(_Float16)(sv.z-(float)h0[2]); h1[3]=(_Float16)(sv.w-(float)h0[3]);
  const size_t PLN = (size_t)MROWS * DD;
  size_t base = (size_t)row * DD + t * 4;
  *(v4h*)(out + base) = h0;
  *(v4h*)(out + PLN + base) = h1;
}

// LayerNorm over concat([x1,x2]) (2048) -> scaled fp16 2-plane split
__global__ __launch_bounds__(256) void ln_concat_split_kernel(const float* __restrict__ x1,
                                                              const float* __restrict__ x2,
                                                              const float* __restrict__ g,
                                                              const float* __restrict__ bta,
                                                              _Float16* __restrict__ out) {
  int row = blockIdx.x;
  int t = threadIdx.x;
  float4 a = ((const float4*)(x1 + (size_t)row * DD))[t];
  float4 b = ((const float4*)(x2 + (size_t)row * DD))[t];
  float s  = a.x + a.y + a.z + a.w + b.x + b.y + b.z + b.w;
  float s2 = a.x*a.x + a.y*a.y + a.z*a.z + a.w*a.w
           + b.x*b.x + b.y*b.y + b.z*b.z + b.w*b.w;
  block_sum2(s, s2);
  float mu   = s * (1.0f / (2*DD));
  float var  = fmaxf(s2 * (1.0f / (2*DD)) - mu * mu, 0.0f);
  float rstd = rsqrtf(var + 1e-12f);
  float4 g1 = ((const float4*)g)[t];
  float4 b1v = ((const float4*)bta)[t];
  float4 g2 = ((const float4*)g)[256 + t];
  float4 b2v = ((const float4*)bta)[256 + t];
  const size_t PLN = (size_t)MROWS * (2*DD);
  float4 s1, s2v;
  s1.x = ((a.x-mu)*rstd*g1.x + b1v.x)*SCF;  s1.y = ((a.y-mu)*rstd*g1.y + b1v.y)*SCF;
  s1.z = ((a.z-mu)*rstd*g1.z + b1v.z)*SCF;  s1.w = ((a.w-mu)*rstd*g1.w + b1v.w)*SCF;
  s2v.x = ((b.x-mu)*rstd*g2.x + b2v.x)*SCF; s2v.y = ((b.y-mu)*rstd*g2.y + b2v.y)*SCF;
  s2v.z = ((b.z-mu)*rstd*g2.z + b2v.z)*SCF; s2v.w = ((b.w-mu)*rstd*g2.w + b2v.w)*SCF;
  v4h h0, h1;
  size_t base = (size_t)row * (2*DD) + t * 4;
  h0[0]=(_Float16)s1.x; h0[1]=(_Float16)s1.y; h0[2]=(_Float16)s1.z; h0[3]=(_Float16)s1.w;
  h1[0]=(_Float16)(s1.x-(float)h0[0]); h1[1]=(_Float16)(s1.y-(float)h0[1]);
  h1[2]=(_Float16)(s1.z-(float)h0[2]); h1[3]=(_Float16)(s1.w-(float)h0[3]);
  *(v4h*)(out + base) = h0;
  *(v4h*)(out + PLN + base) = h1;
  h0[0]=(_Float16)s2v.x; h0[1]=(_Float16)s2v.y; h0[2]=(_Float16)s2v.z; h0[3]=(_Float16)s2v.w;
  h1[0]=(_Float16)(s2v.x-(float)h0[0]); h1[1]=(_Float16)(s2v.y-(float)h0[1]);
  h1[2]=(_Float16)(s2v.z-(float)h0[2]); h1[3]=(_Float16)(s2v.w-(float)h0[3]);
  *(v4h*)(out + base + DD) = h0;
  *(v4h*)(out + PLN + base + DD) = h1;
}

// ---------------------------------------------------------------------------
// weight convert fp32 W[K][·] (row stride ldw) cols [0,N) -> scaled fp16
// 2-plane split Wt[2][Npad][K] (zero pad n>=N)
__global__ __launch_bounds__(256) void wconv_kernel(const float* __restrict__ W,
                                                    _Float16* __restrict__ Wt,
                                                    int K, int N, int Npad, int ldw) {
  __shared__ float tile[32][33];
  int n0 = blockIdx.x * 32, k0 = blockIdx.y * 32;
  int tid = threadIdx.x;
  #pragma unroll
  for (int i = 0; i < 4; i++) {
    int idx = i*256 + tid;
    int kk = idx >> 5, nn = idx & 31;
    float v = 0.0f;
    if (n0 + nn < N) v = W[(size_t)(k0 + kk) * ldw + n0 + nn];
    tile[kk][nn] = v;
  }
  __syncthreads();
  size_t NKs = (size_t)Npad * K;
  #pragma unroll
  for (int i = 0; i < 4; i++) {
    int idx = i*256 + tid;
    int nn = idx >> 5, kk = idx & 31;
    float s = tile[kk][nn] * SCF;
    size_t off = (size_t)(n0 + nn) * K + k0 + kk;
    _Float16 h0 = (_Float16)s;
    _Float16 h1 = (_Float16)(s - (float)h0);
    Wt[off] = h0;
    Wt[NKs + off] = h1;
  }
}

// ---------------------------------------------------------------------------
// fp16x2 MFMA GEMM (R6-verified). PL=2: split (fp32-equivalent); PL=1: single.
// NP: number of cross products when PL=2. NP=4 full QUAD (a0b0+a0b1+a1b0+a1b1)
// for bit-robust discrete consumers (bucket argmax via Wqk). NP=3 drops the
// a1*b1 term (~2^-22 relative) for all continuous-valued GEMMs: -25% MFMA.
// CMODE: 0 store f32, 1 accumulate f32, 2 split-store fp16 2-plane.
// T1 XCD swizzle: bijective chunk remap (all grids divisible by 8) + m-fast
// work decode -> each XCD owns a contiguous n-column; its B-panel stays L2-
// resident and A streams once via L3 instead of per-XCD HBM refetch.
template<int PL, int CMODE, bool BIAS, bool RELU, int NP>
__global__ __launch_bounds__(256) void qgemm_kernel(const _Float16* __restrict__ A,
                                                    const _Float16* __restrict__ Bt,
                                                    const float* __restrict__ bias,
                                                    void* __restrict__ Cv,
                                                    int M, int N, int K,
                                                    size_t aplane, size_t bplane) {
  __shared__ __align__(16) _Float16 As[2*128*32];
  __shared__ __align__(16) _Float16 Bs[2*128*32];
  int tid = threadIdx.x, lane = tid & 63, wave = tid >> 6;
  // --- XCD-aware bijective swizzle (nwg % 8 == 0 for all launches) ---
  int nwg = gridDim.x * gridDim.y;
  int flat = blockIdx.y * gridDim.x + blockIdx.x;
  int w = (flat & 7) * (nwg >> 3) + (flat >> 3);
  int mt = w % gridDim.y;            // m-tile fastest within an XCD chunk
  int nt = w / gridDim.y;
  int m0 = mt * 128, n0 = nt * 128;
  int wm = (wave & 1) * 64, wn = (wave >> 1) * 64;
  int lm = lane & 15, quad = lane >> 4;
  const int NCH = (PL == 2) ? 8 : 4;
  const int ACH = (PL == 2) ? 16 : 8;
  v4f acc[4][4];
  #pragma unroll
  for (int i = 0; i < 4; i++)
    #pragma unroll
    for (int j = 0; j < 4; j++) acc[i][j] = (v4f)0.0f;

  for (int k0 = 0; k0 < K; k0 += 32) {
    #pragma unroll
    for (int i = 0; i < NCH; i++) {
      int c = wave * NCH + i;
      if (c < ACH) {
        int p = c >> 3, q = c & 7;
        int row = q * 16 + (lane >> 2), col = (lane & 3) * 8;
        gld16(A + (size_t)p * aplane + (size_t)(m0 + row) * K + k0 + col,
              (char*)As + (size_t)c * 1024);
      } else {
        int cb = c - ACH;
        int p = cb >> 3, q = cb & 7;
        int row = q * 16 + (lane >> 2), col = (lane & 3) * 8;
        gld16(Bt + (size_t)p * bplane + (size_t)(n0 + row) * K + k0 + col,
              (char*)Bs + (size_t)cb * 1024);
      }
    }
    __syncthreads();
    v8h a[4][2], b[4][2];
    #pragma unroll
    for (int ni = 0; ni < 4; ni++) {
      int boff = (wn + ni*16 + lm) * 32 + quad * 8;
      b[ni][0] = *(const v8h*)&Bs[boff];
      if (PL == 2) b[ni][1] = *(const v8h*)&Bs[4096 + boff];
    }
    #pragma unroll
    for (int mi = 0; mi < 4; mi++) {
      int aoff = (wm + mi*16 + lm) * 32 + quad * 8;
      a[mi][0] = *(const v8h*)&As[aoff];
      if (PL == 2) a[mi][1] = *(const v8h*)&As[4096 + aoff];
    }
    #pragma unroll
    for (int mi = 0; mi < 4; mi++) {
      #pragma unroll
      for (int ni = 0; ni < 4; ni++) {
        v4f c0 = acc[mi][ni];
        c0 = __builtin_amdgcn_mfma_f32_16x16x32_f16(a[mi][0], b[ni][0], c0, 0, 0, 0);
        if (PL == 2) {
          c0 = __builtin_amdgcn_mfma_f32_16x16x32_f16(a[mi][0], b[ni][1], c0, 0, 0, 0);
          c0 = __builtin_amdgcn_mfma_f32_16x16x32_f16(a[mi][1], b[ni][0], c0, 0, 0, 0);
          if (NP == 4)
            c0 = __builtin_amdgcn_mfma_f32_16x16x32_f16(a[mi][1], b[ni][1], c0, 0, 0, 0);
        }
        acc[mi][ni] = c0;
      }
    }
    __syncthreads();
  }

  float* Cf = (float*)Cv;
  _Float16* Ch = (_Float16*)Cv;
  const size_t cplane = (size_t)M * N;
  #pragma unroll
  for (int mi = 0; mi < 4; mi++) {
    int rbase = m0 + wm + mi*16 + quad*4;
    #pragma unroll
    for (int ni = 0; ni < 4; ni++) {
      int col = n0 + wn + ni*16 + lm;
      float bv = BIAS ? bias[col] : 0.0f;
      #pragma unroll
      for (int r = 0; r < 4; r++) {
        float val = acc[mi][ni][r] * DSCF + bv;
        if (RELU) val = fmaxf(val, 0.0f);
        size_t off = (size_t)(rbase + r) * N + col;
        if (CMODE == 0) Cf[off] = val;
        else if (CMODE == 1) Cf[off] += val;
        else {
          float s = val * SCF;
          _Float16 h0 = (_Float16)s;
          _Float16 h1 = (_Float16)(s - (float)h0);
          Ch[off] = h0;
          Ch[cplane + off] = h1;
        }
      }
    }
  }
}

// ---------------------------------------------------------------------------
// rot[h][d][r][n] -> rotT[h][2 planes][rcol=r*64+n][d] scaled fp16 split
__global__ __launch_bounds__(256) void rott_kernel(const float* __restrict__ rot,
                                                   _Float16* __restrict__ rotT) {
  int h = blockIdx.x, grp = blockIdx.y;    // dim3(8,8)
  const float* rh = rot + (size_t)h * (DH * RR * 64);
  for (int idx = threadIdx.x; idx < 16*128; idx += 256) {
    int rc = grp*16 + (idx >> 7), d = idx & 127;
    int r = rc >> 6, nn = rc & 63;
    float f = rh[(size_t)d * 128 + r * 64 + nn] * SCF;
    _Float16 h0 = (_Float16)f;
    rotT[(size_t)h*32768 + (size_t)rc*128 + d] = h0;
    rotT[(size_t)h*32768 + 16384 + (size_t)rc*128 + d] = (_Float16)(f - (float)h0);
  }
}

// ---------------------------------------------------------------------------
// bucket via MFMA: rotated = qk_head @ rotT^T, fused argmax epilogue.
// A: qkb fp32 (in-register QUAD split, R4-verified XOR-swizzle staging).
// Each wave's 64 cols = one full hash round -> per-wave argmax, no combine.
// Kept at full 4-product QUAD: feeds discrete argmax (bucket assignment).
__global__ __launch_bounds__(256) void bucket_mfma_kernel(const float* __restrict__ qkb,
                                                          const _Float16* __restrict__ rotT,
                                                          int* __restrict__ ids) {
  __shared__ __align__(16) float Af[128*32];          // 16 KB XOR-swizzled
  __shared__ __align__(16) _Float16 Bs[2*128*32];     // 16 KB
  int mtile = blockIdx.x, bh = blockIdx.y;
  int b = bh >> 3, h = bh & 7;
  int tid = threadIdx.x, lane = tid & 63, wave = tid >> 6;
  int wm = (wave & 1) * 64;
  int r = wave >> 1;                                   // round handled by this wave
  int wn = r * 64;
  int lm = lane & 15, quad = lane >> 4;
  const float* Aq = qkb + ((size_t)b * SS + (size_t)mtile * 128) * DD + h * DH;
  const _Float16* Bq = rotT + (size_t)h * 32768;
  v4f acc[4][4];
  #pragma unroll
  for (int i = 0; i < 4; i++)
    #pragma unroll
    for (int j = 0; j < 4; j++) acc[i][j] = (v4f)0.0f;

  for (int k0 = 0; k0 < 128; k0 += 32) {
    #pragma unroll
    for (int i = 0; i < 8; i++) {
      int c = wave * 8 + i;
      if (c < 16) {
        int slot = c * 64 + lane;
        int row = slot >> 3;
        int c4 = (slot & 7) ^ (row & 7);
        gld16(Aq + (size_t)row * DD + k0 + c4 * 4, (char*)Af + (size_t)c * 1024);
      } else {
        int cb = c - 16;
        int p = cb >> 3, q = cb & 7;
        int row = q * 16 + (lane >> 2), col = (lane & 3) * 8;
        gld16(Bq + (size_t)p * 16384 + (size_t)row * 128 + k0 + col,
              (char*)Bs + (size_t)p * 8192 + (size_t)q * 1024);
      }
    }
    __syncthreads();
    v8h b0[4], b1[4];
    #pragma unroll
    for (int ni = 0; ni < 4; ni++) {
      int boff = (wn + ni*16 + lm) * 32 + quad * 8;
      b0[ni] = *(const v8h*)&Bs[boff];
      b1[ni] = *(const v8h*)&Bs[4096 + boff];
    }
    #pragma unroll
    for (int mi = 0; mi < 4; mi++) {
      int arow = wm + mi*16 + lm;
      int sw = arow & 7;
      float4 fA = *(const float4*)(Af + arow*32 + (((2*quad)     ^ sw) << 2));
      float4 fB = *(const float4*)(Af + arow*32 + (((2*quad + 1) ^ sw) << 2));
      v8h a0, a1;
      float fs[8] = {fA.x*SCF, fA.y*SCF, fA.z*SCF, fA.w*SCF,
                     fB.x*SCF, fB.y*SCF, fB.z*SCF, fB.w*SCF};
      #pragma unroll
      for (int j = 0; j < 8; j++) {
        _Float16 p0 = (_Float16)fs[j];
        a0[j] = p0;
        a1[j] = (_Float16)(fs[j] - (float)p0);
      }
      #pragma unroll
      for (int ni = 0; ni < 4; ni++) {
        v4f c0 = acc[mi][ni];
        c0 = __builtin_amdgcn_mfma_f32_16x16x32_f16(a0, b0[ni], c0, 0, 0, 0);
        c0 = __builtin_amdgcn_mfma_f32_16x16x32_f16(a0, b1[ni], c0, 0, 0, 0);
        c0 = __builtin_amdgcn_mfma_f32_16x16x32_f16(a1, b0[ni], c0, 0, 0, 0);
        c0 = __builtin_amdgcn_mfma_f32_16x16x32_f16(a1, b1[ni], c0, 0, 0, 0);
        acc[mi][ni] = c0;
      }
    }
    __syncthreads();
  }

  // argmax epilogue (scaled values; comparisons scale-invariant)
  #pragma unroll
  for (int mi = 0; mi < 4; mi++) {
    #pragma unroll
    for (int rr = 0; rr < 4; rr++) {
      float mx = acc[mi][0][rr]; int xi = lm;
      float mn = acc[mi][0][rr]; int ni_ = lm;
      #pragma unroll
      for (int ni = 1; ni < 4; ni++) {
        float vv = acc[mi][ni][rr];
        int col = ni*16 + lm;
        if (vv > mx) { mx = vv; xi = col; }
        if (vv < mn) { mn = vv; ni_ = col; }
      }
      #pragma unroll
      for (int o = 1; o < 16; o <<= 1) {
        float ox = __shfl_xor(mx, o); int oxi = __shfl_xor(xi, o);
        if (ox > mx || (ox == mx && oxi < xi)) { mx = ox; xi = oxi; }
        float on = __shfl_xor(mn, o); int oni = __shfl_xor(ni_, o);
        if (on < mn || (on == mn && oni < ni_)) { mn = on; ni_ = oni; }
      }
      if (lm == 0) {
        int bi = (mx >= -mn) ? xi : 64 + ni_;
        int s = mtile*128 + wm + mi*16 + quad*4 + rr;
        ids[((size_t)bh * RR + r) * SS + s] = bi + r * NBUCK;
      }
    }
  }
}

// ---------------------------------------------------------------------------
// Parallel stable counting sort (R5-verified, bit-exact vs argsort)
__global__ __launch_bounds__(256) void sort_count_kernel(const int* __restrict__ ids,
                                                         int* __restrict__ counts) {
  int w = blockIdx.x * 4 + (threadIdx.x >> 6);
  int lane = threadIdx.x & 63;
  int bhr = w >> 6, seg = w & 63;
  int id = ids[(size_t)bhr * SS + seg * 64 + lane];
  int bin = id & 127;
  unsigned long long eq = ~0ull;
  #pragma unroll
  for (int bit = 0; bit < 7; bit++) {
    unsigned long long bal = __ballot((bin >> bit) & 1);
    eq &= ((bin >> bit) & 1) ? bal : ~bal;
  }
  int rank = __popcll(eq & ((1ull << lane) - 1ull));
  if (rank == 0)
    counts[((size_t)bhr * 64 + seg) * 128 + bin] = __popcll(eq);
}

__global__ __launch_bounds__(128) void sort_prefix_kernel(int* __restrict__ counts) {
  int bhr = blockIdx.x;
  int bin = threadIdx.x;
  int r = bhr & 1;
  int* cp = counts + (size_t)bhr * 64 * 128;
  int total = 0;
  for (int seg = 0; seg < 64; seg++) total += cp[seg * 128 + bin];
  __shared__ int tot[128];
  tot[bin] = total;
  __syncthreads();
  for (int off = 1; off < 128; off <<= 1) {
    int t = (bin >= off) ? tot[bin - off] : 0;
    __syncthreads();
    tot[bin] += t;
    __syncthreads();
  }
  int run = tot[bin] - total + r * SS;
  for (int seg = 0; seg < 64; seg++) {
    int c = cp[seg * 128 + bin];
    cp[seg * 128 + bin] = run;
    run += c;
  }
}

__global__ __launch_bounds__(256) void sort_scatter_kernel(const int* __restrict__ ids,
                                                           const int* __restrict__ offs,
                                                           int* __restrict__ orig,
                                                           int* __restrict__ undo) {
  int w = blockIdx.x * 4 + (threadIdx.x >> 6);
  int lane = threadIdx.x & 63;
  int bhr = w >> 6, seg = w & 63;
  int s = seg * 64 + lane;
  int id = ids[(size_t)bhr * SS + s];
  int bin = id & 127;
  unsigned long long eq = ~0ull;
  #pragma unroll
  for (int bit = 0; bit < 7; bit++) {
    unsigned long long bal = __ballot((bin >> bit) & 1);
    eq &= ((bin >> bit) & 1) ? bal : ~bal;
  }
  int rank = __popcll(eq & ((1ull << lane) - 1ull));
  int o = offs[((size_t)bhr * 64 + seg) * 128 + bin] + rank;
  int bh = bhr >> 1, r = bhr & 1;
  orig[(size_t)bh * RS + o] = s;
  undo[(size_t)bh * RS + r * SS + s] = o;
}

// ---------------------------------------------------------------------------
__global__ __launch_bounds__(256) void rnorm_kernel(const float* __restrict__ qk,
                                                    const int* __restrict__ orig,
                                                    float* __restrict__ rno) {
  int idx = blockIdx.x * 4 + (threadIdx.x >> 6);
  int lane = threadIdx.x & 63;
  int bh = idx >> 13;
  int k = idx & (RS - 1);
  int b = bh >> 3, h = bh & 7;
  int s = orig[(size_t)bh * RS + k];
  const float* row = qk + ((size_t)(b * SS + s)) * DD + h * DH;
  float x0 = row[lane], x1 = row[lane + 64];
  float ss = x0 * x0 + x1 * x1;
  #pragma unroll
  for (int o = 1; o < 64; o <<= 1) ss += __shfl_xor(ss, o);
  if (lane == 0)
    rno[(size_t)bh * RS + k] = rsqrtf(ss * (1.0f / DH) + 1e-6f) * 0.08838834764831845f;
}

// ---------------------------------------------------------------------------
// MFMA chunked attention, T14 async-stage version (raw s_barrier, no vmcnt
// drain at barriers). Q/K/V gathered fp32 -> scaled fp16 PL-plane split.
// PL=2 (layer 0): fp32-equivalent QUAD; PL=1 (layer 1): single product.
// Per phase: [bar] write(cur from regs) + issue loads(next) [lgkm0][bar] MFMA.
// K/V row ids come from kp_lds (staged) -> short issue chains.
// V layout XOR-swizzled: KV[d*36 + (key ^ ((d>>2 &7)<<2))]; reads mirror it
// (4-aligned key blocks preserved) -> store conflicts 16-way -> ~4-way.
template<int PL>
__global__ __launch_bounds__(256) void attn_mfma_kernel(const float* __restrict__ qk,
                                                        const float* __restrict__ v,
                                                        const int* __restrict__ orig,
                                                        const float* __restrict__ rno,
                                                        float* __restrict__ osort,
                                                        float* __restrict__ lg) {
  constexpr int QPs = 64*136, Kps = 32*136, Vps = 128*36;
  constexpr size_t QPB = (size_t)PL * QPs * 2;       // Q/P region bytes
  constexpr size_t KVB = (size_t)PL * Vps * 2;       // K/V region bytes (V is larger)
  __shared__ __align__(16) char smem[QPB + KVB + 1024];
  _Float16* QP = (_Float16*)smem;                     // [PL][64][136]
  _Float16* KV = (_Float16*)(smem + QPB);             // K: [PL][32][136] / V: [PL][128][36]
  int* kp_lds = (int*)(smem + QPB + KVB);
  int* qp_lds = kp_lds + 128;

  int blk = blockIdx.x;
  int n = blk & (NC - 1), bh = blk >> 7;
  int b = bh >> 3, h = bh & 7;
  int pn = (n + NC - 1) & (NC - 1);
  int tid = threadIdx.x, lane = tid & 63, wave = tid >> 6;
  int lm = lane & 15, quad = lane >> 4;
  const int* origp = orig + (size_t)bh * RS;
  const float* rnp = rno + (size_t)bh * RS;
  const size_t base = (size_t)b * SS * DD + (size_t)h * DH;

  // per-thread staging geometry: fixed d4 column, 8-strided rows
  int d4 = tid & 31;
  int row0 = tid >> 5;                                 // 0..7
  // key base (sorted-index space) per group g
  int kb[4] = {pn*64, pn*64 + 32, n*64, n*64 + 32};

  // ---- prologue: issue Q loads + K(0) loads; stage kp/qp ids ----
  float4 qreg[8];
  #pragma unroll
  for (int i = 0; i < 8; i++)
    qreg[i] = *(const float4*)(qk + base + (size_t)origp[n*64 + row0 + i*8]*DD + d4*4);

  float4 kreg[2][4]; float krn[2][4];
  #pragma unroll
  for (int i = 0; i < 4; i++) {
    int key = row0 + i*8;
    krn[0][i] = rnp[kb[0] + key];
    kreg[0][i] = *(const float4*)(qk + base + (size_t)origp[kb[0] + key]*DD + d4*4);
  }

  if (tid < 128) kp_lds[tid] = origp[(tid < 64) ? (pn*64 + tid) : (n*64 + tid - 64)];
  else if (tid < 192) qp_lds[tid - 128] = origp[n*64 + tid - 128];

  // write Q (waits only the Q loads; K0 stays in flight)
  #pragma unroll
  for (int i = 0; i < 8; i++) {
    int q = row0 + i*8;
    float4 f = qreg[i];
    f.x *= SCF; f.y *= SCF; f.z *= SCF; f.w *= SCF;
    v4h h0; h0[0]=(_Float16)f.x; h0[1]=(_Float16)f.y; h0[2]=(_Float16)f.z; h0[3]=(_Float16)f.w;
    *(v4h*)(QP + q*136 + d4*4) = h0;
    if (PL == 2) {
      v4h h1; h1[0]=(_Float16)(f.x-(float)h0[0]); h1[1]=(_Float16)(f.y-(float)h0[1]);
      h1[2]=(_Float16)(f.z-(float)h0[2]); h1[3]=(_Float16)(f.w-(float)h0[3]);
      *(v4h*)(QP + QPs + q*136 + d4*4) = h1;
    }
  }
  asm volatile("s_waitcnt lgkmcnt(0)" ::: "memory");   // publish Q + kp/qp ids

  v4f sc[8];
  #pragma unroll
  for (int j = 0; j < 8; j++) sc[j] = (v4f)0.0f;

  // --- scores: 4 key-groups of 32, software-pipelined ---
  #pragma unroll
  for (int g = 0; g < 4; g++) {
    __builtin_amdgcn_s_barrier();                      // prev readers done / pub
    int cur = g & 1;
    // write K(g) from regs
    #pragma unroll
    for (int i = 0; i < 4; i++) {
      int key = row0 + i*8;
      float rn = krn[cur][i] * SCF;
      float4 f = kreg[cur][i];
      f.x *= rn; f.y *= rn; f.z *= rn; f.w *= rn;
      v4h h0; h0[0]=(_Float16)f.x; h0[1]=(_Float16)f.y; h0[2]=(_Float16)f.z; h0[3]=(_Float16)f.w;
      *(v4h*)(KV + key*136 + d4*4) = h0;
      if (PL == 2) {
        v4h h1; h1[0]=(_Float16)(f.x-(float)h0[0]); h1[1]=(_Float16)(f.y-(float)h0[1]);
        h1[2]=(_Float16)(f.z-(float)h0[2]); h1[3]=(_Float16)(f.w-(float)h0[3]);
        *(v4h*)(KV + Kps + key*136 + d4*4) = h1;
      }
    }
    // issue K(g+1): row ids from LDS (fast), then gathered float4
    if (g < 3) {
      #pragma unroll
      for (int i = 0; i < 4; i++) {
        int key = row0 + i*8;
        int rowid = kp_lds[(g+1)*32 + key];
        krn[cur^1][i] = rnp[kb[g+1] + key];
        kreg[cur^1][i] = *(const float4*)(qk + base + (size_t)rowid*DD + d4*4);
      }
    }
    asm volatile("s_waitcnt lgkmcnt(0)" ::: "memory"); // K(g) writes done
    __builtin_amdgcn_s_barrier();
    __builtin_amdgcn_s_setprio(1);
    #pragma unroll
    for (int ni = 0; ni < 2; ni++) {
      v4f c0 = sc[g*2 + ni];
      #pragma unroll
      for (int ks = 0; ks < 4; ks++) {
        v8h a0 = *(const v8h*)(QP + (wave*16 + lm)*136 + ks*32 + quad*8);
        v8h b0 = *(const v8h*)(KV + (ni*16 + lm)*136 + ks*32 + quad*8);
        c0 = __builtin_amdgcn_mfma_f32_16x16x32_f16(a0, b0, c0, 0, 0, 0);
        if (PL == 2) {
          v8h a1 = *(const v8h*)(QP + QPs + (wave*16 + lm)*136 + ks*32 + quad*8);
          v8h b1 = *(const v8h*)(KV + Kps + (ni*16 + lm)*136 + ks*32 + quad*8);
          c0 = __builtin_amdgcn_mfma_f32_16x16x32_f16(a0, b1, c0, 0, 0, 0);
          c0 = __builtin_amdgcn_mfma_f32_16x16x32_f16(a1, b0, c0, 0, 0, 0);
          c0 = __builtin_amdgcn_mfma_f32_16x16x32_f16(a1, b1, c0, 0, 0, 0);
        }
      }
      sc[g*2 + ni] = c0;
    }
    __builtin_amdgcn_s_setprio(0);
  }

  // issue V(0) loads NOW -- they fly under the softmax
  float4 vreg[2][4];
  #pragma unroll
  for (int i = 0; i < 4; i++) {
    int key = row0 + i*8;
    int rowid = kp_lds[key];                           // group 0 rows
    vreg[0][i] = *(const float4*)(v + base + (size_t)rowid*DD + d4*4);
  }

  __builtin_amdgcn_s_barrier();                        // score reads of QP done

  int kp_l[8];
  #pragma unroll
  for (int j = 0; j < 8; j++) kp_l[j] = kp_lds[j*16 + lm];

  // --- masked softmax per row; write scaled-split probs into QP ---
  #pragma unroll
  for (int rr = 0; rr < 4; rr++) {
    int row = wave*16 + quad*4 + rr;
    int qp = qp_lds[row];
    float sv[8];
    #pragma unroll
    for (int j = 0; j < 8; j++) {
      float s = sc[j][rr] * DSCF;
      int kp = kp_l[j];
      sv[j] = (kp > qp) ? -1000000000.0f : ((kp == qp) ? -100000.0f : s);
    }
    float m = sv[0];
    #pragma unroll
    for (int j = 1; j < 8; j++) m = fmaxf(m, sv[j]);
    #pragma unroll
    for (int o = 1; o < 16; o <<= 1) m = fmaxf(m, __shfl_xor(m, o));
    float es[8], S = 0.0f;
    #pragma unroll
    for (int j = 0; j < 8; j++) { es[j] = __expf(sv[j] - m); S += es[j]; }
    #pragma unroll
    for (int o = 1; o < 16; o <<= 1) S += __shfl_xor(S, o);
    float inv = 1.0f / S;
    if (lm == 0) lg[(size_t)bh * RS + n*64 + row] = m + __logf(S);
    #pragma unroll
    for (int j = 0; j < 8; j++) {
      float p = es[j] * inv * SCF;
      _Float16 p0 = (_Float16)p;
      QP[row*136 + j*16 + lm] = p0;
      if (PL == 2) QP[QPs + row*136 + j*16 + lm] = (_Float16)(p - (float)p0);
    }
  }

  // --- PV: 4 key-groups, V transposed into [d][key^swz] (stride 36) ---
  v4f oacc[8];
  #pragma unroll
  for (int j = 0; j < 8; j++) oacc[j] = (v4f)0.0f;
  #pragma unroll
  for (int g = 0; g < 4; g++) {
    __builtin_amdgcn_s_barrier();                      // prev V readers done
    int cur = g & 1;
    int xbs = (d4 & 7) << 2;
    // write V(g) from regs (swizzled)
    #pragma unroll
    for (int i = 0; i < 4; i++) {
      int keyS = (row0 + i*8) ^ xbs;
      float4 f = vreg[cur][i];
      float fs[4] = {f.x*SCF, f.y*SCF, f.z*SCF, f.w*SCF};
      #pragma unroll
      for (int j = 0; j < 4; j++) {
        int d = d4*4 + j;
        _Float16 p0 = (_Float16)fs[j];
        KV[d*36 + keyS] = p0;
        if (PL == 2) KV[Vps + d*36 + keyS] = (_Float16)(fs[j] - (float)p0);
      }
    }
    // issue V(g+1)
    if (g < 3) {
      #pragma unroll
      for (int i = 0; i < 4; i++) {
        int key = row0 + i*8;
        int rowid = kp_lds[(g+1)*32 + key];
        vreg[cur^1][i] = *(const float4*)(v + base + (size_t)rowid*DD + d4*4);
      }
    }
    asm volatile("s_waitcnt lgkmcnt(0)" ::: "memory"); // V(g) + P writes done
    __builtin_amdgcn_s_barrier();
    __builtin_amdgcn_s_setprio(1);
    v8h a0 = *(const v8h*)(QP + (wave*16 + lm)*136 + g*32 + quad*8);
    v8h a1;
    if (PL == 2) a1 = *(const v8h*)(QP + QPs + (wave*16 + lm)*136 + g*32 + quad*8);
    #pragma unroll
    for (int dn = 0; dn < 8; dn++) {
      int d = dn*16 + lm;
      int klo = (quad*8) ^ (((d >> 2) & 7) << 2);      // 4-aligned block
      v4h lo0 = *(const v4h*)(KV + d*36 + klo);
      v4h hi0 = *(const v4h*)(KV + d*36 + (klo ^ 4));
      v8h b0 = __builtin_shufflevector(lo0, hi0, 0,1,2,3,4,5,6,7);
      v4f c0 = oacc[dn];
      c0 = __builtin_amdgcn_mfma_f32_16x16x32_f16(a0, b0, c0, 0, 0, 0);
      if (PL == 2) {
        v4h lo1 = *(const v4h*)(KV + Vps + d*36 + klo);
        v4h hi1 = *(const v4h*)(KV + Vps + d*36 + (klo ^ 4));
        v8h b1 = __builtin_shufflevector(lo1, hi1, 0,1,2,3,4,5,6,7);
        c0 = __builtin_amdgcn_mfma_f32_16x16x32_f16(a0, b1, c0, 0, 0, 0);
        c0 = __builtin_amdgcn_mfma_f32_16x16x32_f16(a1, b0, c0, 0, 0, 0);
        c0 = __builtin_amdgcn_mfma_f32_16x16x32_f16(a1, b1, c0, 0, 0, 0);
      }
      oacc[dn] = c0;
    }
    __builtin_amdgcn_s_setprio(0);
  }

  // epilogue: O -> osort fp32
  #pragma unroll
  for (int dn = 0; dn < 8; dn++) {
    #pragma unroll
    for (int rr = 0; rr < 4; rr++) {
      int row = wave*16 + quad*4 + rr;
      osort[((size_t)bh * RS + n*64 + row) * DH + dn*16 + lm] = oacc[dn][rr] * DSCF;
    }
  }
}

// ---------------------------------------------------------------------------
// unsort + round-combine -> scaled fp16 2-plane split in h region
__global__ __launch_bounds__(256) void unsort_split_kernel(const float* __restrict__ osort,
                                                           const float* __restrict__ lg,
                                                           const int* __restrict__ undo,
                                                           _Float16* __restrict__ attn) {
  int gid = blockIdx.x * 4 + (threadIdx.x >> 6);
  int lane = threadIdx.x & 63;
  int bh = gid >> 12;
  int s = gid & (SS - 1);
  int b = bh >> 3, h = bh & 7;
  int k0 = undo[(size_t)bh * RS + s];
  int k1 = undo[(size_t)bh * RS + SS + s];
  float l0 = lg[(size_t)bh * RS + k0], l1 = lg[(size_t)bh * RS + k1];
  float m = fmaxf(l0, l1);
  float e0 = __expf(l0 - m), e1 = __expf(l1 - m);
  float inv = 1.0f / (e0 + e1);
  float w0 = e0 * inv, w1 = e1 * inv;
  const float* r0 = osort + ((size_t)bh * RS + k0) * DH;
  const float* r1 = osort + ((size_t)bh * RS + k1) * DH;
  const size_t PLN = (size_t)MROWS * DD;
  _Float16* outp = attn + ((size_t)(b * SS + s)) * DD + h * DH;
  float sA = (w0 * r0[lane]      + w1 * r1[lane])      * SCF;
  float sB = (w0 * r0[lane + 64] + w1 * r1[lane + 64]) * SCF;
  _Float16 a0 = (_Float16)sA, b0 = (_Float16)sB;
  outp[lane] = a0;                 outp[lane + 64] = b0;
  outp[PLN + lane] = (_Float16)(sA - (float)a0);
  outp[PLN + lane + 64] = (_Float16)(sB - (float)b0);
}

// ---------------------------------------------------------------------------
__global__ __launch_bounds__(256) void softmax_b_kernel(const float* __restrict__ logits,
                                                        const float* __restrict__ bout,
                                                        float* __restrict__ out) {
  int i = blockIdx.x * 256 + threadIdx.x;
  if (i >= SS * VV) return;
  int s = i / VV, vv = i - s * VV;
  float bvv = bout[vv];
  float l0 = logits[(size_t)s * VP + vv] + bvv;
  float l1 = logits[(size_t)(SS + s) * VP + vv] + bvv;
  float m = fmaxf(l0, l1);
  float e0 = __expf(l0 - m), e1 = __expf(l1 - m);
  float inv = 1.0f / (e0 + e1);
  out[(size_t)s * VV + vv] = e0 * inv;
  out[(size_t)(SS + s) * VV + vv] = e1 * inv;
}

// ---------------------------------------------------------------------------
// Workspace: extent 237,502,464 B (proven). pool[2NX..4NX) = osort region,
// time-shared: weights wt at +0, counts at +8MB, rotT at +10MB — all dead
// before attn writes osort and before FFN reuses [0,16MB).
extern "C" void kernel_launch(void* const* d_in, const int* in_sizes, int n_in,
                              void* d_out, int out_size, void* d_ws, size_t ws_size,
                              hipStream_t stream) {
  (void)in_sizes; (void)n_in; (void)out_size; (void)ws_size;
  const float* x     = (const float*)d_in[0];
  const float* ln1_g = (const float*)d_in[1];
  const float* ln1_b = (const float*)d_in[2];
  const float* Wqk   = (const float*)d_in[3];
  const float* Wv    = (const float*)d_in[4];
  const float* Wo    = (const float*)d_in[5];
  const float* rot   = (const float*)d_in[6];
  const float* ln2_g = (const float*)d_in[7];
  const float* ln2_b = (const float*)d_in[8];
  const float* W1    = (const float*)d_in[9];
  const float* b1    = (const float*)d_in[10];
  const float* W2    = (const float*)d_in[11];
  const float* b2    = (const float*)d_in[12];
  const float* lnf_g = (const float*)d_in[13];
  const float* lnf_b = (const float*)d_in[14];
  const float* Wout  = (const float*)d_in[15];
  const float* bout  = (const float*)d_in[16];

  const size_t NX = (size_t)MROWS * DD;            // 8,388,608
  float* x1 = (float*)d_ws;
  float* x2 = x1 + NX;
  float* h  = x2 + NX;
  _Float16* hs = (_Float16*)h;                     // [2][M][1024] fp16
  float* pool = h + NX;
  float* qkb   = pool;
  float* vb    = pool + NX;
  float* osort = pool + 2*NX;
  _Float16* ffh = (_Float16*)pool;                 // [2][M][2048] fp16
  _Float16* hcs = (_Float16*)pool;                 // head phase
  char* wbase = (char*)(pool + 2*NX);
  _Float16* wt = (_Float16*)wbase;                 // weight squat region
  int* counts = (int*)(wbase + (8u<<20));          // 1 MB
  _Float16* rotTs = (_Float16*)(wbase + (10u<<20));// 512 KB
  float* after = pool + 4*NX;
  float* lgb = after;
  float* rno = lgb + (size_t)BH * RS;
  int* orig = (int*)(rno + (size_t)BH * RS);
  int* undo = orig + (size_t)BH * RS;
  int* ids  = undo + (size_t)BH * RS;
  float* logitsP = h;                              // head phase

  const size_t AP_D  = NX;
  const size_t AP_FF = (size_t)MROWS * 2048;
  const size_t BP_D  = (size_t)DD * DD;
  const size_t BP_W1 = (size_t)2048 * DD;
  const size_t BP_W2 = (size_t)DD * 2048;
  const size_t BP_HD = (size_t)VP * 2048;

  init_x_kernel<<<(int)(NX / 256), 256, 0, stream>>>(x, x1, x2);

  for (int l = 0; l < LL; l++) {
    // --- attention ---
    ln_split_kernel<<<MROWS, 256, 0, stream>>>(x2, ln1_g + l*DD, ln1_b + l*DD, hs);

    wconv_kernel<<<dim3(32, 32), 256, 0, stream>>>(Wqk + (size_t)l*DD*DD, wt, DD, DD, DD, DD);
    qgemm_kernel<2,0,false,false,4><<<dim3(8, 64), 256, 0, stream>>>(
        hs, wt, nullptr, qkb, MROWS, DD, DD, AP_D, BP_D);

    wconv_kernel<<<dim3(32, 32), 256, 0, stream>>>(Wv + (size_t)l*DD*DD, wt, DD, DD, DD, DD);
    if (l == 0)
      qgemm_kernel<2,0,false,false,3><<<dim3(8, 64), 256, 0, stream>>>(
          hs, wt, nullptr, vb, MROWS, DD, DD, AP_D, BP_D);
    else
      qgemm_kernel<1,0,false,false,3><<<dim3(8, 64), 256, 0, stream>>>(
          hs, wt, nullptr, vb, MROWS, DD, DD, AP_D, BP_D);

    rott_kernel<<<dim3(8, 8), 256, 0, stream>>>(rot + (size_t)l*HH*DH*RR*64, rotTs);
    bucket_mfma_kernel<<<dim3(32, 16), 256, 0, stream>>>(qkb, rotTs, ids);

    hipMemsetAsync(counts, 0, (size_t)BH * RR * 64 * 128 * sizeof(int), stream);
    sort_count_kernel<<<512, 256, 0, stream>>>(ids, counts);
    sort_prefix_kernel<<<BH*RR, 128, 0, stream>>>(counts);
    sort_scatter_kernel<<<512, 256, 0, stream>>>(ids, counts, orig, undo);

    rnorm_kernel<<<BH*RS/4, 256, 0, stream>>>(qkb, orig, rno);
    if (l == 0)
      attn_mfma_kernel<2><<<BH*NC, 256, 0, stream>>>(qkb, vb, orig, rno, osort, lgb);
    else
      attn_mfma_kernel<1><<<BH*NC, 256, 0, stream>>>(qkb, vb, orig, rno, osort, lgb);
    unsort_split_kernel<<<BH*SS/4, 256, 0, stream>>>(osort, lgb, undo, hs);   // osort dead

    wconv_kernel<<<dim3(32, 32), 256, 0, stream>>>(Wo + (size_t)l*DD*DD, wt, DD, DD, DD, DD);
    if (l == 0)
      qgemm_kernel<2,1,false,false,3><<<dim3(8, 64), 256, 0, stream>>>(
          hs, wt, nullptr, x1, MROWS, DD, DD, AP_D, BP_D);
    else
      qgemm_kernel<1,1,false,false,3><<<dim3(8, 64), 256, 0, stream>>>(
          hs, wt, nullptr, x1, MROWS, DD, DD, AP_D, BP_D);

    // --- FFN, two FF-halves of 2048 ---
    ln_split_kernel<<<MROWS, 256, 0, stream>>>(x1, ln2_g + l*DD, ln2_b + l*DD, hs);
    for (int hf = 0; hf < 2; hf++) {
      const float* W1h = W1 + (size_t)l*DD*FFD + (size_t)hf*2048;
      const float* W2h = W2 + (size_t)l*FFD*DD + (size_t)hf*2048*DD;
      _Float16* wt1 = wt;
      _Float16* wt2 = wt + 2u*2097152u;
      wconv_kernel<<<dim3(64, 32), 256, 0, stream>>>(W1h, wt1, DD, 2048, 2048, FFD);
      wconv_kernel<<<dim3(32, 64), 256, 0, stream>>>(W2h, wt2, 2048, DD, DD, DD);
      if (l == 0) {
        qgemm_kernel<2,2,true,true,3><<<dim3(16, 64), 256, 0, stream>>>(
            hs, wt1, b1 + (size_t)l*FFD + hf*2048, ffh, MROWS, 2048, DD, AP_D, BP_W1);
        if (hf == 0)
          qgemm_kernel<2,1,true,false,3><<<dim3(8, 64), 256, 0, stream>>>(
              ffh, wt2, b2 + (size_t)l*DD, x2, MROWS, DD, 2048, AP_FF, BP_W2);
        else
          qgemm_kernel<2,1,false,false,3><<<dim3(8, 64), 256, 0, stream>>>(
              ffh, wt2, nullptr, x2, MROWS, DD, 2048, AP_FF, BP_W2);
      } else {
        qgemm_kernel<1,2,true,true,3><<<dim3(16, 64), 256, 0, stream>>>(
            hs, wt1, b1 + (size_t)l*FFD + hf*2048, ffh, MROWS, 2048, DD, AP_D, BP_W1);
        if (hf == 0)
          qgemm_kernel<1,1,true,false,3><<<dim3(8, 64), 256, 0, stream>>>(
              ffh, wt2, b2 + (size_t)l*DD, x2, MROWS, DD, 2048, AP_FF, BP_W2);
        else
          qgemm_kernel<1,1,false,false,3><<<dim3(8, 64), 256, 0, stream>>>(
              ffh, wt2, nullptr, x2, MROWS, DD, 2048, AP_FF, BP_W2);
      }
    }
  }

  // --- head ---
  ln_concat_split_kernel<<<MROWS, 256, 0, stream>>>(x1, x2, lnf_g, lnf_b, hcs);
  wconv_kernel<<<dim3(12, 64), 256, 0, stream>>>(Wout, wt, 2*DD, VV, VP, VV);
  qgemm_kernel<1,0,false,false,3><<<dim3(3, 64), 256, 0, stream>>>(
      hcs, wt, nullptr, logitsP, MROWS, VP, 2*DD, AP_FF, BP_HD);
  softmax_b_kernel<<<(SS*VV + 255)/256, 256, 0, stream>>>(logitsP, bout, (float*)d_out);
}

// Round 4
// 1751.356 us; speedup vs baseline: 1.0268x; 1.0268x over previous
//
#include <hip/hip_runtime.h>
#include <hip/hip_fp16.h>
#include <math.h>

#define BB 2
#define SS 4096
#define DD 1024
#define HH 8
#define DH 128
#define RR 2
#define CC 64
#define NBUCK 128
#define LL 2
#define FFD 4096
#define VV 258
#define VP 384            // padded vocab for head GEMM (multiple of 128)
#define RS (RR*SS)        // 8192
#define NC (RS/CC)        // 128
#define BH (BB*HH)        // 16
#define MROWS (BB*SS)     // 8192

// scale 2^8 on both operand splits; descale 2^-16 in epilogue (fp16 denorm guard)
#define SCF 256.0f
#define DSCF (1.0f/65536.0f)

typedef __attribute__((ext_vector_type(8))) _Float16 v8h;
typedef __attribute__((ext_vector_type(4))) _Float16 v4h;
typedef __attribute__((ext_vector_type(4))) float v4f;

// ---------------------------------------------------------------------------
__device__ __forceinline__ void gld16(const void* g, void* l) {
  __builtin_amdgcn_global_load_lds((const __attribute__((address_space(1))) void*)g,
                                   (__attribute__((address_space(3))) void*)l, 16, 0, 0);
}

// ---------------------------------------------------------------------------
__device__ __forceinline__ void block_sum2(float& s, float& s2) {
  #pragma unroll
  for (int o = 1; o < 64; o <<= 1) { s += __shfl_xor(s, o); s2 += __shfl_xor(s2, o); }
  __shared__ float rs[4], rq[4];
  int wave = threadIdx.x >> 6;
  if ((threadIdx.x & 63) == 0) { rs[wave] = s; rq[wave] = s2; }
  __syncthreads();
  s  = rs[0] + rs[1] + rs[2] + rs[3];
  s2 = rq[0] + rq[1] + rq[2] + rq[3];
}

// ---------------------------------------------------------------------------
__global__ __launch_bounds__(256) void init_x_kernel(const float* __restrict__ x,
                                                     float* __restrict__ x1,
                                                     float* __restrict__ x2) {
  size_t i = (size_t)blockIdx.x * 256 + threadIdx.x;
  float v = x[i];
  x1[i] = v; x2[i] = v;
}

// ---------------------------------------------------------------------------
// LayerNorm over D=1024 -> scaled fp16 2-plane split (plane stride MROWS*DD)
__global__ __launch_bounds__(256) void ln_split_kernel(const float* __restrict__ x,
                                                       const float* __restrict__ g,
                                                       const float* __restrict__ bta,
                                                       _Float16* __restrict__ out) {
  int row = blockIdx.x;
  int t = threadIdx.x;
  float4 xv = ((const float4*)(x + (size_t)row * DD))[t];
  float s  = xv.x + xv.y + xv.z + xv.w;
  float s2 = xv.x*xv.x + xv.y*xv.y + xv.z*xv.z + xv.w*xv.w;
  block_sum2(s, s2);
  float mu   = s * (1.0f / DD);
  float var  = fmaxf(s2 * (1.0f / DD) - mu * mu, 0.0f);
  float rstd = rsqrtf(var + 1e-12f);
  float4 gv = ((const float4*)g)[t];
  float4 bv = ((const float4*)bta)[t];
  float4 sv;
  sv.x = ((xv.x - mu) * rstd * gv.x + bv.x) * SCF;
  sv.y = ((xv.y - mu) * rstd * gv.y + bv.y) * SCF;
  sv.z = ((xv.z - mu) * rstd * gv.z + bv.z) * SCF;
  sv.w = ((xv.w - mu) * rstd * gv.w + bv.w) * SCF;
  v4h h0, h1;
  h0[0]=(_Float16)sv.x; h0[1]=(_Float16)sv.y; h0[2]=(_Float16)sv.z; h0[3]=(_Float16)sv.w;
  h1[0]=(_Float16)(sv.x-(float)h0[0]); h1[1]=(_Float16)(sv.y-(float)h0[1]);
  h1[2]=(_Float16)(sv.z-(float)h0[2]); h1[3]=(_Float16)(sv.w-(float)h0[3]);
  const size_t PLN = (size_t)MROWS * DD;
  size_t base = (size_t)row * DD + t * 4;
  *(v4h*)(out + base) = h0;
  *(v4h*)(out + PLN + base) = h1;
}

// LayerNorm over concat([x1,x2]) (2048) -> scaled fp16 single plane
// (head GEMM is PL=1: plane-1 stores were dead, dropped)
__global__ __launch_bounds__(256) void ln_concat_split_kernel(const float* __restrict__ x1,
                                                              const float* __restrict__ x2,
                                                              const float* __restrict__ g,
                                                              const float* __restrict__ bta,
                                                              _Float16* __restrict__ out) {
  int row = blockIdx.x;
  int t = threadIdx.x;
  float4 a = ((const float4*)(x1 + (size_t)row * DD))[t];
  float4 b = ((const float4*)(x2 + (size_t)row * DD))[t];
  float s  = a.x + a.y + a.z + a.w + b.x + b.y + b.z + b.w;
  float s2 = a.x*a.x + a.y*a.y + a.z*a.z + a.w*a.w
           + b.x*b.x + b.y*b.y + b.z*b.z + b.w*b.w;
  block_sum2(s, s2);
  float mu   = s * (1.0f / (2*DD));
  float var  = fmaxf(s2 * (1.0f / (2*DD)) - mu * mu, 0.0f);
  float rstd = rsqrtf(var + 1e-12f);
  float4 g1 = ((const float4*)g)[t];
  float4 b1v = ((const float4*)bta)[t];
  float4 g2 = ((const float4*)g)[256 + t];
  float4 b2v = ((const float4*)bta)[256 + t];
  float4 s1, s2v;
  s1.x = ((a.x-mu)*rstd*g1.x + b1v.x)*SCF;  s1.y = ((a.y-mu)*rstd*g1.y + b1v.y)*SCF;
  s1.z = ((a.z-mu)*rstd*g1.z + b1v.z)*SCF;  s1.w = ((a.w-mu)*rstd*g1.w + b1v.w)*SCF;
  s2v.x = ((b.x-mu)*rstd*g2.x + b2v.x)*SCF; s2v.y = ((b.y-mu)*rstd*g2.y + b2v.y)*SCF;
  s2v.z = ((b.z-mu)*rstd*g2.z + b2v.z)*SCF; s2v.w = ((b.w-mu)*rstd*g2.w + b2v.w)*SCF;
  v4h h0;
  size_t base = (size_t)row * (2*DD) + t * 4;
  h0[0]=(_Float16)s1.x; h0[1]=(_Float16)s1.y; h0[2]=(_Float16)s1.z; h0[3]=(_Float16)s1.w;
  *(v4h*)(out + base) = h0;
  h0[0]=(_Float16)s2v.x; h0[1]=(_Float16)s2v.y; h0[2]=(_Float16)s2v.z; h0[3]=(_Float16)s2v.w;
  *(v4h*)(out + base + DD) = h0;
}

// ---------------------------------------------------------------------------
// weight convert fp32 W[K][·] (row stride ldw) cols [0,N) -> scaled fp16
// 2-plane split Wt[2][Npad][K] (zero pad n>=N)
__global__ __launch_bounds__(256) void wconv_kernel(const float* __restrict__ W,
                                                    _Float16* __restrict__ Wt,
                                                    int K, int N, int Npad, int ldw) {
  __shared__ float tile[32][33];
  int n0 = blockIdx.x * 32, k0 = blockIdx.y * 32;
  int tid = threadIdx.x;
  #pragma unroll
  for (int i = 0; i < 4; i++) {
    int idx = i*256 + tid;
    int kk = idx >> 5, nn = idx & 31;
    float v = 0.0f;
    if (n0 + nn < N) v = W[(size_t)(k0 + kk) * ldw + n0 + nn];
    tile[kk][nn] = v;
  }
  __syncthreads();
  size_t NKs = (size_t)Npad * K;
  #pragma unroll
  for (int i = 0; i < 4; i++) {
    int idx = i*256 + tid;
    int nn = idx >> 5, kk = idx & 31;
    float s = tile[kk][nn] * SCF;
    size_t off = (size_t)(n0 + nn) * K + k0 + kk;
    _Float16 h0 = (_Float16)s;
    _Float16 h1 = (_Float16)(s - (float)h0);
    Wt[off] = h0;
    Wt[NKs + off] = h1;
  }
}

// ---------------------------------------------------------------------------
// fp16x2 MFMA GEMM, 2-phase async pipeline (T3-minimum). PL=2: split
// (fp32-equivalent); PL=1: single. NP=4 full QUAD for discrete consumers
// (bucket argmax via Wqk); NP=3 drops a1*b1 (~2^-22 rel) elsewhere.
// Double-buffered LDS; per K-step: ds_read frags(cur) -> issue stage(t+1 ->
// cur^1) -> MFMA (register-only, overlaps load flight) -> ONE barrier whose
// compiler vmcnt(0) drain lands after ~48 MFMAs instead of before them.
// Numerics bit-identical to the 2-barrier version (same MFMA order).
// CMODE: 0 store f32, 1 accumulate f32, 2 split-store fp16 2-plane.
template<int PL, int CMODE, bool BIAS, bool RELU, int NP>
__global__ __launch_bounds__(256) void qgemm_kernel(const _Float16* __restrict__ A,
                                                    const _Float16* __restrict__ Bt,
                                                    const float* __restrict__ bias,
                                                    void* __restrict__ Cv,
                                                    int M, int N, int K,
                                                    size_t aplane, size_t bplane) {
  __shared__ __align__(16) _Float16 As[2][PL*128*32];
  __shared__ __align__(16) _Float16 Bs[2][PL*128*32];
  int tid = threadIdx.x, lane = tid & 63, wave = tid >> 6;
  int m0 = blockIdx.y * 128, n0 = blockIdx.x * 128;
  int wm = (wave & 1) * 64, wn = (wave >> 1) * 64;
  int lm = lane & 15, quad = lane >> 4;
  const int NCH = (PL == 2) ? 8 : 4;
  const int ACH = (PL == 2) ? 16 : 8;
  v4f acc[4][4];
  #pragma unroll
  for (int i = 0; i < 4; i++)
    #pragma unroll
    for (int j = 0; j < 4; j++) acc[i][j] = (v4f)0.0f;

  auto stage = [&](int k0, int bufi) {
    #pragma unroll
    for (int i = 0; i < NCH; i++) {
      int c = wave * NCH + i;
      if (c < ACH) {
        int p = c >> 3, q = c & 7;
        int row = q * 16 + (lane >> 2), col = (lane & 3) * 8;
        gld16(A + (size_t)p * aplane + (size_t)(m0 + row) * K + k0 + col,
              (char*)As[bufi] + (size_t)c * 1024);
      } else {
        int cb = c - ACH;
        int p = cb >> 3, q = cb & 7;
        int row = q * 16 + (lane >> 2), col = (lane & 3) * 8;
        gld16(Bt + (size_t)p * bplane + (size_t)(n0 + row) * K + k0 + col,
              (char*)Bs[bufi] + (size_t)cb * 1024);
      }
    }
  };

  const int nsteps = K >> 5;
  stage(0, 0);
  __syncthreads();

  for (int t = 0; t < nsteps; ++t) {
    int cur = t & 1;
    const _Float16* Ab = As[cur];
    const _Float16* Bb = Bs[cur];
    // fragment loads (LDS of cur buffer)
    v8h a[4][2], b[4][2];
    #pragma unroll
    for (int ni = 0; ni < 4; ni++) {
      int boff = (wn + ni*16 + lm) * 32 + quad * 8;
      b[ni][0] = *(const v8h*)&Bb[boff];
      if (PL == 2) b[ni][1] = *(const v8h*)&Bb[4096 + boff];
    }
    #pragma unroll
    for (int mi = 0; mi < 4; mi++) {
      int aoff = (wm + mi*16 + lm) * 32 + quad * 8;
      a[mi][0] = *(const v8h*)&Ab[aoff];
      if (PL == 2) a[mi][1] = *(const v8h*)&Ab[4096 + aoff];
    }
    // issue next tile's staging; loads fly under the MFMAs below
    if (t + 1 < nsteps) stage((t + 1) << 5, cur ^ 1);
    #pragma unroll
    for (int mi = 0; mi < 4; mi++) {
      #pragma unroll
      for (int ni = 0; ni < 4; ni++) {
        v4f c0 = acc[mi][ni];
        c0 = __builtin_amdgcn_mfma_f32_16x16x32_f16(a[mi][0], b[ni][0], c0, 0, 0, 0);
        if (PL == 2) {
          c0 = __builtin_amdgcn_mfma_f32_16x16x32_f16(a[mi][0], b[ni][1], c0, 0, 0, 0);
          c0 = __builtin_amdgcn_mfma_f32_16x16x32_f16(a[mi][1], b[ni][0], c0, 0, 0, 0);
          if (NP == 4)
            c0 = __builtin_amdgcn_mfma_f32_16x16x32_f16(a[mi][1], b[ni][1], c0, 0, 0, 0);
        }
        acc[mi][ni] = c0;
      }
    }
    __syncthreads();
  }

  float* Cf = (float*)Cv;
  _Float16* Ch = (_Float16*)Cv;
  const size_t cplane = (size_t)M * N;
  #pragma unroll
  for (int mi = 0; mi < 4; mi++) {
    int rbase = m0 + wm + mi*16 + quad*4;
    #pragma unroll
    for (int ni = 0; ni < 4; ni++) {
      int col = n0 + wn + ni*16 + lm;
      float bv = BIAS ? bias[col] : 0.0f;
      #pragma unroll
      for (int r = 0; r < 4; r++) {
        float val = acc[mi][ni][r] * DSCF + bv;
        if (RELU) val = fmaxf(val, 0.0f);
        size_t off = (size_t)(rbase + r) * N + col;
        if (CMODE == 0) Cf[off] = val;
        else if (CMODE == 1) Cf[off] += val;
        else {
          float s = val * SCF;
          _Float16 h0 = (_Float16)s;
          _Float16 h1 = (_Float16)(s - (float)h0);
          Ch[off] = h0;
          Ch[cplane + off] = h1;
        }
      }
    }
  }
}

// ---------------------------------------------------------------------------
// rot[h][d][r][n] -> rotT[h][2 planes][rcol=r*64+n][d] scaled fp16 split
__global__ __launch_bounds__(256) void rott_kernel(const float* __restrict__ rot,
                                                   _Float16* __restrict__ rotT) {
  int h = blockIdx.x, grp = blockIdx.y;    // dim3(8,8)
  const float* rh = rot + (size_t)h * (DH * RR * 64);
  for (int idx = threadIdx.x; idx < 16*128; idx += 256) {
    int rc = grp*16 + (idx >> 7), d = idx & 127;
    int r = rc >> 6, nn = rc & 63;
    float f = rh[(size_t)d * 128 + r * 64 + nn] * SCF;
    _Float16 h0 = (_Float16)f;
    rotT[(size_t)h*32768 + (size_t)rc*128 + d] = h0;
    rotT[(size_t)h*32768 + 16384 + (size_t)rc*128 + d] = (_Float16)(f - (float)h0);
  }
}

// ---------------------------------------------------------------------------
// bucket via MFMA: rotated = qk_head @ rotT^T, fused argmax epilogue.
// A: qkb fp32 (in-register QUAD split, R4-verified XOR-swizzle staging).
// Each wave's 64 cols = one full hash round -> per-wave argmax, no combine.
// Kept at full 4-product QUAD: feeds discrete argmax (bucket assignment).
__global__ __launch_bounds__(256) void bucket_mfma_kernel(const float* __restrict__ qkb,
                                                          const _Float16* __restrict__ rotT,
                                                          int* __restrict__ ids) {
  __shared__ __align__(16) float Af[128*32];          // 16 KB XOR-swizzled
  __shared__ __align__(16) _Float16 Bs[2*128*32];     // 16 KB
  int mtile = blockIdx.x, bh = blockIdx.y;
  int b = bh >> 3, h = bh & 7;
  int tid = threadIdx.x, lane = tid & 63, wave = tid >> 6;
  int wm = (wave & 1) * 64;
  int r = wave >> 1;                                   // round handled by this wave
  int wn = r * 64;
  int lm = lane & 15, quad = lane >> 4;
  const float* Aq = qkb + ((size_t)b * SS + (size_t)mtile * 128) * DD + h * DH;
  const _Float16* Bq = rotT + (size_t)h * 32768;
  v4f acc[4][4];
  #pragma unroll
  for (int i = 0; i < 4; i++)
    #pragma unroll
    for (int j = 0; j < 4; j++) acc[i][j] = (v4f)0.0f;

  for (int k0 = 0; k0 < 128; k0 += 32) {
    #pragma unroll
    for (int i = 0; i < 8; i++) {
      int c = wave * 8 + i;
      if (c < 16) {
        int slot = c * 64 + lane;
        int row = slot >> 3;
        int c4 = (slot & 7) ^ (row & 7);
        gld16(Aq + (size_t)row * DD + k0 + c4 * 4, (char*)Af + (size_t)c * 1024);
      } else {
        int cb = c - 16;
        int p = cb >> 3, q = cb & 7;
        int row = q * 16 + (lane >> 2), col = (lane & 3) * 8;
        gld16(Bq + (size_t)p * 16384 + (size_t)row * 128 + k0 + col,
              (char*)Bs + (size_t)p * 8192 + (size_t)q * 1024);
      }
    }
    __syncthreads();
    v8h b0[4], b1[4];
    #pragma unroll
    for (int ni = 0; ni < 4; ni++) {
      int boff = (wn + ni*16 + lm) * 32 + quad * 8;
      b0[ni] = *(const v8h*)&Bs[boff];
      b1[ni] = *(const v8h*)&Bs[4096 + boff];
    }
    #pragma unroll
    for (int mi = 0; mi < 4; mi++) {
      int arow = wm + mi*16 + lm;
      int sw = arow & 7;
      float4 fA = *(const float4*)(Af + arow*32 + (((2*quad)     ^ sw) << 2));
      float4 fB = *(const float4*)(Af + arow*32 + (((2*quad + 1) ^ sw) << 2));
      v8h a0, a1;
      float fs[8] = {fA.x*SCF, fA.y*SCF, fA.z*SCF, fA.w*SCF,
                     fB.x*SCF, fB.y*SCF, fB.z*SCF, fB.w*SCF};
      #pragma unroll
      for (int j = 0; j < 8; j++) {
        _Float16 p0 = (_Float16)fs[j];
        a0[j] = p0;
        a1[j] = (_Float16)(fs[j] - (float)p0);
      }
      #pragma unroll
      for (int ni = 0; ni < 4; ni++) {
        v4f c0 = acc[mi][ni];
        c0 = __builtin_amdgcn_mfma_f32_16x16x32_f16(a0, b0[ni], c0, 0, 0, 0);
        c0 = __builtin_amdgcn_mfma_f32_16x16x32_f16(a0, b1[ni], c0, 0, 0, 0);
        c0 = __builtin_amdgcn_mfma_f32_16x16x32_f16(a1, b0[ni], c0, 0, 0, 0);
        c0 = __builtin_amdgcn_mfma_f32_16x16x32_f16(a1, b1[ni], c0, 0, 0, 0);
        acc[mi][ni] = c0;
      }
    }
    __syncthreads();
  }

  // argmax epilogue (scaled values; comparisons scale-invariant)
  #pragma unroll
  for (int mi = 0; mi < 4; mi++) {
    #pragma unroll
    for (int rr = 0; rr < 4; rr++) {
      float mx = acc[mi][0][rr]; int xi = lm;
      float mn = acc[mi][0][rr]; int ni_ = lm;
      #pragma unroll
      for (int ni = 1; ni < 4; ni++) {
        float vv = acc[mi][ni][rr];
        int col = ni*16 + lm;
        if (vv > mx) { mx = vv; xi = col; }
        if (vv < mn) { mn = vv; ni_ = col; }
      }
      #pragma unroll
      for (int o = 1; o < 16; o <<= 1) {
        float ox = __shfl_xor(mx, o); int oxi = __shfl_xor(xi, o);
        if (ox > mx || (ox == mx && oxi < xi)) { mx = ox; xi = oxi; }
        float on = __shfl_xor(mn, o); int oni = __shfl_xor(ni_, o);
        if (on < mn || (on == mn && oni < ni_)) { mn = on; ni_ = oni; }
      }
      if (lm == 0) {
        int bi = (mx >= -mn) ? xi : 64 + ni_;
        int s = mtile*128 + wm + mi*16 + quad*4 + rr;
        ids[((size_t)bh * RR + r) * SS + s] = bi + r * NBUCK;
      }
    }
  }
}

// ---------------------------------------------------------------------------
// Parallel stable counting sort (R5-verified, bit-exact vs argsort)
__global__ __launch_bounds__(256) void sort_count_kernel(const int* __restrict__ ids,
                                                         int* __restrict__ counts) {
  int w = blockIdx.x * 4 + (threadIdx.x >> 6);
  int lane = threadIdx.x & 63;
  int bhr = w >> 6, seg = w & 63;
  int id = ids[(size_t)bhr * SS + seg * 64 + lane];
  int bin = id & 127;
  unsigned long long eq = ~0ull;
  #pragma unroll
  for (int bit = 0; bit < 7; bit++) {
    unsigned long long bal = __ballot((bin >> bit) & 1);
    eq &= ((bin >> bit) & 1) ? bal : ~bal;
  }
  int rank = __popcll(eq & ((1ull << lane) - 1ull));
  if (rank == 0)
    counts[((size_t)bhr * 64 + seg) * 128 + bin] = __popcll(eq);
}

__global__ __launch_bounds__(128) void sort_prefix_kernel(int* __restrict__ counts) {
  int bhr = blockIdx.x;
  int bin = threadIdx.x;
  int r = bhr & 1;
  int* cp = counts + (size_t)bhr * 64 * 128;
  int total = 0;
  for (int seg = 0; seg < 64; seg++) total += cp[seg * 128 + bin];
  __shared__ int tot[128];
  tot[bin] = total;
  __syncthreads();
  for (int off = 1; off < 128; off <<= 1) {
    int t = (bin >= off) ? tot[bin - off] : 0;
    __syncthreads();
    tot[bin] += t;
    __syncthreads();
  }
  int run = tot[bin] - total + r * SS;
  for (int seg = 0; seg < 64; seg++) {
    int c = cp[seg * 128 + bin];
    cp[seg * 128 + bin] = run;
    run += c;
  }
}

__global__ __launch_bounds__(256) void sort_scatter_kernel(const int* __restrict__ ids,
                                                           const int* __restrict__ offs,
                                                           int* __restrict__ orig,
                                                           int* __restrict__ undo) {
  int w = blockIdx.x * 4 + (threadIdx.x >> 6);
  int lane = threadIdx.x & 63;
  int bhr = w >> 6, seg = w & 63;
  int s = seg * 64 + lane;
  int id = ids[(size_t)bhr * SS + s];
  int bin = id & 127;
  unsigned long long eq = ~0ull;
  #pragma unroll
  for (int bit = 0; bit < 7; bit++) {
    unsigned long long bal = __ballot((bin >> bit) & 1);
    eq &= ((bin >> bit) & 1) ? bal : ~bal;
  }
  int rank = __popcll(eq & ((1ull << lane) - 1ull));
  int o = offs[((size_t)bhr * 64 + seg) * 128 + bin] + rank;
  int bh = bhr >> 1, r = bhr & 1;
  orig[(size_t)bh * RS + o] = s;
  undo[(size_t)bh * RS + r * SS + s] = o;
}

// ---------------------------------------------------------------------------
__global__ __launch_bounds__(256) void rnorm_kernel(const float* __restrict__ qk,
                                                    const int* __restrict__ orig,
                                                    float* __restrict__ rno) {
  int idx = blockIdx.x * 4 + (threadIdx.x >> 6);
  int lane = threadIdx.x & 63;
  int bh = idx >> 13;
  int k = idx & (RS - 1);
  int b = bh >> 3, h = bh & 7;
  int s = orig[(size_t)bh * RS + k];
  const float* row = qk + ((size_t)(b * SS + s)) * DD + h * DH;
  float x0 = row[lane], x1 = row[lane + 64];
  float ss = x0 * x0 + x1 * x1;
  #pragma unroll
  for (int o = 1; o < 64; o <<= 1) ss += __shfl_xor(ss, o);
  if (lane == 0)
    rno[(size_t)bh * RS + k] = rsqrtf(ss * (1.0f / DH) + 1e-6f) * 0.08838834764831845f;
}

// ---------------------------------------------------------------------------
// MFMA chunked attention, T14 async-stage version (raw s_barrier, no vmcnt
// drain at barriers). Q/K/V gathered fp32 -> scaled fp16 PL-plane split.
// PL=2 (layer 0): fp32-equivalent QUAD; PL=1 (layer 1): single product.
// Per phase: [bar] write(cur from regs) + issue loads(next) [lgkm0][bar] MFMA.
// K/V row ids come from kp_lds (staged) -> short issue chains.
// V layout XOR-swizzled: KV[d*36 + (key ^ ((d>>2 &7)<<2))]; reads mirror it
// (4-aligned key blocks preserved) -> store conflicts 16-way -> ~4-way.
template<int PL>
__global__ __launch_bounds__(256) void attn_mfma_kernel(const float* __restrict__ qk,
                                                        const float* __restrict__ v,
                                                        const int* __restrict__ orig,
                                                        const float* __restrict__ rno,
                                                        float* __restrict__ osort,
                                                        float* __restrict__ lg) {
  constexpr int QPs = 64*136, Kps = 32*136, Vps = 128*36;
  constexpr size_t QPB = (size_t)PL * QPs * 2;       // Q/P region bytes
  constexpr size_t KVB = (size_t)PL * Vps * 2;       // K/V region bytes (V is larger)
  __shared__ __align__(16) char smem[QPB + KVB + 1024];
  _Float16* QP = (_Float16*)smem;                     // [PL][64][136]
  _Float16* KV = (_Float16*)(smem + QPB);             // K: [PL][32][136] / V: [PL][128][36]
  int* kp_lds = (int*)(smem + QPB + KVB);
  int* qp_lds = kp_lds + 128;

  int blk = blockIdx.x;
  int n = blk & (NC - 1), bh = blk >> 7;
  int b = bh >> 3, h = bh & 7;
  int pn = (n + NC - 1) & (NC - 1);
  int tid = threadIdx.x, lane = tid & 63, wave = tid >> 6;
  int lm = lane & 15, quad = lane >> 4;
  const int* origp = orig + (size_t)bh * RS;
  const float* rnp = rno + (size_t)bh * RS;
  const size_t base = (size_t)b * SS * DD + (size_t)h * DH;

  // per-thread staging geometry: fixed d4 column, 8-strided rows
  int d4 = tid & 31;
  int row0 = tid >> 5;                                 // 0..7
  // key base (sorted-index space) per group g
  int kb[4] = {pn*64, pn*64 + 32, n*64, n*64 + 32};

  // ---- prologue: issue Q loads + K(0) loads; stage kp/qp ids ----
  float4 qreg[8];
  #pragma unroll
  for (int i = 0; i < 8; i++)
    qreg[i] = *(const float4*)(qk + base + (size_t)origp[n*64 + row0 + i*8]*DD + d4*4);

  float4 kreg[2][4]; float krn[2][4];
  #pragma unroll
  for (int i = 0; i < 4; i++) {
    int key = row0 + i*8;
    krn[0][i] = rnp[kb[0] + key];
    kreg[0][i] = *(const float4*)(qk + base + (size_t)origp[kb[0] + key]*DD + d4*4);
  }

  if (tid < 128) kp_lds[tid] = origp[(tid < 64) ? (pn*64 + tid) : (n*64 + tid - 64)];
  else if (tid < 192) qp_lds[tid - 128] = origp[n*64 + tid - 128];

  // write Q (waits only the Q loads; K0 stays in flight)
  #pragma unroll
  for (int i = 0; i < 8; i++) {
    int q = row0 + i*8;
    float4 f = qreg[i];
    f.x *= SCF; f.y *= SCF; f.z *= SCF; f.w *= SCF;
    v4h h0; h0[0]=(_Float16)f.x; h0[1]=(_Float16)f.y; h0[2]=(_Float16)f.z; h0[3]=(_Float16)f.w;
    *(v4h*)(QP + q*136 + d4*4) = h0;
    if (PL == 2) {
      v4h h1; h1[0]=(_Float16)(f.x-(float)h0[0]); h1[1]=(_Float16)(f.y-(float)h0[1]);
      h1[2]=(_Float16)(f.z-(float)h0[2]); h1[3]=(_Float16)(f.w-(float)h0[3]);
      *(v4h*)(QP + QPs + q*136 + d4*4) = h1;
    }
  }
  asm volatile("s_waitcnt lgkmcnt(0)" ::: "memory");   // publish Q + kp/qp ids

  v4f sc[8];
  #pragma unroll
  for (int j = 0; j < 8; j++) sc[j] = (v4f)0.0f;

  // --- scores: 4 key-groups of 32, software-pipelined ---
  #pragma unroll
  for (int g = 0; g < 4; g++) {
    __builtin_amdgcn_s_barrier();                      // prev readers done / pub
    int cur = g & 1;
    // write K(g) from regs
    #pragma unroll
    for (int i = 0; i < 4; i++) {
      int key = row0 + i*8;
      float rn = krn[cur][i] * SCF;
      float4 f = kreg[cur][i];
      f.x *= rn; f.y *= rn; f.z *= rn; f.w *= rn;
      v4h h0; h0[0]=(_Float16)f.x; h0[1]=(_Float16)f.y; h0[2]=(_Float16)f.z; h0[3]=(_Float16)f.w;
      *(v4h*)(KV + key*136 + d4*4) = h0;
      if (PL == 2) {
        v4h h1; h1[0]=(_Float16)(f.x-(float)h0[0]); h1[1]=(_Float16)(f.y-(float)h0[1]);
        h1[2]=(_Float16)(f.z-(float)h0[2]); h1[3]=(_Float16)(f.w-(float)h0[3]);
        *(v4h*)(KV + Kps + key*136 + d4*4) = h1;
      }
    }
    // issue K(g+1): row ids from LDS (fast), then gathered float4
    if (g < 3) {
      #pragma unroll
      for (int i = 0; i < 4; i++) {
        int key = row0 + i*8;
        int rowid = kp_lds[(g+1)*32 + key];
        krn[cur^1][i] = rnp[kb[g+1] + key];
        kreg[cur^1][i] = *(const float4*)(qk + base + (size_t)rowid*DD + d4*4);
      }
    }
    asm volatile("s_waitcnt lgkmcnt(0)" ::: "memory"); // K(g) writes done
    __builtin_amdgcn_s_barrier();
    __builtin_amdgcn_s_setprio(1);
    #pragma unroll
    for (int ni = 0; ni < 2; ni++) {
      v4f c0 = sc[g*2 + ni];
      #pragma unroll
      for (int ks = 0; ks < 4; ks++) {
        v8h a0 = *(const v8h*)(QP + (wave*16 + lm)*136 + ks*32 + quad*8);
        v8h b0 = *(const v8h*)(KV + (ni*16 + lm)*136 + ks*32 + quad*8);
        c0 = __builtin_amdgcn_mfma_f32_16x16x32_f16(a0, b0, c0, 0, 0, 0);
        if (PL == 2) {
          v8h a1 = *(const v8h*)(QP + QPs + (wave*16 + lm)*136 + ks*32 + quad*8);
          v8h b1 = *(const v8h*)(KV + Kps + (ni*16 + lm)*136 + ks*32 + quad*8);
          c0 = __builtin_amdgcn_mfma_f32_16x16x32_f16(a0, b1, c0, 0, 0, 0);
          c0 = __builtin_amdgcn_mfma_f32_16x16x32_f16(a1, b0, c0, 0, 0, 0);
          c0 = __builtin_amdgcn_mfma_f32_16x16x32_f16(a1, b1, c0, 0, 0, 0);
        }
      }
      sc[g*2 + ni] = c0;
    }
    __builtin_amdgcn_s_setprio(0);
  }

  // issue V(0) loads NOW -- they fly under the softmax
  float4 vreg[2][4];
  #pragma unroll
  for (int i = 0; i < 4; i++) {
    int key = row0 + i*8;
    int rowid = kp_lds[key];                           // group 0 rows
    vreg[0][i] = *(const float4*)(v + base + (size_t)rowid*DD + d4*4);
  }

  __builtin_amdgcn_s_barrier();                        // score reads of QP done

  int kp_l[8];
  #pragma unroll
  for (int j = 0; j < 8; j++) kp_l[j] = kp_lds[j*16 + lm];

  // --- masked softmax per row; write scaled-split probs into QP ---
  #pragma unroll
  for (int rr = 0; rr < 4; rr++) {
    int row = wave*16 + quad*4 + rr;
    int qp = qp_lds[row];
    float sv[8];
    #pragma unroll
    for (int j = 0; j < 8; j++) {
      float s = sc[j][rr] * DSCF;
      int kp = kp_l[j];
      sv[j] = (kp > qp) ? -1000000000.0f : ((kp == qp) ? -100000.0f : s);
    }
    float m = sv[0];
    #pragma unroll
    for (int j = 1; j < 8; j++) m = fmaxf(m, sv[j]);
    #pragma unroll
    for (int o = 1; o < 16; o <<= 1) m = fmaxf(m, __shfl_xor(m, o));
    float es[8], S = 0.0f;
    #pragma unroll
    for (int j = 0; j < 8; j++) { es[j] = __expf(sv[j] - m); S += es[j]; }
    #pragma unroll
    for (int o = 1; o < 16; o <<= 1) S += __shfl_xor(S, o);
    float inv = 1.0f / S;
    if (lm == 0) lg[(size_t)bh * RS + n*64 + row] = m + __logf(S);
    #pragma unroll
    for (int j = 0; j < 8; j++) {
      float p = es[j] * inv * SCF;
      _Float16 p0 = (_Float16)p;
      QP[row*136 + j*16 + lm] = p0;
      if (PL == 2) QP[QPs + row*136 + j*16 + lm] = (_Float16)(p - (float)p0);
    }
  }

  // --- PV: 4 key-groups, V transposed into [d][key^swz] (stride 36) ---
  v4f oacc[8];
  #pragma unroll
  for (int j = 0; j < 8; j++) oacc[j] = (v4f)0.0f;
  #pragma unroll
  for (int g = 0; g < 4; g++) {
    __builtin_amdgcn_s_barrier();                      // prev V readers done
    int cur = g & 1;
    int xbs = (d4 & 7) << 2;
    // write V(g) from regs (swizzled)
    #pragma unroll
    for (int i = 0; i < 4; i++) {
      int keyS = (row0 + i*8) ^ xbs;
      float4 f = vreg[cur][i];
      float fs[4] = {f.x*SCF, f.y*SCF, f.z*SCF, f.w*SCF};
      #pragma unroll
      for (int j = 0; j < 4; j++) {
        int d = d4*4 + j;
        _Float16 p0 = (_Float16)fs[j];
        KV[d*36 + keyS] = p0;
        if (PL == 2) KV[Vps + d*36 + keyS] = (_Float16)(fs[j] - (float)p0);
      }
    }
    // issue V(g+1)
    if (g < 3) {
      #pragma unroll
      for (int i = 0; i < 4; i++) {
        int key = row0 + i*8;
        int rowid = kp_lds[(g+1)*32 + key];
        vreg[cur^1][i] = *(const float4*)(v + base + (size_t)rowid*DD + d4*4);
      }
    }
    asm volatile("s_waitcnt lgkmcnt(0)" ::: "memory"); // V(g) + P writes done
    __builtin_amdgcn_s_barrier();
    __builtin_amdgcn_s_setprio(1);
    v8h a0 = *(const v8h*)(QP + (wave*16 + lm)*136 + g*32 + quad*8);
    v8h a1;
    if (PL == 2) a1 = *(const v8h*)(QP + QPs + (wave*16 + lm)*136 + g*32 + quad*8);
    #pragma unroll
    for (int dn = 0; dn < 8; dn++) {
      int d = dn*16 + lm;
      int klo = (quad*8) ^ (((d >> 2) & 7) << 2);      // 4-aligned block
      v4h lo0 = *(const v4h*)(KV + d*36 + klo);
      v4h hi0 = *(const v4h*)(KV + d*36 + (klo ^ 4));
      v8h b0 = __builtin_shufflevector(lo0, hi0, 0,1,2,3,4,5,6,7);
      v4f c0 = oacc[dn];
      c0 = __builtin_amdgcn_mfma_f32_16x16x32_f16(a0, b0, c0, 0, 0, 0);
      if (PL == 2) {
        v4h lo1 = *(const v4h*)(KV + Vps + d*36 + klo);
        v4h hi1 = *(const v4h*)(KV + Vps + d*36 + (klo ^ 4));
        v8h b1 = __builtin_shufflevector(lo1, hi1, 0,1,2,3,4,5,6,7);
        c0 = __builtin_amdgcn_mfma_f32_16x16x32_f16(a0, b1, c0, 0, 0, 0);
        c0 = __builtin_amdgcn_mfma_f32_16x16x32_f16(a1, b0, c0, 0, 0, 0);
        c0 = __builtin_amdgcn_mfma_f32_16x16x32_f16(a1, b1, c0, 0, 0, 0);
      }
      oacc[dn] = c0;
    }
    __builtin_amdgcn_s_setprio(0);
  }

  // epilogue: O -> osort fp32
  #pragma unroll
  for (int dn = 0; dn < 8; dn++) {
    #pragma unroll
    for (int rr = 0; rr < 4; rr++) {
      int row = wave*16 + quad*4 + rr;
      osort[((size_t)bh * RS + n*64 + row) * DH + dn*16 + lm] = oacc[dn][rr] * DSCF;
    }
  }
}

// ---------------------------------------------------------------------------
// unsort + round-combine -> scaled fp16 2-plane split in h region
__global__ __launch_bounds__(256) void unsort_split_kernel(const float* __restrict__ osort,
                                                           const float* __restrict__ lg,
                                                           const int* __restrict__ undo,
                                                           _Float16* __restrict__ attn) {
  int gid = blockIdx.x * 4 + (threadIdx.x >> 6);
  int lane = threadIdx.x & 63;
  int bh = gid >> 12;
  int s = gid & (SS - 1);
  int b = bh >> 3, h = bh & 7;
  int k0 = undo[(size_t)bh * RS + s];
  int k1 = undo[(size_t)bh * RS + SS + s];
  float l0 = lg[(size_t)bh * RS + k0], l1 = lg[(size_t)bh * RS + k1];
  float m = fmaxf(l0, l1);
  float e0 = __expf(l0 - m), e1 = __expf(l1 - m);
  float inv = 1.0f / (e0 + e1);
  float w0 = e0 * inv, w1 = e1 * inv;
  const float* r0 = osort + ((size_t)bh * RS + k0) * DH;
  const float* r1 = osort + ((size_t)bh * RS + k1) * DH;
  const size_t PLN = (size_t)MROWS * DD;
  _Float16* outp = attn + ((size_t)(b * SS + s)) * DD + h * DH;
  float sA = (w0 * r0[lane]      + w1 * r1[lane])      * SCF;
  float sB = (w0 * r0[lane + 64] + w1 * r1[lane + 64]) * SCF;
  _Float16 a0 = (_Float16)sA, b0 = (_Float16)sB;
  outp[lane] = a0;                 outp[lane + 64] = b0;
  outp[PLN + lane] = (_Float16)(sA - (float)a0);
  outp[PLN + lane + 64] = (_Float16)(sB - (float)b0);
}

// ---------------------------------------------------------------------------
__global__ __launch_bounds__(256) void softmax_b_kernel(const float* __restrict__ logits,
                                                        const float* __restrict__ bout,
                                                        float* __restrict__ out) {
  int i = blockIdx.x * 256 + threadIdx.x;
  if (i >= SS * VV) return;
  int s = i / VV, vv = i - s * VV;
  float bvv = bout[vv];
  float l0 = logits[(size_t)s * VP + vv] + bvv;
  float l1 = logits[(size_t)(SS + s) * VP + vv] + bvv;
  float m = fmaxf(l0, l1);
  float e0 = __expf(l0 - m), e1 = __expf(l1 - m);
  float inv = 1.0f / (e0 + e1);
  out[(size_t)s * VV + vv] = e0 * inv;
  out[(size_t)(SS + s) * VV + vv] = e1 * inv;
}

// ---------------------------------------------------------------------------
// Workspace: extent 237,502,464 B (proven). pool[2NX..4NX) = osort region,
// time-shared: weights wt at +0, counts at +8MB, rotT at +10MB — all dead
// before attn writes osort and before FFN reuses [0,16MB).
extern "C" void kernel_launch(void* const* d_in, const int* in_sizes, int n_in,
                              void* d_out, int out_size, void* d_ws, size_t ws_size,
                              hipStream_t stream) {
  (void)in_sizes; (void)n_in; (void)out_size; (void)ws_size;
  const float* x     = (const float*)d_in[0];
  const float* ln1_g = (const float*)d_in[1];
  const float* ln1_b = (const float*)d_in[2];
  const float* Wqk   = (const float*)d_in[3];
  const float* Wv    = (const float*)d_in[4];
  const float* Wo    = (const float*)d_in[5];
  const float* rot   = (const float*)d_in[6];
  const float* ln2_g = (const float*)d_in[7];
  const float* ln2_b = (const float*)d_in[8];
  const float* W1    = (const float*)d_in[9];
  const float* b1    = (const float*)d_in[10];
  const float* W2    = (const float*)d_in[11];
  const float* b2    = (const float*)d_in[12];
  const float* lnf_g = (const float*)d_in[13];
  const float* lnf_b = (const float*)d_in[14];
  const float* Wout  = (const float*)d_in[15];
  const float* bout  = (const float*)d_in[16];

  const size_t NX = (size_t)MROWS * DD;            // 8,388,608
  float* x1 = (float*)d_ws;
  float* x2 = x1 + NX;
  float* h  = x2 + NX;
  _Float16* hs = (_Float16*)h;                     // [2][M][1024] fp16
  float* pool = h + NX;
  float* qkb   = pool;
  float* vb    = pool + NX;
  float* osort = pool + 2*NX;
  _Float16* ffh = (_Float16*)pool;                 // [2][M][2048] fp16
  _Float16* hcs = (_Float16*)pool;                 // head phase
  char* wbase = (char*)(pool + 2*NX);
  _Float16* wt = (_Float16*)wbase;                 // weight squat region
  int* counts = (int*)(wbase + (8u<<20));          // 1 MB
  _Float16* rotTs = (_Float16*)(wbase + (10u<<20));// 512 KB
  float* after = pool + 4*NX;
  float* lgb = after;
  float* rno = lgb + (size_t)BH * RS;
  int* orig = (int*)(rno + (size_t)BH * RS);
  int* undo = orig + (size_t)BH * RS;
  int* ids  = undo + (size_t)BH * RS;
  float* logitsP = h;                              // head phase

  const size_t AP_D  = NX;
  const size_t AP_FF = (size_t)MROWS * 2048;
  const size_t BP_D  = (size_t)DD * DD;
  const size_t BP_W1 = (size_t)2048 * DD;
  const size_t BP_W2 = (size_t)DD * 2048;
  const size_t BP_HD = (size_t)VP * 2048;

  init_x_kernel<<<(int)(NX / 256), 256, 0, stream>>>(x, x1, x2);

  for (int l = 0; l < LL; l++) {
    // --- attention ---
    ln_split_kernel<<<MROWS, 256, 0, stream>>>(x2, ln1_g + l*DD, ln1_b + l*DD, hs);

    wconv_kernel<<<dim3(32, 32), 256, 0, stream>>>(Wqk + (size_t)l*DD*DD, wt, DD, DD, DD, DD);
    qgemm_kernel<2,0,false,false,4><<<dim3(8, 64), 256, 0, stream>>>(
        hs, wt, nullptr, qkb, MROWS, DD, DD, AP_D, BP_D);

    wconv_kernel<<<dim3(32, 32), 256, 0, stream>>>(Wv + (size_t)l*DD*DD, wt, DD, DD, DD, DD);
    if (l == 0)
      qgemm_kernel<2,0,false,false,3><<<dim3(8, 64), 256, 0, stream>>>(
          hs, wt, nullptr, vb, MROWS, DD, DD, AP_D, BP_D);
    else
      qgemm_kernel<1,0,false,false,3><<<dim3(8, 64), 256, 0, stream>>>(
          hs, wt, nullptr, vb, MROWS, DD, DD, AP_D, BP_D);

    rott_kernel<<<dim3(8, 8), 256, 0, stream>>>(rot + (size_t)l*HH*DH*RR*64, rotTs);
    bucket_mfma_kernel<<<dim3(32, 16), 256, 0, stream>>>(qkb, rotTs, ids);

    hipMemsetAsync(counts, 0, (size_t)BH * RR * 64 * 128 * sizeof(int), stream);
    sort_count_kernel<<<512, 256, 0, stream>>>(ids, counts);
    sort_prefix_kernel<<<BH*RR, 128, 0, stream>>>(counts);
    sort_scatter_kernel<<<512, 256, 0, stream>>>(ids, counts, orig, undo);

    rnorm_kernel<<<BH*RS/4, 256, 0, stream>>>(qkb, orig, rno);
    if (l == 0)
      attn_mfma_kernel<2><<<BH*NC, 256, 0, stream>>>(qkb, vb, orig, rno, osort, lgb);
    else
      attn_mfma_kernel<1><<<BH*NC, 256, 0, stream>>>(qkb, vb, orig, rno, osort, lgb);
    unsort_split_kernel<<<BH*SS/4, 256, 0, stream>>>(osort, lgb, undo, hs);   // osort dead

    wconv_kernel<<<dim3(32, 32), 256, 0, stream>>>(Wo + (size_t)l*DD*DD, wt, DD, DD, DD, DD);
    if (l == 0)
      qgemm_kernel<2,1,false,false,3><<<dim3(8, 64), 256, 0, stream>>>(
          hs, wt, nullptr, x1, MROWS, DD, DD, AP_D, BP_D);
    else
      qgemm_kernel<1,1,false,false,3><<<dim3(8, 64), 256, 0, stream>>>(
          hs, wt, nullptr, x1, MROWS, DD, DD, AP_D, BP_D);

    // --- FFN, two FF-halves of 2048 ---
    ln_split_kernel<<<MROWS, 256, 0, stream>>>(x1, ln2_g + l*DD, ln2_b + l*DD, hs);
    for (int hf = 0; hf < 2; hf++) {
      const float* W1h = W1 + (size_t)l*DD*FFD + (size_t)hf*2048;
      const float* W2h = W2 + (size_t)l*FFD*DD + (size_t)hf*2048*DD;
      _Float16* wt1 = wt;
      _Float16* wt2 = wt + 2u*2097152u;
      wconv_kernel<<<dim3(64, 32), 256, 0, stream>>>(W1h, wt1, DD, 2048, 2048, FFD);
      wconv_kernel<<<dim3(32, 64), 256, 0, stream>>>(W2h, wt2, 2048, DD, DD, DD);
      if (l == 0) {
        qgemm_kernel<2,2,true,true,3><<<dim3(16, 64), 256, 0, stream>>>(
            hs, wt1, b1 + (size_t)l*FFD + hf*2048, ffh, MROWS, 2048, DD, AP_D, BP_W1);
        if (hf == 0)
          qgemm_kernel<2,1,true,false,3><<<dim3(8, 64), 256, 0, stream>>>(
              ffh, wt2, b2 + (size_t)l*DD, x2, MROWS, DD, 2048, AP_FF, BP_W2);
        else
          qgemm_kernel<2,1,false,false,3><<<dim3(8, 64), 256, 0, stream>>>(
              ffh, wt2, nullptr, x2, MROWS, DD, 2048, AP_FF, BP_W2);
      } else {
        qgemm_kernel<1,2,true,true,3><<<dim3(16, 64), 256, 0, stream>>>(
            hs, wt1, b1 + (size_t)l*FFD + hf*2048, ffh, MROWS, 2048, DD, AP_D, BP_W1);
        if (hf == 0)
          qgemm_kernel<1,1,true,false,3><<<dim3(8, 64), 256, 0, stream>>>(
              ffh, wt2, b2 + (size_t)l*DD, x2, MROWS, DD, 2048, AP_FF, BP_W2);
        else
          qgemm_kernel<1,1,false,false,3><<<dim3(8, 64), 256, 0, stream>>>(
              ffh, wt2, nullptr, x2, MROWS, DD, 2048, AP_FF, BP_W2);
      }
    }
  }

  // --- head ---
  ln_concat_split_kernel<<<MROWS, 256, 0, stream>>>(x1, x2, lnf_g, lnf_b, hcs);
  wconv_kernel<<<dim3(12, 64), 256, 0, stream>>>(Wout, wt, 2*DD, VV, VP, VV);
  qgemm_kernel<1,0,false,false,3><<<dim3(3, 64), 256, 0, stream>>>(
      hcs, wt, nullptr, logitsP, MROWS, VP, 2*DD, AP_FF, BP_HD);
  softmax_b_kernel<<<(SS*VV + 255)/256, 256, 0, stream>>>(logitsP, bout, (float*)d_out);
}

// Round 5
// 1677.648 us; speedup vs baseline: 1.0719x; 1.0439x over previous
//
#include <hip/hip_runtime.h>
#include <hip/hip_fp16.h>
#include <math.h>

#define BB 2
#define SS 4096
#define DD 1024
#define HH 8
#define DH 128
#define RR 2
#define CC 64
#define NBUCK 128
#define LL 2
#define FFD 4096
#define VV 258
#define VP 384            // padded vocab for head GEMM (multiple of 128)
#define RS (RR*SS)        // 8192
#define NC (RS/CC)        // 128
#define BH (BB*HH)        // 16
#define MROWS (BB*SS)     // 8192

// scale 2^8 on both operand splits; descale 2^-16 in epilogue (fp16 denorm guard)
#define SCF 256.0f
#define DSCF (1.0f/65536.0f)

typedef __attribute__((ext_vector_type(8))) _Float16 v8h;
typedef __attribute__((ext_vector_type(4))) _Float16 v4h;
typedef __attribute__((ext_vector_type(4))) float v4f;

// ---------------------------------------------------------------------------
__device__ __forceinline__ void gld16(const void* g, void* l) {
  __builtin_amdgcn_global_load_lds((const __attribute__((address_space(1))) void*)g,
                                   (__attribute__((address_space(3))) void*)l, 16, 0, 0);
}

// ---------------------------------------------------------------------------
__device__ __forceinline__ void block_sum2(float& s, float& s2) {
  #pragma unroll
  for (int o = 1; o < 64; o <<= 1) { s += __shfl_xor(s, o); s2 += __shfl_xor(s2, o); }
  __shared__ float rs[4], rq[4];
  int wave = threadIdx.x >> 6;
  if ((threadIdx.x & 63) == 0) { rs[wave] = s; rq[wave] = s2; }
  __syncthreads();
  s  = rs[0] + rs[1] + rs[2] + rs[3];
  s2 = rq[0] + rq[1] + rq[2] + rq[3];
}

// ---------------------------------------------------------------------------
__global__ __launch_bounds__(256) void init_x_kernel(const float* __restrict__ x,
                                                     float* __restrict__ x1,
                                                     float* __restrict__ x2) {
  size_t i = (size_t)blockIdx.x * 256 + threadIdx.x;
  float v = x[i];
  x1[i] = v; x2[i] = v;
}

// ---------------------------------------------------------------------------
// LayerNorm over D=1024 -> scaled fp16 2-plane split (plane stride MROWS*DD)
__global__ __launch_bounds__(256) void ln_split_kernel(const float* __restrict__ x,
                                                       const float* __restrict__ g,
                                                       const float* __restrict__ bta,
                                                       _Float16* __restrict__ out) {
  int row = blockIdx.x;
  int t = threadIdx.x;
  float4 xv = ((const float4*)(x + (size_t)row * DD))[t];
  float s  = xv.x + xv.y + xv.z + xv.w;
  float s2 = xv.x*xv.x + xv.y*xv.y + xv.z*xv.z + xv.w*xv.w;
  block_sum2(s, s2);
  float mu   = s * (1.0f / DD);
  float var  = fmaxf(s2 * (1.0f / DD) - mu * mu, 0.0f);
  float rstd = rsqrtf(var + 1e-12f);
  float4 gv = ((const float4*)g)[t];
  float4 bv = ((const float4*)bta)[t];
  float4 sv;
  sv.x = ((xv.x - mu) * rstd * gv.x + bv.x) * SCF;
  sv.y = ((xv.y - mu) * rstd * gv.y + bv.y) * SCF;
  sv.z = ((xv.z - mu) * rstd * gv.z + bv.z) * SCF;
  sv.w = ((xv.w - mu) * rstd * gv.w + bv.w) * SCF;
  v4h h0, h1;
  h0[0]=(_Float16)sv.x; h0[1]=(_Float16)sv.y; h0[2]=(_Float16)sv.z; h0[3]=(_Float16)sv.w;
  h1[0]=(_Float16)(sv.x-(float)h0[0]); h1[1]=(_Float16)(sv.y-(float)h0[1]);
  h1[2]=(_Float16)(sv.z-(float)h0[2]); h1[3]=(_Float16)(sv.w-(float)h0[3]);
  const size_t PLN = (size_t)MROWS * DD;
  size_t base = (size_t)row * DD + t * 4;
  *(v4h*)(out + base) = h0;
  *(v4h*)(out + PLN + base) = h1;
}

// LayerNorm over concat([x1,x2]) (2048) -> scaled fp16 single plane
// (head GEMM is PL=1: plane-1 stores were dead, dropped)
__global__ __launch_bounds__(256) void ln_concat_split_kernel(const float* __restrict__ x1,
                                                              const float* __restrict__ x2,
                                                              const float* __restrict__ g,
                                                              const float* __restrict__ bta,
                                                              _Float16* __restrict__ out) {
  int row = blockIdx.x;
  int t = threadIdx.x;
  float4 a = ((const float4*)(x1 + (size_t)row * DD))[t];
  float4 b = ((const float4*)(x2 + (size_t)row * DD))[t];
  float s  = a.x + a.y + a.z + a.w + b.x + b.y + b.z + b.w;
  float s2 = a.x*a.x + a.y*a.y + a.z*a.z + a.w*a.w
           + b.x*b.x + b.y*b.y + b.z*b.z + b.w*b.w;
  block_sum2(s, s2);
  float mu   = s * (1.0f / (2*DD));
  float var  = fmaxf(s2 * (1.0f / (2*DD)) - mu * mu, 0.0f);
  float rstd = rsqrtf(var + 1e-12f);
  float4 g1 = ((const float4*)g)[t];
  float4 b1v = ((const float4*)bta)[t];
  float4 g2 = ((const float4*)g)[256 + t];
  float4 b2v = ((const float4*)bta)[256 + t];
  float4 s1, s2v;
  s1.x = ((a.x-mu)*rstd*g1.x + b1v.x)*SCF;  s1.y = ((a.y-mu)*rstd*g1.y + b1v.y)*SCF;
  s1.z = ((a.z-mu)*rstd*g1.z + b1v.z)*SCF;  s1.w = ((a.w-mu)*rstd*g1.w + b1v.w)*SCF;
  s2v.x = ((b.x-mu)*rstd*g2.x + b2v.x)*SCF; s2v.y = ((b.y-mu)*rstd*g2.y + b2v.y)*SCF;
  s2v.z = ((b.z-mu)*rstd*g2.z + b2v.z)*SCF; s2v.w = ((b.w-mu)*rstd*g2.w + b2v.w)*SCF;
  v4h h0;
  size_t base = (size_t)row * (2*DD) + t * 4;
  h0[0]=(_Float16)s1.x; h0[1]=(_Float16)s1.y; h0[2]=(_Float16)s1.z; h0[3]=(_Float16)s1.w;
  *(v4h*)(out + base) = h0;
  h0[0]=(_Float16)s2v.x; h0[1]=(_Float16)s2v.y; h0[2]=(_Float16)s2v.z; h0[3]=(_Float16)s2v.w;
  *(v4h*)(out + base + DD) = h0;
}

// ---------------------------------------------------------------------------
// weight convert fp32 W[K][·] (row stride ldw) cols [0,N) -> scaled fp16
// 2-plane split Wt[2][Npad][K] (zero pad n>=N)
__global__ __launch_bounds__(256) void wconv_kernel(const float* __restrict__ W,
                                                    _Float16* __restrict__ Wt,
                                                    int K, int N, int Npad, int ldw) {
  __shared__ float tile[32][33];
  int n0 = blockIdx.x * 32, k0 = blockIdx.y * 32;
  int tid = threadIdx.x;
  #pragma unroll
  for (int i = 0; i < 4; i++) {
    int idx = i*256 + tid;
    int kk = idx >> 5, nn = idx & 31;
    float v = 0.0f;
    if (n0 + nn < N) v = W[(size_t)(k0 + kk) * ldw + n0 + nn];
    tile[kk][nn] = v;
  }
  __syncthreads();
  size_t NKs = (size_t)Npad * K;
  #pragma unroll
  for (int i = 0; i < 4; i++) {
    int idx = i*256 + tid;
    int nn = idx >> 5, kk = idx & 31;
    float s = tile[kk][nn] * SCF;
    size_t off = (size_t)(n0 + nn) * K + k0 + kk;
    _Float16 h0 = (_Float16)s;
    _Float16 h1 = (_Float16)(s - (float)h0);
    Wt[off] = h0;
    Wt[NKs + off] = h1;
  }
}

// ---------------------------------------------------------------------------
// fp16x2 MFMA GEMM, 2-phase pipeline with COUNTED vmcnt (T3+T4). PL=2: split
// (fp32-equivalent); PL=1: single. NP=4 full QUAD for discrete consumers
// (bucket argmax via Wqk); NP=3 drops a1*b1 (~2^-22 rel) elsewhere.
// Raw s_barrier only (no implicit vmcnt(0) drain). Per K-step:
//   s_waitcnt vmcnt(NCH)     -- oldest stage complete, next stays IN FLIGHT
//   s_barrier                -- all waves see buf[cur] filled
//   ds_read frags(buf[cur])
//   s_waitcnt lgkmcnt(0); s_barrier  -- all waves done reading buf[cur]
//   stage(t+2 -> buf[cur])   -- refill just-read buffer
//   MFMA                     -- register-only; loads fly underneath
// Numerics bit-identical (same MFMA order).
// CMODE: 0 store f32, 1 accumulate f32, 2 split-store fp16 2-plane.
template<int PL, int CMODE, bool BIAS, bool RELU, int NP>
__global__ __launch_bounds__(256) void qgemm_kernel(const _Float16* __restrict__ A,
                                                    const _Float16* __restrict__ Bt,
                                                    const float* __restrict__ bias,
                                                    void* __restrict__ Cv,
                                                    int M, int N, int K,
                                                    size_t aplane, size_t bplane) {
  __shared__ __align__(16) _Float16 As[2][PL*128*32];
  __shared__ __align__(16) _Float16 Bs[2][PL*128*32];
  int tid = threadIdx.x, lane = tid & 63, wave = tid >> 6;
  int m0 = blockIdx.y * 128, n0 = blockIdx.x * 128;
  int wm = (wave & 1) * 64, wn = (wave >> 1) * 64;
  int lm = lane & 15, quad = lane >> 4;
  const int NCH = (PL == 2) ? 8 : 4;
  const int ACH = (PL == 2) ? 16 : 8;
  v4f acc[4][4];
  #pragma unroll
  for (int i = 0; i < 4; i++)
    #pragma unroll
    for (int j = 0; j < 4; j++) acc[i][j] = (v4f)0.0f;

  auto stage = [&](int k0, int bufi) {
    #pragma unroll
    for (int i = 0; i < NCH; i++) {
      int c = wave * NCH + i;
      if (c < ACH) {
        int p = c >> 3, q = c & 7;
        int row = q * 16 + (lane >> 2), col = (lane & 3) * 8;
        gld16(A + (size_t)p * aplane + (size_t)(m0 + row) * K + k0 + col,
              (char*)As[bufi] + (size_t)c * 1024);
      } else {
        int cb = c - ACH;
        int p = cb >> 3, q = cb & 7;
        int row = q * 16 + (lane >> 2), col = (lane & 3) * 8;
        gld16(Bt + (size_t)p * bplane + (size_t)(n0 + row) * K + k0 + col,
              (char*)Bs[bufi] + (size_t)cb * 1024);
      }
    }
  };

  const int nsteps = K >> 5;   // >= 32 for all launches
  stage(0, 0);
  stage(32, 1);

  for (int t = 0; t < nsteps; ++t) {
    int cur = t & 1;
    // wait for stage(t) only; stage(t+1)'s NCH loads remain in flight
    if (t + 1 < nsteps) {
      if (PL == 2) asm volatile("s_waitcnt vmcnt(8)" ::: "memory");
      else         asm volatile("s_waitcnt vmcnt(4)" ::: "memory");
    } else {
      asm volatile("s_waitcnt vmcnt(0)" ::: "memory");
    }
    __builtin_amdgcn_s_barrier();

    const _Float16* Ab = As[cur];
    const _Float16* Bb = Bs[cur];
    v8h a[4][2], b[4][2];
    #pragma unroll
    for (int ni = 0; ni < 4; ni++) {
      int boff = (wn + ni*16 + lm) * 32 + quad * 8;
      b[ni][0] = *(const v8h*)&Bb[boff];
      if (PL == 2) b[ni][1] = *(const v8h*)&Bb[4096 + boff];
    }
    #pragma unroll
    for (int mi = 0; mi < 4; mi++) {
      int aoff = (wm + mi*16 + lm) * 32 + quad * 8;
      a[mi][0] = *(const v8h*)&Ab[aoff];
      if (PL == 2) a[mi][1] = *(const v8h*)&Ab[4096 + aoff];
    }
    asm volatile("s_waitcnt lgkmcnt(0)" ::: "memory");  // this wave's reads done
    __builtin_amdgcn_s_barrier();                       // all waves' reads done

    // refill the buffer we just read; flies under the MFMAs below
    if (t + 2 < nsteps) stage((t + 2) << 5, cur);

    #pragma unroll
    for (int mi = 0; mi < 4; mi++) {
      #pragma unroll
      for (int ni = 0; ni < 4; ni++) {
        v4f c0 = acc[mi][ni];
        c0 = __builtin_amdgcn_mfma_f32_16x16x32_f16(a[mi][0], b[ni][0], c0, 0, 0, 0);
        if (PL == 2) {
          c0 = __builtin_amdgcn_mfma_f32_16x16x32_f16(a[mi][0], b[ni][1], c0, 0, 0, 0);
          c0 = __builtin_amdgcn_mfma_f32_16x16x32_f16(a[mi][1], b[ni][0], c0, 0, 0, 0);
          if (NP == 4)
            c0 = __builtin_amdgcn_mfma_f32_16x16x32_f16(a[mi][1], b[ni][1], c0, 0, 0, 0);
        }
        acc[mi][ni] = c0;
      }
    }
  }

  float* Cf = (float*)Cv;
  _Float16* Ch = (_Float16*)Cv;
  const size_t cplane = (size_t)M * N;
  #pragma unroll
  for (int mi = 0; mi < 4; mi++) {
    int rbase = m0 + wm + mi*16 + quad*4;
    #pragma unroll
    for (int ni = 0; ni < 4; ni++) {
      int col = n0 + wn + ni*16 + lm;
      float bv = BIAS ? bias[col] : 0.0f;
      #pragma unroll
      for (int r = 0; r < 4; r++) {
        float val = acc[mi][ni][r] * DSCF + bv;
        if (RELU) val = fmaxf(val, 0.0f);
        size_t off = (size_t)(rbase + r) * N + col;
        if (CMODE == 0) Cf[off] = val;
        else if (CMODE == 1) Cf[off] += val;
        else {
          float s = val * SCF;
          _Float16 h0 = (_Float16)s;
          _Float16 h1 = (_Float16)(s - (float)h0);
          Ch[off] = h0;
          Ch[cplane + off] = h1;
        }
      }
    }
  }
}

// ---------------------------------------------------------------------------
// rot[h][d][r][n] -> rotT[h][2 planes][rcol=r*64+n][d] scaled fp16 split
__global__ __launch_bounds__(256) void rott_kernel(const float* __restrict__ rot,
                                                   _Float16* __restrict__ rotT) {
  int h = blockIdx.x, grp = blockIdx.y;    // dim3(8,8)
  const float* rh = rot + (size_t)h * (DH * RR * 64);
  for (int idx = threadIdx.x; idx < 16*128; idx += 256) {
    int rc = grp*16 + (idx >> 7), d = idx & 127;
    int r = rc >> 6, nn = rc & 63;
    float f = rh[(size_t)d * 128 + r * 64 + nn] * SCF;
    _Float16 h0 = (_Float16)f;
    rotT[(size_t)h*32768 + (size_t)rc*128 + d] = h0;
    rotT[(size_t)h*32768 + 16384 + (size_t)rc*128 + d] = (_Float16)(f - (float)h0);
  }
}

// ---------------------------------------------------------------------------
// bucket via MFMA: rotated = qk_head @ rotT^T, fused argmax epilogue.
// A: qkb fp32 (in-register QUAD split, R4-verified XOR-swizzle staging).
// Each wave's 64 cols = one full hash round -> per-wave argmax, no combine.
// Kept at full 4-product QUAD: feeds discrete argmax (bucket assignment).
__global__ __launch_bounds__(256) void bucket_mfma_kernel(const float* __restrict__ qkb,
                                                          const _Float16* __restrict__ rotT,
                                                          int* __restrict__ ids) {
  __shared__ __align__(16) float Af[128*32];          // 16 KB XOR-swizzled
  __shared__ __align__(16) _Float16 Bs[2*128*32];     // 16 KB
  int mtile = blockIdx.x, bh = blockIdx.y;
  int b = bh >> 3, h = bh & 7;
  int tid = threadIdx.x, lane = tid & 63, wave = tid >> 6;
  int wm = (wave & 1) * 64;
  int r = wave >> 1;                                   // round handled by this wave
  int wn = r * 64;
  int lm = lane & 15, quad = lane >> 4;
  const float* Aq = qkb + ((size_t)b * SS + (size_t)mtile * 128) * DD + h * DH;
  const _Float16* Bq = rotT + (size_t)h * 32768;
  v4f acc[4][4];
  #pragma unroll
  for (int i = 0; i < 4; i++)
    #pragma unroll
    for (int j = 0; j < 4; j++) acc[i][j] = (v4f)0.0f;

  for (int k0 = 0; k0 < 128; k0 += 32) {
    #pragma unroll
    for (int i = 0; i < 8; i++) {
      int c = wave * 8 + i;
      if (c < 16) {
        int slot = c * 64 + lane;
        int row = slot >> 3;
        int c4 = (slot & 7) ^ (row & 7);
        gld16(Aq + (size_t)row * DD + k0 + c4 * 4, (char*)Af + (size_t)c * 1024);
      } else {
        int cb = c - 16;
        int p = cb >> 3, q = cb & 7;
        int row = q * 16 + (lane >> 2), col = (lane & 3) * 8;
        gld16(Bq + (size_t)p * 16384 + (size_t)row * 128 + k0 + col,
              (char*)Bs + (size_t)p * 8192 + (size_t)q * 1024);
      }
    }
    __syncthreads();
    v8h b0[4], b1[4];
    #pragma unroll
    for (int ni = 0; ni < 4; ni++) {
      int boff = (wn + ni*16 + lm) * 32 + quad * 8;
      b0[ni] = *(const v8h*)&Bs[boff];
      b1[ni] = *(const v8h*)&Bs[4096 + boff];
    }
    #pragma unroll
    for (int mi = 0; mi < 4; mi++) {
      int arow = wm + mi*16 + lm;
      int sw = arow & 7;
      float4 fA = *(const float4*)(Af + arow*32 + (((2*quad)     ^ sw) << 2));
      float4 fB = *(const float4*)(Af + arow*32 + (((2*quad + 1) ^ sw) << 2));
      v8h a0, a1;
      float fs[8] = {fA.x*SCF, fA.y*SCF, fA.z*SCF, fA.w*SCF,
                     fB.x*SCF, fB.y*SCF, fB.z*SCF, fB.w*SCF};
      #pragma unroll
      for (int j = 0; j < 8; j++) {
        _Float16 p0 = (_Float16)fs[j];
        a0[j] = p0;
        a1[j] = (_Float16)(fs[j] - (float)p0);
      }
      #pragma unroll
      for (int ni = 0; ni < 4; ni++) {
        v4f c0 = acc[mi][ni];
        c0 = __builtin_amdgcn_mfma_f32_16x16x32_f16(a0, b0[ni], c0, 0, 0, 0);
        c0 = __builtin_amdgcn_mfma_f32_16x16x32_f16(a0, b1[ni], c0, 0, 0, 0);
        c0 = __builtin_amdgcn_mfma_f32_16x16x32_f16(a1, b0[ni], c0, 0, 0, 0);
        c0 = __builtin_amdgcn_mfma_f32_16x16x32_f16(a1, b1[ni], c0, 0, 0, 0);
        acc[mi][ni] = c0;
      }
    }
    __syncthreads();
  }

  // argmax epilogue (scaled values; comparisons scale-invariant)
  #pragma unroll
  for (int mi = 0; mi < 4; mi++) {
    #pragma unroll
    for (int rr = 0; rr < 4; rr++) {
      float mx = acc[mi][0][rr]; int xi = lm;
      float mn = acc[mi][0][rr]; int ni_ = lm;
      #pragma unroll
      for (int ni = 1; ni < 4; ni++) {
        float vv = acc[mi][ni][rr];
        int col = ni*16 + lm;
        if (vv > mx) { mx = vv; xi = col; }
        if (vv < mn) { mn = vv; ni_ = col; }
      }
      #pragma unroll
      for (int o = 1; o < 16; o <<= 1) {
        float ox = __shfl_xor(mx, o); int oxi = __shfl_xor(xi, o);
        if (ox > mx || (ox == mx && oxi < xi)) { mx = ox; xi = oxi; }
        float on = __shfl_xor(mn, o); int oni = __shfl_xor(ni_, o);
        if (on < mn || (on == mn && oni < ni_)) { mn = on; ni_ = oni; }
      }
      if (lm == 0) {
        int bi = (mx >= -mn) ? xi : 64 + ni_;
        int s = mtile*128 + wm + mi*16 + quad*4 + rr;
        ids[((size_t)bh * RR + r) * SS + s] = bi + r * NBUCK;
      }
    }
  }
}

// ---------------------------------------------------------------------------
// Parallel stable counting sort (R5-verified, bit-exact vs argsort)
__global__ __launch_bounds__(256) void sort_count_kernel(const int* __restrict__ ids,
                                                         int* __restrict__ counts) {
  int w = blockIdx.x * 4 + (threadIdx.x >> 6);
  int lane = threadIdx.x & 63;
  int bhr = w >> 6, seg = w & 63;
  int id = ids[(size_t)bhr * SS + seg * 64 + lane];
  int bin = id & 127;
  unsigned long long eq = ~0ull;
  #pragma unroll
  for (int bit = 0; bit < 7; bit++) {
    unsigned long long bal = __ballot((bin >> bit) & 1);
    eq &= ((bin >> bit) & 1) ? bal : ~bal;
  }
  int rank = __popcll(eq & ((1ull << lane) - 1ull));
  if (rank == 0)
    counts[((size_t)bhr * 64 + seg) * 128 + bin] = __popcll(eq);
}

__global__ __launch_bounds__(128) void sort_prefix_kernel(int* __restrict__ counts) {
  int bhr = blockIdx.x;
  int bin = threadIdx.x;
  int r = bhr & 1;
  int* cp = counts + (size_t)bhr * 64 * 128;
  int total = 0;
  for (int seg = 0; seg < 64; seg++) total += cp[seg * 128 + bin];
  __shared__ int tot[128];
  tot[bin] = total;
  __syncthreads();
  for (int off = 1; off < 128; off <<= 1) {
    int t = (bin >= off) ? tot[bin - off] : 0;
    __syncthreads();
    tot[bin] += t;
    __syncthreads();
  }
  int run = tot[bin] - total + r * SS;
  for (int seg = 0; seg < 64; seg++) {
    int c = cp[seg * 128 + bin];
    cp[seg * 128 + bin] = run;
    run += c;
  }
}

__global__ __launch_bounds__(256) void sort_scatter_kernel(const int* __restrict__ ids,
                                                           const int* __restrict__ offs,
                                                           int* __restrict__ orig,
                                                           int* __restrict__ undo) {
  int w = blockIdx.x * 4 + (threadIdx.x >> 6);
  int lane = threadIdx.x & 63;
  int bhr = w >> 6, seg = w & 63;
  int s = seg * 64 + lane;
  int id = ids[(size_t)bhr * SS + s];
  int bin = id & 127;
  unsigned long long eq = ~0ull;
  #pragma unroll
  for (int bit = 0; bit < 7; bit++) {
    unsigned long long bal = __ballot((bin >> bit) & 1);
    eq &= ((bin >> bit) & 1) ? bal : ~bal;
  }
  int rank = __popcll(eq & ((1ull << lane) - 1ull));
  int o = offs[((size_t)bhr * 64 + seg) * 128 + bin] + rank;
  int bh = bhr >> 1, r = bhr & 1;
  orig[(size_t)bh * RS + o] = s;
  undo[(size_t)bh * RS + r * SS + s] = o;
}

// ---------------------------------------------------------------------------
__global__ __launch_bounds__(256) void rnorm_kernel(const float* __restrict__ qk,
                                                    const int* __restrict__ orig,
                                                    float* __restrict__ rno) {
  int idx = blockIdx.x * 4 + (threadIdx.x >> 6);
  int lane = threadIdx.x & 63;
  int bh = idx >> 13;
  int k = idx & (RS - 1);
  int b = bh >> 3, h = bh & 7;
  int s = orig[(size_t)bh * RS + k];
  const float* row = qk + ((size_t)(b * SS + s)) * DD + h * DH;
  float x0 = row[lane], x1 = row[lane + 64];
  float ss = x0 * x0 + x1 * x1;
  #pragma unroll
  for (int o = 1; o < 64; o <<= 1) ss += __shfl_xor(ss, o);
  if (lane == 0)
    rno[(size_t)bh * RS + k] = rsqrtf(ss * (1.0f / DH) + 1e-6f) * 0.08838834764831845f;
}

// ---------------------------------------------------------------------------
// MFMA chunked attention, T14 async-stage version (raw s_barrier, no vmcnt
// drain at barriers). Q/K/V gathered fp32 -> scaled fp16 PL-plane split.
// PL=2 (layer 0): fp32-equivalent QUAD; PL=1 (layer 1): single product.
// Per phase: [bar] write(cur from regs) + issue loads(next) [lgkm0][bar] MFMA.
// K/V row ids come from kp_lds (staged) -> short issue chains.
// V layout XOR-swizzled: KV[d*36 + (key ^ ((d>>2 &7)<<2))]; reads mirror it
// (4-aligned key blocks preserved) -> store conflicts 16-way -> ~4-way.
template<int PL>
__global__ __launch_bounds__(256) void attn_mfma_kernel(const float* __restrict__ qk,
                                                        const float* __restrict__ v,
                                                        const int* __restrict__ orig,
                                                        const float* __restrict__ rno,
                                                        float* __restrict__ osort,
                                                        float* __restrict__ lg) {
  constexpr int QPs = 64*136, Kps = 32*136, Vps = 128*36;
  constexpr size_t QPB = (size_t)PL * QPs * 2;       // Q/P region bytes
  constexpr size_t KVB = (size_t)PL * Vps * 2;       // K/V region bytes (V is larger)
  __shared__ __align__(16) char smem[QPB + KVB + 1024];
  _Float16* QP = (_Float16*)smem;                     // [PL][64][136]
  _Float16* KV = (_Float16*)(smem + QPB);             // K: [PL][32][136] / V: [PL][128][36]
  int* kp_lds = (int*)(smem + QPB + KVB);
  int* qp_lds = kp_lds + 128;

  int blk = blockIdx.x;
  int n = blk & (NC - 1), bh = blk >> 7;
  int b = bh >> 3, h = bh & 7;
  int pn = (n + NC - 1) & (NC - 1);
  int tid = threadIdx.x, lane = tid & 63, wave = tid >> 6;
  int lm = lane & 15, quad = lane >> 4;
  const int* origp = orig + (size_t)bh * RS;
  const float* rnp = rno + (size_t)bh * RS;
  const size_t base = (size_t)b * SS * DD + (size_t)h * DH;

  // per-thread staging geometry: fixed d4 column, 8-strided rows
  int d4 = tid & 31;
  int row0 = tid >> 5;                                 // 0..7
  // key base (sorted-index space) per group g
  int kb[4] = {pn*64, pn*64 + 32, n*64, n*64 + 32};

  // ---- prologue: issue Q loads + K(0) loads; stage kp/qp ids ----
  float4 qreg[8];
  #pragma unroll
  for (int i = 0; i < 8; i++)
    qreg[i] = *(const float4*)(qk + base + (size_t)origp[n*64 + row0 + i*8]*DD + d4*4);

  float4 kreg[2][4]; float krn[2][4];
  #pragma unroll
  for (int i = 0; i < 4; i++) {
    int key = row0 + i*8;
    krn[0][i] = rnp[kb[0] + key];
    kreg[0][i] = *(const float4*)(qk + base + (size_t)origp[kb[0] + key]*DD + d4*4);
  }

  if (tid < 128) kp_lds[tid] = origp[(tid < 64) ? (pn*64 + tid) : (n*64 + tid - 64)];
  else if (tid < 192) qp_lds[tid - 128] = origp[n*64 + tid - 128];

  // write Q (waits only the Q loads; K0 stays in flight)
  #pragma unroll
  for (int i = 0; i < 8; i++) {
    int q = row0 + i*8;
    float4 f = qreg[i];
    f.x *= SCF; f.y *= SCF; f.z *= SCF; f.w *= SCF;
    v4h h0; h0[0]=(_Float16)f.x; h0[1]=(_Float16)f.y; h0[2]=(_Float16)f.z; h0[3]=(_Float16)f.w;
    *(v4h*)(QP + q*136 + d4*4) = h0;
    if (PL == 2) {
      v4h h1; h1[0]=(_Float16)(f.x-(float)h0[0]); h1[1]=(_Float16)(f.y-(float)h0[1]);
      h1[2]=(_Float16)(f.z-(float)h0[2]); h1[3]=(_Float16)(f.w-(float)h0[3]);
      *(v4h*)(QP + QPs + q*136 + d4*4) = h1;
    }
  }
  asm volatile("s_waitcnt lgkmcnt(0)" ::: "memory");   // publish Q + kp/qp ids

  v4f sc[8];
  #pragma unroll
  for (int j = 0; j < 8; j++) sc[j] = (v4f)0.0f;

  // --- scores: 4 key-groups of 32, software-pipelined ---
  #pragma unroll
  for (int g = 0; g < 4; g++) {
    __builtin_amdgcn_s_barrier();                      // prev readers done / pub
    int cur = g & 1;
    // write K(g) from regs
    #pragma unroll
    for (int i = 0; i < 4; i++) {
      int key = row0 + i*8;
      float rn = krn[cur][i] * SCF;
      float4 f = kreg[cur][i];
      f.x *= rn; f.y *= rn; f.z *= rn; f.w *= rn;
      v4h h0; h0[0]=(_Float16)f.x; h0[1]=(_Float16)f.y; h0[2]=(_Float16)f.z; h0[3]=(_Float16)f.w;
      *(v4h*)(KV + key*136 + d4*4) = h0;
      if (PL == 2) {
        v4h h1; h1[0]=(_Float16)(f.x-(float)h0[0]); h1[1]=(_Float16)(f.y-(float)h0[1]);
        h1[2]=(_Float16)(f.z-(float)h0[2]); h1[3]=(_Float16)(f.w-(float)h0[3]);
        *(v4h*)(KV + Kps + key*136 + d4*4) = h1;
      }
    }
    // issue K(g+1): row ids from LDS (fast), then gathered float4
    if (g < 3) {
      #pragma unroll
      for (int i = 0; i < 4; i++) {
        int key = row0 + i*8;
        int rowid = kp_lds[(g+1)*32 + key];
        krn[cur^1][i] = rnp[kb[g+1] + key];
        kreg[cur^1][i] = *(const float4*)(qk + base + (size_t)rowid*DD + d4*4);
      }
    }
    asm volatile("s_waitcnt lgkmcnt(0)" ::: "memory"); // K(g) writes done
    __builtin_amdgcn_s_barrier();
    __builtin_amdgcn_s_setprio(1);
    #pragma unroll
    for (int ni = 0; ni < 2; ni++) {
      v4f c0 = sc[g*2 + ni];
      #pragma unroll
      for (int ks = 0; ks < 4; ks++) {
        v8h a0 = *(const v8h*)(QP + (wave*16 + lm)*136 + ks*32 + quad*8);
        v8h b0 = *(const v8h*)(KV + (ni*16 + lm)*136 + ks*32 + quad*8);
        c0 = __builtin_amdgcn_mfma_f32_16x16x32_f16(a0, b0, c0, 0, 0, 0);
        if (PL == 2) {
          v8h a1 = *(const v8h*)(QP + QPs + (wave*16 + lm)*136 + ks*32 + quad*8);
          v8h b1 = *(const v8h*)(KV + Kps + (ni*16 + lm)*136 + ks*32 + quad*8);
          c0 = __builtin_amdgcn_mfma_f32_16x16x32_f16(a0, b1, c0, 0, 0, 0);
          c0 = __builtin_amdgcn_mfma_f32_16x16x32_f16(a1, b0, c0, 0, 0, 0);
          c0 = __builtin_amdgcn_mfma_f32_16x16x32_f16(a1, b1, c0, 0, 0, 0);
        }
      }
      sc[g*2 + ni] = c0;
    }
    __builtin_amdgcn_s_setprio(0);
  }

  // issue V(0) loads NOW -- they fly under the softmax
  float4 vreg[2][4];
  #pragma unroll
  for (int i = 0; i < 4; i++) {
    int key = row0 + i*8;
    int rowid = kp_lds[key];                           // group 0 rows
    vreg[0][i] = *(const float4*)(v + base + (size_t)rowid*DD + d4*4);
  }

  __builtin_amdgcn_s_barrier();                        // score reads of QP done

  int kp_l[8];
  #pragma unroll
  for (int j = 0; j < 8; j++) kp_l[j] = kp_lds[j*16 + lm];

  // --- masked softmax per row; write scaled-split probs into QP ---
  #pragma unroll
  for (int rr = 0; rr < 4; rr++) {
    int row = wave*16 + quad*4 + rr;
    int qp = qp_lds[row];
    float sv[8];
    #pragma unroll
    for (int j = 0; j < 8; j++) {
      float s = sc[j][rr] * DSCF;
      int kp = kp_l[j];
      sv[j] = (kp > qp) ? -1000000000.0f : ((kp == qp) ? -100000.0f : s);
    }
    float m = sv[0];
    #pragma unroll
    for (int j = 1; j < 8; j++) m = fmaxf(m, sv[j]);
    #pragma unroll
    for (int o = 1; o < 16; o <<= 1) m = fmaxf(m, __shfl_xor(m, o));
    float es[8], S = 0.0f;
    #pragma unroll
    for (int j = 0; j < 8; j++) { es[j] = __expf(sv[j] - m); S += es[j]; }
    #pragma unroll
    for (int o = 1; o < 16; o <<= 1) S += __shfl_xor(S, o);
    float inv = 1.0f / S;
    if (lm == 0) lg[(size_t)bh * RS + n*64 + row] = m + __logf(S);
    #pragma unroll
    for (int j = 0; j < 8; j++) {
      float p = es[j] * inv * SCF;
      _Float16 p0 = (_Float16)p;
      QP[row*136 + j*16 + lm] = p0;
      if (PL == 2) QP[QPs + row*136 + j*16 + lm] = (_Float16)(p - (float)p0);
    }
  }

  // --- PV: 4 key-groups, V transposed into [d][key^swz] (stride 36) ---
  v4f oacc[8];
  #pragma unroll
  for (int j = 0; j < 8; j++) oacc[j] = (v4f)0.0f;
  #pragma unroll
  for (int g = 0; g < 4; g++) {
    __builtin_amdgcn_s_barrier();                      // prev V readers done
    int cur = g & 1;
    int xbs = (d4 & 7) << 2;
    // write V(g) from regs (swizzled)
    #pragma unroll
    for (int i = 0; i < 4; i++) {
      int keyS = (row0 + i*8) ^ xbs;
      float4 f = vreg[cur][i];
      float fs[4] = {f.x*SCF, f.y*SCF, f.z*SCF, f.w*SCF};
      #pragma unroll
      for (int j = 0; j < 4; j++) {
        int d = d4*4 + j;
        _Float16 p0 = (_Float16)fs[j];
        KV[d*36 + keyS] = p0;
        if (PL == 2) KV[Vps + d*36 + keyS] = (_Float16)(fs[j] - (float)p0);
      }
    }
    // issue V(g+1)
    if (g < 3) {
      #pragma unroll
      for (int i = 0; i < 4; i++) {
        int key = row0 + i*8;
        int rowid = kp_lds[(g+1)*32 + key];
        vreg[cur^1][i] = *(const float4*)(v + base + (size_t)rowid*DD + d4*4);
      }
    }
    asm volatile("s_waitcnt lgkmcnt(0)" ::: "memory"); // V(g) + P writes done
    __builtin_amdgcn_s_barrier();
    __builtin_amdgcn_s_setprio(1);
    v8h a0 = *(const v8h*)(QP + (wave*16 + lm)*136 + g*32 + quad*8);
    v8h a1;
    if (PL == 2) a1 = *(const v8h*)(QP + QPs + (wave*16 + lm)*136 + g*32 + quad*8);
    #pragma unroll
    for (int dn = 0; dn < 8; dn++) {
      int d = dn*16 + lm;
      int klo = (quad*8) ^ (((d >> 2) & 7) << 2);      // 4-aligned block
      v4h lo0 = *(const v4h*)(KV + d*36 + klo);
      v4h hi0 = *(const v4h*)(KV + d*36 + (klo ^ 4));
      v8h b0 = __builtin_shufflevector(lo0, hi0, 0,1,2,3,4,5,6,7);
      v4f c0 = oacc[dn];
      c0 = __builtin_amdgcn_mfma_f32_16x16x32_f16(a0, b0, c0, 0, 0, 0);
      if (PL == 2) {
        v4h lo1 = *(const v4h*)(KV + Vps + d*36 + klo);
        v4h hi1 = *(const v4h*)(KV + Vps + d*36 + (klo ^ 4));
        v8h b1 = __builtin_shufflevector(lo1, hi1, 0,1,2,3,4,5,6,7);
        c0 = __builtin_amdgcn_mfma_f32_16x16x32_f16(a0, b1, c0, 0, 0, 0);
        c0 = __builtin_amdgcn_mfma_f32_16x16x32_f16(a1, b0, c0, 0, 0, 0);
        c0 = __builtin_amdgcn_mfma_f32_16x16x32_f16(a1, b1, c0, 0, 0, 0);
      }
      oacc[dn] = c0;
    }
    __builtin_amdgcn_s_setprio(0);
  }

  // epilogue: O -> osort fp32
  #pragma unroll
  for (int dn = 0; dn < 8; dn++) {
    #pragma unroll
    for (int rr = 0; rr < 4; rr++) {
      int row = wave*16 + quad*4 + rr;
      osort[((size_t)bh * RS + n*64 + row) * DH + dn*16 + lm] = oacc[dn][rr] * DSCF;
    }
  }
}

// ---------------------------------------------------------------------------
// unsort + round-combine -> scaled fp16 2-plane split in h region
__global__ __launch_bounds__(256) void unsort_split_kernel(const float* __restrict__ osort,
                                                           const float* __restrict__ lg,
                                                           const int* __restrict__ undo,
                                                           _Float16* __restrict__ attn) {
  int gid = blockIdx.x * 4 + (threadIdx.x >> 6);
  int lane = threadIdx.x & 63;
  int bh = gid >> 12;
  int s = gid & (SS - 1);
  int b = bh >> 3, h = bh & 7;
  int k0 = undo[(size_t)bh * RS + s];
  int k1 = undo[(size_t)bh * RS + SS + s];
  float l0 = lg[(size_t)bh * RS + k0], l1 = lg[(size_t)bh * RS + k1];
  float m = fmaxf(l0, l1);
  float e0 = __expf(l0 - m), e1 = __expf(l1 - m);
  float inv = 1.0f / (e0 + e1);
  float w0 = e0 * inv, w1 = e1 * inv;
  const float* r0 = osort + ((size_t)bh * RS + k0) * DH;
  const float* r1 = osort + ((size_t)bh * RS + k1) * DH;
  const size_t PLN = (size_t)MROWS * DD;
  _Float16* outp = attn + ((size_t)(b * SS + s)) * DD + h * DH;
  float sA = (w0 * r0[lane]      + w1 * r1[lane])      * SCF;
  float sB = (w0 * r0[lane + 64] + w1 * r1[lane + 64]) * SCF;
  _Float16 a0 = (_Float16)sA, b0 = (_Float16)sB;
  outp[lane] = a0;                 outp[lane + 64] = b0;
  outp[PLN + lane] = (_Float16)(sA - (float)a0);
  outp[PLN + lane + 64] = (_Float16)(sB - (float)b0);
}

// ---------------------------------------------------------------------------
__global__ __launch_bounds__(256) void softmax_b_kernel(const float* __restrict__ logits,
                                                        const float* __restrict__ bout,
                                                        float* __restrict__ out) {
  int i = blockIdx.x * 256 + threadIdx.x;
  if (i >= SS * VV) return;
  int s = i / VV, vv = i - s * VV;
  float bvv = bout[vv];
  float l0 = logits[(size_t)s * VP + vv] + bvv;
  float l1 = logits[(size_t)(SS + s) * VP + vv] + bvv;
  float m = fmaxf(l0, l1);
  float e0 = __expf(l0 - m), e1 = __expf(l1 - m);
  float inv = 1.0f / (e0 + e1);
  out[(size_t)s * VV + vv] = e0 * inv;
  out[(size_t)(SS + s) * VV + vv] = e1 * inv;
}

// ---------------------------------------------------------------------------
// Workspace: extent 237,502,464 B (proven). pool[2NX..4NX) = osort region,
// time-shared: weights wt at +0, counts at +8MB, rotT at +10MB — all dead
// before attn writes osort and before FFN reuses [0,16MB).
extern "C" void kernel_launch(void* const* d_in, const int* in_sizes, int n_in,
                              void* d_out, int out_size, void* d_ws, size_t ws_size,
                              hipStream_t stream) {
  (void)in_sizes; (void)n_in; (void)out_size; (void)ws_size;
  const float* x     = (const float*)d_in[0];
  const float* ln1_g = (const float*)d_in[1];
  const float* ln1_b = (const float*)d_in[2];
  const float* Wqk   = (const float*)d_in[3];
  const float* Wv    = (const float*)d_in[4];
  const float* Wo    = (const float*)d_in[5];
  const float* rot   = (const float*)d_in[6];
  const float* ln2_g = (const float*)d_in[7];
  const float* ln2_b = (const float*)d_in[8];
  const float* W1    = (const float*)d_in[9];
  const float* b1    = (const float*)d_in[10];
  const float* W2    = (const float*)d_in[11];
  const float* b2    = (const float*)d_in[12];
  const float* lnf_g = (const float*)d_in[13];
  const float* lnf_b = (const float*)d_in[14];
  const float* Wout  = (const float*)d_in[15];
  const float* bout  = (const float*)d_in[16];

  const size_t NX = (size_t)MROWS * DD;            // 8,388,608
  float* x1 = (float*)d_ws;
  float* x2 = x1 + NX;
  float* h  = x2 + NX;
  _Float16* hs = (_Float16*)h;                     // [2][M][1024] fp16
  float* pool = h + NX;
  float* qkb   = pool;
  float* vb    = pool + NX;
  float* osort = pool + 2*NX;
  _Float16* ffh = (_Float16*)pool;                 // [2][M][2048] fp16
  _Float16* hcs = (_Float16*)pool;                 // head phase
  char* wbase = (char*)(pool + 2*NX);
  _Float16* wt = (_Float16*)wbase;                 // weight squat region
  int* counts = (int*)(wbase + (8u<<20));          // 1 MB
  _Float16* rotTs = (_Float16*)(wbase + (10u<<20));// 512 KB
  float* after = pool + 4*NX;
  float* lgb = after;
  float* rno = lgb + (size_t)BH * RS;
  int* orig = (int*)(rno + (size_t)BH * RS);
  int* undo = orig + (size_t)BH * RS;
  int* ids  = undo + (size_t)BH * RS;
  float* logitsP = h;                              // head phase

  const size_t AP_D  = NX;
  const size_t AP_FF = (size_t)MROWS * 2048;
  const size_t BP_D  = (size_t)DD * DD;
  const size_t BP_W1 = (size_t)2048 * DD;
  const size_t BP_W2 = (size_t)DD * 2048;
  const size_t BP_HD = (size_t)VP * 2048;

  init_x_kernel<<<(int)(NX / 256), 256, 0, stream>>>(x, x1, x2);

  for (int l = 0; l < LL; l++) {
    // --- attention ---
    ln_split_kernel<<<MROWS, 256, 0, stream>>>(x2, ln1_g + l*DD, ln1_b + l*DD, hs);

    wconv_kernel<<<dim3(32, 32), 256, 0, stream>>>(Wqk + (size_t)l*DD*DD, wt, DD, DD, DD, DD);
    qgemm_kernel<2,0,false,false,4><<<dim3(8, 64), 256, 0, stream>>>(
        hs, wt, nullptr, qkb, MROWS, DD, DD, AP_D, BP_D);

    wconv_kernel<<<dim3(32, 32), 256, 0, stream>>>(Wv + (size_t)l*DD*DD, wt, DD, DD, DD, DD);
    if (l == 0)
      qgemm_kernel<2,0,false,false,3><<<dim3(8, 64), 256, 0, stream>>>(
          hs, wt, nullptr, vb, MROWS, DD, DD, AP_D, BP_D);
    else
      qgemm_kernel<1,0,false,false,3><<<dim3(8, 64), 256, 0, stream>>>(
          hs, wt, nullptr, vb, MROWS, DD, DD, AP_D, BP_D);

    rott_kernel<<<dim3(8, 8), 256, 0, stream>>>(rot + (size_t)l*HH*DH*RR*64, rotTs);
    bucket_mfma_kernel<<<dim3(32, 16), 256, 0, stream>>>(qkb, rotTs, ids);

    hipMemsetAsync(counts, 0, (size_t)BH * RR * 64 * 128 * sizeof(int), stream);
    sort_count_kernel<<<512, 256, 0, stream>>>(ids, counts);
    sort_prefix_kernel<<<BH*RR, 128, 0, stream>>>(counts);
    sort_scatter_kernel<<<512, 256, 0, stream>>>(ids, counts, orig, undo);

    rnorm_kernel<<<BH*RS/4, 256, 0, stream>>>(qkb, orig, rno);
    if (l == 0)
      attn_mfma_kernel<2><<<BH*NC, 256, 0, stream>>>(qkb, vb, orig, rno, osort, lgb);
    else
      attn_mfma_kernel<1><<<BH*NC, 256, 0, stream>>>(qkb, vb, orig, rno, osort, lgb);
    unsort_split_kernel<<<BH*SS/4, 256, 0, stream>>>(osort, lgb, undo, hs);   // osort dead

    wconv_kernel<<<dim3(32, 32), 256, 0, stream>>>(Wo + (size_t)l*DD*DD, wt, DD, DD, DD, DD);
    if (l == 0)
      qgemm_kernel<2,1,false,false,3><<<dim3(8, 64), 256, 0, stream>>>(
          hs, wt, nullptr, x1, MROWS, DD, DD, AP_D, BP_D);
    else
      qgemm_kernel<1,1,false,false,3><<<dim3(8, 64), 256, 0, stream>>>(
          hs, wt, nullptr, x1, MROWS, DD, DD, AP_D, BP_D);

    // --- FFN, two FF-halves of 2048 ---
    ln_split_kernel<<<MROWS, 256, 0, stream>>>(x1, ln2_g + l*DD, ln2_b + l*DD, hs);
    for (int hf = 0; hf < 2; hf++) {
      const float* W1h = W1 + (size_t)l*DD*FFD + (size_t)hf*2048;
      const float* W2h = W2 + (size_t)l*FFD*DD + (size_t)hf*2048*DD;
      _Float16* wt1 = wt;
      _Float16* wt2 = wt + 2u*2097152u;
      wconv_kernel<<<dim3(64, 32), 256, 0, stream>>>(W1h, wt1, DD, 2048, 2048, FFD);
      wconv_kernel<<<dim3(32, 64), 256, 0, stream>>>(W2h, wt2, 2048, DD, DD, DD);
      if (l == 0) {
        qgemm_kernel<2,2,true,true,3><<<dim3(16, 64), 256, 0, stream>>>(
            hs, wt1, b1 + (size_t)l*FFD + hf*2048, ffh, MROWS, 2048, DD, AP_D, BP_W1);
        if (hf == 0)
          qgemm_kernel<2,1,true,false,3><<<dim3(8, 64), 256, 0, stream>>>(
              ffh, wt2, b2 + (size_t)l*DD, x2, MROWS, DD, 2048, AP_FF, BP_W2);
        else
          qgemm_kernel<2,1,false,false,3><<<dim3(8, 64), 256, 0, stream>>>(
              ffh, wt2, nullptr, x2, MROWS, DD, 2048, AP_FF, BP_W2);
      } else {
        qgemm_kernel<1,2,true,true,3><<<dim3(16, 64), 256, 0, stream>>>(
            hs, wt1, b1 + (size_t)l*FFD + hf*2048, ffh, MROWS, 2048, DD, AP_D, BP_W1);
        if (hf == 0)
          qgemm_kernel<1,1,true,false,3><<<dim3(8, 64), 256, 0, stream>>>(
              ffh, wt2, b2 + (size_t)l*DD, x2, MROWS, DD, 2048, AP_FF, BP_W2);
        else
          qgemm_kernel<1,1,false,false,3><<<dim3(8, 64), 256, 0, stream>>>(
              ffh, wt2, nullptr, x2, MROWS, DD, 2048, AP_FF, BP_W2);
      }
    }
  }

  // --- head ---
  ln_concat_split_kernel<<<MROWS, 256, 0, stream>>>(x1, x2, lnf_g, lnf_b, hcs);
  wconv_kernel<<<dim3(12, 64), 256, 0, stream>>>(Wout, wt, 2*DD, VV, VP, VV);
  qgemm_kernel<1,0,false,false,3><<<dim3(3, 64), 256, 0, stream>>>(
      hcs, wt, nullptr, logitsP, MROWS, VP, 2*DD, AP_FF, BP_HD);
  softmax_b_kernel<<<(SS*VV + 255)/256, 256, 0, stream>>>(logitsP, bout, (float*)d_out);
}

// Round 6
// 1666.730 us; speedup vs baseline: 1.0790x; 1.0066x over previous
//
#include <hip/hip_runtime.h>
#include <hip/hip_fp16.h>
#include <math.h>

#define BB 2
#define SS 4096
#define DD 1024
#define HH 8
#define DH 128
#define RR 2
#define CC 64
#define NBUCK 128
#define LL 2
#define FFD 4096
#define VV 258
#define VP 384            // padded vocab for head GEMM (multiple of 128)
#define RS (RR*SS)        // 8192
#define NC (RS/CC)        // 128
#define BH (BB*HH)        // 16
#define MROWS (BB*SS)     // 8192

// scale 2^8 on both operand splits; descale 2^-16 in epilogue (fp16 denorm guard)
#define SCF 256.0f
#define DSCF (1.0f/65536.0f)

typedef __attribute__((ext_vector_type(8))) _Float16 v8h;
typedef __attribute__((ext_vector_type(4))) _Float16 v4h;
typedef __attribute__((ext_vector_type(4))) float v4f;

// ---------------------------------------------------------------------------
__device__ __forceinline__ void gld16(const void* g, void* l) {
  __builtin_amdgcn_global_load_lds((const __attribute__((address_space(1))) void*)g,
                                   (__attribute__((address_space(3))) void*)l, 16, 0, 0);
}

// ---------------------------------------------------------------------------
__device__ __forceinline__ void block_sum2(float& s, float& s2) {
  #pragma unroll
  for (int o = 1; o < 64; o <<= 1) { s += __shfl_xor(s, o); s2 += __shfl_xor(s2, o); }
  __shared__ float rs[4], rq[4];
  int wave = threadIdx.x >> 6;
  if ((threadIdx.x & 63) == 0) { rs[wave] = s; rq[wave] = s2; }
  __syncthreads();
  s  = rs[0] + rs[1] + rs[2] + rs[3];
  s2 = rq[0] + rq[1] + rq[2] + rq[3];
}

// ---------------------------------------------------------------------------
__global__ __launch_bounds__(256) void init_x_kernel(const float* __restrict__ x,
                                                     float* __restrict__ x1,
                                                     float* __restrict__ x2) {
  size_t i = (size_t)blockIdx.x * 256 + threadIdx.x;
  float v = x[i];
  x1[i] = v; x2[i] = v;
}

// ---------------------------------------------------------------------------
// LayerNorm over D=1024 -> scaled fp16 2-plane split (plane stride MROWS*DD)
__global__ __launch_bounds__(256) void ln_split_kernel(const float* __restrict__ x,
                                                       const float* __restrict__ g,
                                                       const float* __restrict__ bta,
                                                       _Float16* __restrict__ out) {
  int row = blockIdx.x;
  int t = threadIdx.x;
  float4 xv = ((const float4*)(x + (size_t)row * DD))[t];
  float s  = xv.x + xv.y + xv.z + xv.w;
  float s2 = xv.x*xv.x + xv.y*xv.y + xv.z*xv.z + xv.w*xv.w;
  block_sum2(s, s2);
  float mu   = s * (1.0f / DD);
  float var  = fmaxf(s2 * (1.0f / DD) - mu * mu, 0.0f);
  float rstd = rsqrtf(var + 1e-12f);
  float4 gv = ((const float4*)g)[t];
  float4 bv = ((const float4*)bta)[t];
  float4 sv;
  sv.x = ((xv.x - mu) * rstd * gv.x + bv.x) * SCF;
  sv.y = ((xv.y - mu) * rstd * gv.y + bv.y) * SCF;
  sv.z = ((xv.z - mu) * rstd * gv.z + bv.z) * SCF;
  sv.w = ((xv.w - mu) * rstd * gv.w + bv.w) * SCF;
  v4h h0, h1;
  h0[0]=(_Float16)sv.x; h0[1]=(_Float16)sv.y; h0[2]=(_Float16)sv.z; h0[3]=(_Float16)sv.w;
  h1[0]=(_Float16)(sv.x-(float)h0[0]); h1[1]=(_Float16)(sv.y-(float)h0[1]);
  h1[2]=(_Float16)(sv.z-(float)h0[2]); h1[3]=(_Float16)(sv.w-(float)h0[3]);
  const size_t PLN = (size_t)MROWS * DD;
  size_t base = (size_t)row * DD + t * 4;
  *(v4h*)(out + base) = h0;
  *(v4h*)(out + PLN + base) = h1;
}

// LayerNorm over concat([x1,x2]) (2048) -> scaled fp16 single plane
// (head GEMM is PL=1: plane-1 stores were dead, dropped)
__global__ __launch_bounds__(256) void ln_concat_split_kernel(const float* __restrict__ x1,
                                                              const float* __restrict__ x2,
                                                              const float* __restrict__ g,
                                                              const float* __restrict__ bta,
                                                              _Float16* __restrict__ out) {
  int row = blockIdx.x;
  int t = threadIdx.x;
  float4 a = ((const float4*)(x1 + (size_t)row * DD))[t];
  float4 b = ((const float4*)(x2 + (size_t)row * DD))[t];
  float s  = a.x + a.y + a.z + a.w + b.x + b.y + b.z + b.w;
  float s2 = a.x*a.x + a.y*a.y + a.z*a.z + a.w*a.w
           + b.x*b.x + b.y*b.y + b.z*b.z + b.w*b.w;
  block_sum2(s, s2);
  float mu   = s * (1.0f / (2*DD));
  float var  = fmaxf(s2 * (1.0f / (2*DD)) - mu * mu, 0.0f);
  float rstd = rsqrtf(var + 1e-12f);
  float4 g1 = ((const float4*)g)[t];
  float4 b1v = ((const float4*)bta)[t];
  float4 g2 = ((const float4*)g)[256 + t];
  float4 b2v = ((const float4*)bta)[256 + t];
  float4 s1, s2v;
  s1.x = ((a.x-mu)*rstd*g1.x + b1v.x)*SCF;  s1.y = ((a.y-mu)*rstd*g1.y + b1v.y)*SCF;
  s1.z = ((a.z-mu)*rstd*g1.z + b1v.z)*SCF;  s1.w = ((a.w-mu)*rstd*g1.w + b1v.w)*SCF;
  s2v.x = ((b.x-mu)*rstd*g2.x + b2v.x)*SCF; s2v.y = ((b.y-mu)*rstd*g2.y + b2v.y)*SCF;
  s2v.z = ((b.z-mu)*rstd*g2.z + b2v.z)*SCF; s2v.w = ((b.w-mu)*rstd*g2.w + b2v.w)*SCF;
  v4h h0;
  size_t base = (size_t)row * (2*DD) + t * 4;
  h0[0]=(_Float16)s1.x; h0[1]=(_Float16)s1.y; h0[2]=(_Float16)s1.z; h0[3]=(_Float16)s1.w;
  *(v4h*)(out + base) = h0;
  h0[0]=(_Float16)s2v.x; h0[1]=(_Float16)s2v.y; h0[2]=(_Float16)s2v.z; h0[3]=(_Float16)s2v.w;
  *(v4h*)(out + base + DD) = h0;
}

// ---------------------------------------------------------------------------
// weight convert fp32 W[K][·] (row stride ldw) cols [0,N) -> scaled fp16
// 2-plane split Wt[2][Npad][K] (zero pad n>=N)
__global__ __launch_bounds__(256) void wconv_kernel(const float* __restrict__ W,
                                                    _Float16* __restrict__ Wt,
                                                    int K, int N, int Npad, int ldw) {
  __shared__ float tile[32][33];
  int n0 = blockIdx.x * 32, k0 = blockIdx.y * 32;
  int tid = threadIdx.x;
  #pragma unroll
  for (int i = 0; i < 4; i++) {
    int idx = i*256 + tid;
    int kk = idx >> 5, nn = idx & 31;
    float v = 0.0f;
    if (n0 + nn < N) v = W[(size_t)(k0 + kk) * ldw + n0 + nn];
    tile[kk][nn] = v;
  }
  __syncthreads();
  size_t NKs = (size_t)Npad * K;
  #pragma unroll
  for (int i = 0; i < 4; i++) {
    int idx = i*256 + tid;
    int nn = idx >> 5, kk = idx & 31;
    float s = tile[kk][nn] * SCF;
    size_t off = (size_t)(n0 + nn) * K + k0 + kk;
    _Float16 h0 = (_Float16)s;
    _Float16 h1 = (_Float16)(s - (float)h0);
    Wt[off] = h0;
    Wt[NKs + off] = h1;
  }
}

// ---------------------------------------------------------------------------
// fp16x2 MFMA GEMM, counted-vmcnt pipeline (T3+T4) + T2 XOR-swizzled LDS.
// PL=2: split (fp32-equivalent); PL=1: single. NP=4 full QUAD for discrete
// consumers (bucket argmax via Wqk); NP=3 drops a1*b1 (~2^-22 rel) elsewhere.
//
// T2 swizzle (rule #21: both-sides-or-neither with global_load_lds):
// LDS dest stays linear (lane*16); the GLOBAL source column is pre-swizzled
// so LDS[row][slot] holds global half-block (slot ^ ((row>>1)&3)). The
// fragment read mirrors it: offset (quad ^ ((lm>>1)&3))*8. Bank check:
// per 16-lane phase, banks = 16*(l&1) + 4*((l>>1)&3) -> 2 lanes/bank =
// minimum (was 8 banks @ 4x extra cycles; SQ_LDS_BANK_CONFLICT 2^23/disp).
//
// Loop: vmcnt(NCH) [counted, never 0 mid-loop] -> bar -> ds_read frags ->
// MFMA (compiler's fine lgkm waits; starts as frags arrive) -> lgkm0 ->
// bar -> stage(t+2 -> cur). Numerics bit-identical.
// CMODE: 0 store f32, 1 accumulate f32, 2 split-store fp16 2-plane.
template<int PL, int CMODE, bool BIAS, bool RELU, int NP>
__global__ __launch_bounds__(256) void qgemm_kernel(const _Float16* __restrict__ A,
                                                    const _Float16* __restrict__ Bt,
                                                    const float* __restrict__ bias,
                                                    void* __restrict__ Cv,
                                                    int M, int N, int K,
                                                    size_t aplane, size_t bplane) {
  __shared__ __align__(16) _Float16 As[2][PL*128*32];
  __shared__ __align__(16) _Float16 Bs[2][PL*128*32];
  int tid = threadIdx.x, lane = tid & 63, wave = tid >> 6;
  int m0 = blockIdx.y * 128, n0 = blockIdx.x * 128;
  int wm = (wave & 1) * 64, wn = (wave >> 1) * 64;
  int lm = lane & 15, quad = lane >> 4;
  const int NCH = (PL == 2) ? 8 : 4;
  const int ACH = (PL == 2) ? 16 : 8;
  v4f acc[4][4];
  #pragma unroll
  for (int i = 0; i < 4; i++)
    #pragma unroll
    for (int j = 0; j < 4; j++) acc[i][j] = (v4f)0.0f;

  // source-column swizzle: (lane>>3)&3 == (row>>1)&3 for row = q*16+(lane>>2)
  auto stage = [&](int k0, int bufi) {
    int sl = (lane >> 3) & 3;
    int col = ((lane & 3) ^ sl) * 8;
    #pragma unroll
    for (int i = 0; i < NCH; i++) {
      int c = wave * NCH + i;
      if (c < ACH) {
        int p = c >> 3, q = c & 7;
        int row = q * 16 + (lane >> 2);
        gld16(A + (size_t)p * aplane + (size_t)(m0 + row) * K + k0 + col,
              (char*)As[bufi] + (size_t)c * 1024);
      } else {
        int cb = c - ACH;
        int p = cb >> 3, q = cb & 7;
        int row = q * 16 + (lane >> 2);
        gld16(Bt + (size_t)p * bplane + (size_t)(n0 + row) * K + k0 + col,
              (char*)Bs[bufi] + (size_t)cb * 1024);
      }
    }
  };

  const int nsteps = K >> 5;   // >= 32 for all launches
  stage(0, 0);
  stage(32, 1);

  int swl = (lm >> 1) & 3;     // read-side mirror of the source swizzle

  for (int t = 0; t < nsteps; ++t) {
    int cur = t & 1;
    // wait for stage(t) only; stage(t+1)'s NCH loads remain in flight
    if (t + 1 < nsteps) {
      if (PL == 2) asm volatile("s_waitcnt vmcnt(8)" ::: "memory");
      else         asm volatile("s_waitcnt vmcnt(4)" ::: "memory");
    } else {
      asm volatile("s_waitcnt vmcnt(0)" ::: "memory");
    }
    __builtin_amdgcn_s_barrier();

    const _Float16* Ab = As[cur];
    const _Float16* Bb = Bs[cur];
    v8h a[4][2], b[4][2];
    #pragma unroll
    for (int ni = 0; ni < 4; ni++) {
      int boff = (wn + ni*16 + lm) * 32 + (quad ^ swl) * 8;
      b[ni][0] = *(const v8h*)&Bb[boff];
      if (PL == 2) b[ni][1] = *(const v8h*)&Bb[4096 + boff];
    }
    #pragma unroll
    for (int mi = 0; mi < 4; mi++) {
      int aoff = (wm + mi*16 + lm) * 32 + (quad ^ swl) * 8;
      a[mi][0] = *(const v8h*)&Ab[aoff];
      if (PL == 2) a[mi][1] = *(const v8h*)&Ab[4096 + aoff];
    }

    // MFMAs start as fragments arrive (compiler fine-grained lgkmcnt)
    #pragma unroll
    for (int mi = 0; mi < 4; mi++) {
      #pragma unroll
      for (int ni = 0; ni < 4; ni++) {
        v4f c0 = acc[mi][ni];
        c0 = __builtin_amdgcn_mfma_f32_16x16x32_f16(a[mi][0], b[ni][0], c0, 0, 0, 0);
        if (PL == 2) {
          c0 = __builtin_amdgcn_mfma_f32_16x16x32_f16(a[mi][0], b[ni][1], c0, 0, 0, 0);
          c0 = __builtin_amdgcn_mfma_f32_16x16x32_f16(a[mi][1], b[ni][0], c0, 0, 0, 0);
          if (NP == 4)
            c0 = __builtin_amdgcn_mfma_f32_16x16x32_f16(a[mi][1], b[ni][1], c0, 0, 0, 0);
        }
        acc[mi][ni] = c0;
      }
    }

    asm volatile("s_waitcnt lgkmcnt(0)" ::: "memory");  // all my reads executed
    __builtin_amdgcn_s_barrier();                       // all waves done with buf[cur]
    if (t + 2 < nsteps) stage((t + 2) << 5, cur);       // refill; flies under next step
  }

  float* Cf = (float*)Cv;
  _Float16* Ch = (_Float16*)Cv;
  const size_t cplane = (size_t)M * N;
  #pragma unroll
  for (int mi = 0; mi < 4; mi++) {
    int rbase = m0 + wm + mi*16 + quad*4;
    #pragma unroll
    for (int ni = 0; ni < 4; ni++) {
      int col = n0 + wn + ni*16 + lm;
      float bv = BIAS ? bias[col] : 0.0f;
      #pragma unroll
      for (int r = 0; r < 4; r++) {
        float val = acc[mi][ni][r] * DSCF + bv;
        if (RELU) val = fmaxf(val, 0.0f);
        size_t off = (size_t)(rbase + r) * N + col;
        if (CMODE == 0) Cf[off] = val;
        else if (CMODE == 1) Cf[off] += val;
        else {
          float s = val * SCF;
          _Float16 h0 = (_Float16)s;
          _Float16 h1 = (_Float16)(s - (float)h0);
          Ch[off] = h0;
          Ch[cplane + off] = h1;
        }
      }
    }
  }
}

// ---------------------------------------------------------------------------
// rot[h][d][r][n] -> rotT[h][2 planes][rcol=r*64+n][d] scaled fp16 split
__global__ __launch_bounds__(256) void rott_kernel(const float* __restrict__ rot,
                                                   _Float16* __restrict__ rotT) {
  int h = blockIdx.x, grp = blockIdx.y;    // dim3(8,8)
  const float* rh = rot + (size_t)h * (DH * RR * 64);
  for (int idx = threadIdx.x; idx < 16*128; idx += 256) {
    int rc = grp*16 + (idx >> 7), d = idx & 127;
    int r = rc >> 6, nn = rc & 63;
    float f = rh[(size_t)d * 128 + r * 64 + nn] * SCF;
    _Float16 h0 = (_Float16)f;
    rotT[(size_t)h*32768 + (size_t)rc*128 + d] = h0;
    rotT[(size_t)h*32768 + 16384 + (size_t)rc*128 + d] = (_Float16)(f - (float)h0);
  }
}

// ---------------------------------------------------------------------------
// bucket via MFMA: rotated = qk_head @ rotT^T, fused argmax epilogue.
// A: qkb fp32 (in-register QUAD split, R4-verified XOR-swizzle staging).
// B staging/reads use the same T2 source-swizzle as qgemm (bank-conflict-free).
// Each wave's 64 cols = one full hash round -> per-wave argmax, no combine.
// Kept at full 4-product QUAD: feeds discrete argmax (bucket assignment).
__global__ __launch_bounds__(256) void bucket_mfma_kernel(const float* __restrict__ qkb,
                                                          const _Float16* __restrict__ rotT,
                                                          int* __restrict__ ids) {
  __shared__ __align__(16) float Af[128*32];          // 16 KB XOR-swizzled
  __shared__ __align__(16) _Float16 Bs[2*128*32];     // 16 KB
  int mtile = blockIdx.x, bh = blockIdx.y;
  int b = bh >> 3, h = bh & 7;
  int tid = threadIdx.x, lane = tid & 63, wave = tid >> 6;
  int wm = (wave & 1) * 64;
  int r = wave >> 1;                                   // round handled by this wave
  int wn = r * 64;
  int lm = lane & 15, quad = lane >> 4;
  const float* Aq = qkb + ((size_t)b * SS + (size_t)mtile * 128) * DD + h * DH;
  const _Float16* Bq = rotT + (size_t)h * 32768;
  int swl = (lm >> 1) & 3;
  v4f acc[4][4];
  #pragma unroll
  for (int i = 0; i < 4; i++)
    #pragma unroll
    for (int j = 0; j < 4; j++) acc[i][j] = (v4f)0.0f;

  for (int k0 = 0; k0 < 128; k0 += 32) {
    #pragma unroll
    for (int i = 0; i < 8; i++) {
      int c = wave * 8 + i;
      if (c < 16) {
        int slot = c * 64 + lane;
        int row = slot >> 3;
        int c4 = (slot & 7) ^ (row & 7);
        gld16(Aq + (size_t)row * DD + k0 + c4 * 4, (char*)Af + (size_t)c * 1024);
      } else {
        int cb = c - 16;
        int p = cb >> 3, q = cb & 7;
        int row = q * 16 + (lane >> 2);
        int col = ((lane & 3) ^ ((lane >> 3) & 3)) * 8;
        gld16(Bq + (size_t)p * 16384 + (size_t)row * 128 + k0 + col,
              (char*)Bs + (size_t)p * 8192 + (size_t)q * 1024);
      }
    }
    __syncthreads();
    v8h b0[4], b1[4];
    #pragma unroll
    for (int ni = 0; ni < 4; ni++) {
      int boff = (wn + ni*16 + lm) * 32 + (quad ^ swl) * 8;
      b0[ni] = *(const v8h*)&Bs[boff];
      b1[ni] = *(const v8h*)&Bs[4096 + boff];
    }
    #pragma unroll
    for (int mi = 0; mi < 4; mi++) {
      int arow = wm + mi*16 + lm;
      int sw = arow & 7;
      float4 fA = *(const float4*)(Af + arow*32 + (((2*quad)     ^ sw) << 2));
      float4 fB = *(const float4*)(Af + arow*32 + (((2*quad + 1) ^ sw) << 2));
      v8h a0, a1;
      float fs[8] = {fA.x*SCF, fA.y*SCF, fA.z*SCF, fA.w*SCF,
                     fB.x*SCF, fB.y*SCF, fB.z*SCF, fB.w*SCF};
      #pragma unroll
      for (int j = 0; j < 8; j++) {
        _Float16 p0 = (_Float16)fs[j];
        a0[j] = p0;
        a1[j] = (_Float16)(fs[j] - (float)p0);
      }
      #pragma unroll
      for (int ni = 0; ni < 4; ni++) {
        v4f c0 = acc[mi][ni];
        c0 = __builtin_amdgcn_mfma_f32_16x16x32_f16(a0, b0[ni], c0, 0, 0, 0);
        c0 = __builtin_amdgcn_mfma_f32_16x16x32_f16(a0, b1[ni], c0, 0, 0, 0);
        c0 = __builtin_amdgcn_mfma_f32_16x16x32_f16(a1, b0[ni], c0, 0, 0, 0);
        c0 = __builtin_amdgcn_mfma_f32_16x16x32_f16(a1, b1[ni], c0, 0, 0, 0);
        acc[mi][ni] = c0;
      }
    }
    __syncthreads();
  }

  // argmax epilogue (scaled values; comparisons scale-invariant)
  #pragma unroll
  for (int mi = 0; mi < 4; mi++) {
    #pragma unroll
    for (int rr = 0; rr < 4; rr++) {
      float mx = acc[mi][0][rr]; int xi = lm;
      float mn = acc[mi][0][rr]; int ni_ = lm;
      #pragma unroll
      for (int ni = 1; ni < 4; ni++) {
        float vv = acc[mi][ni][rr];
        int col = ni*16 + lm;
        if (vv > mx) { mx = vv; xi = col; }
        if (vv < mn) { mn = vv; ni_ = col; }
      }
      #pragma unroll
      for (int o = 1; o < 16; o <<= 1) {
        float ox = __shfl_xor(mx, o); int oxi = __shfl_xor(xi, o);
        if (ox > mx || (ox == mx && oxi < xi)) { mx = ox; xi = oxi; }
        float on = __shfl_xor(mn, o); int oni = __shfl_xor(ni_, o);
        if (on < mn || (on == mn && oni < ni_)) { mn = on; ni_ = oni; }
      }
      if (lm == 0) {
        int bi = (mx >= -mn) ? xi : 64 + ni_;
        int s = mtile*128 + wm + mi*16 + quad*4 + rr;
        ids[((size_t)bh * RR + r) * SS + s] = bi + r * NBUCK;
      }
    }
  }
}

// ---------------------------------------------------------------------------
// Parallel stable counting sort (R5-verified, bit-exact vs argsort)
__global__ __launch_bounds__(256) void sort_count_kernel(const int* __restrict__ ids,
                                                         int* __restrict__ counts) {
  int w = blockIdx.x * 4 + (threadIdx.x >> 6);
  int lane = threadIdx.x & 63;
  int bhr = w >> 6, seg = w & 63;
  int id = ids[(size_t)bhr * SS + seg * 64 + lane];
  int bin = id & 127;
  unsigned long long eq = ~0ull;
  #pragma unroll
  for (int bit = 0; bit < 7; bit++) {
    unsigned long long bal = __ballot((bin >> bit) & 1);
    eq &= ((bin >> bit) & 1) ? bal : ~bal;
  }
  int rank = __popcll(eq & ((1ull << lane) - 1ull));
  if (rank == 0)
    counts[((size_t)bhr * 64 + seg) * 128 + bin] = __popcll(eq);
}

__global__ __launch_bounds__(128) void sort_prefix_kernel(int* __restrict__ counts) {
  int bhr = blockIdx.x;
  int bin = threadIdx.x;
  int r = bhr & 1;
  int* cp = counts + (size_t)bhr * 64 * 128;
  int total = 0;
  for (int seg = 0; seg < 64; seg++) total += cp[seg * 128 + bin];
  __shared__ int tot[128];
  tot[bin] = total;
  __syncthreads();
  for (int off = 1; off < 128; off <<= 1) {
    int t = (bin >= off) ? tot[bin - off] : 0;
    __syncthreads();
    tot[bin] += t;
    __syncthreads();
  }
  int run = tot[bin] - total + r * SS;
  for (int seg = 0; seg < 64; seg++) {
    int c = cp[seg * 128 + bin];
    cp[seg * 128 + bin] = run;
    run += c;
  }
}

__global__ __launch_bounds__(256) void sort_scatter_kernel(const int* __restrict__ ids,
                                                           const int* __restrict__ offs,
                                                           int* __restrict__ orig,
                                                           int* __restrict__ undo) {
  int w = blockIdx.x * 4 + (threadIdx.x >> 6);
  int lane = threadIdx.x & 63;
  int bhr = w >> 6, seg = w & 63;
  int s = seg * 64 + lane;
  int id = ids[(size_t)bhr * SS + s];
  int bin = id & 127;
  unsigned long long eq = ~0ull;
  #pragma unroll
  for (int bit = 0; bit < 7; bit++) {
    unsigned long long bal = __ballot((bin >> bit) & 1);
    eq &= ((bin >> bit) & 1) ? bal : ~bal;
  }
  int rank = __popcll(eq & ((1ull << lane) - 1ull));
  int o = offs[((size_t)bhr * 64 + seg) * 128 + bin] + rank;
  int bh = bhr >> 1, r = bhr & 1;
  orig[(size_t)bh * RS + o] = s;
  undo[(size_t)bh * RS + r * SS + s] = o;
}

// ---------------------------------------------------------------------------
__global__ __launch_bounds__(256) void rnorm_kernel(const float* __restrict__ qk,
                                                    const int* __restrict__ orig,
                                                    float* __restrict__ rno) {
  int idx = blockIdx.x * 4 + (threadIdx.x >> 6);
  int lane = threadIdx.x & 63;
  int bh = idx >> 13;
  int k = idx & (RS - 1);
  int b = bh >> 3, h = bh & 7;
  int s = orig[(size_t)bh * RS + k];
  const float* row = qk + ((size_t)(b * SS + s)) * DD + h * DH;
  float x0 = row[lane], x1 = row[lane + 64];
  float ss = x0 * x0 + x1 * x1;
  #pragma unroll
  for (int o = 1; o < 64; o <<= 1) ss += __shfl_xor(ss, o);
  if (lane == 0)
    rno[(size_t)bh * RS + k] = rsqrtf(ss * (1.0f / DH) + 1e-6f) * 0.08838834764831845f;
}

// ---------------------------------------------------------------------------
// MFMA chunked attention, T14 async-stage version (raw s_barrier, no vmcnt
// drain at barriers). Q/K/V gathered fp32 -> scaled fp16 PL-plane split.
// PL=2 (layer 0): fp32-equivalent QUAD; PL=1 (layer 1): single product.
// Per phase: [bar] write(cur from regs) + issue loads(next) [lgkm0][bar] MFMA.
// K/V row ids come from kp_lds (staged) -> short issue chains.
// V layout XOR-swizzled: KV[d*36 + (key ^ ((d>>2 &7)<<2))]; reads mirror it
// (4-aligned key blocks preserved) -> store conflicts 16-way -> ~4-way.
template<int PL>
__global__ __launch_bounds__(256) void attn_mfma_kernel(const float* __restrict__ qk,
                                                        const float* __restrict__ v,
                                                        const int* __restrict__ orig,
                                                        const float* __restrict__ rno,
                                                        float* __restrict__ osort,
                                                        float* __restrict__ lg) {
  constexpr int QPs = 64*136, Kps = 32*136, Vps = 128*36;
  constexpr size_t QPB = (size_t)PL * QPs * 2;       // Q/P region bytes
  constexpr size_t KVB = (size_t)PL * Vps * 2;       // K/V region bytes (V is larger)
  __shared__ __align__(16) char smem[QPB + KVB + 1024];
  _Float16* QP = (_Float16*)smem;                     // [PL][64][136]
  _Float16* KV = (_Float16*)(smem + QPB);             // K: [PL][32][136] / V: [PL][128][36]
  int* kp_lds = (int*)(smem + QPB + KVB);
  int* qp_lds = kp_lds + 128;

  int blk = blockIdx.x;
  int n = blk & (NC - 1), bh = blk >> 7;
  int b = bh >> 3, h = bh & 7;
  int pn = (n + NC - 1) & (NC - 1);
  int tid = threadIdx.x, lane = tid & 63, wave = tid >> 6;
  int lm = lane & 15, quad = lane >> 4;
  const int* origp = orig + (size_t)bh * RS;
  const float* rnp = rno + (size_t)bh * RS;
  const size_t base = (size_t)b * SS * DD + (size_t)h * DH;

  // per-thread staging geometry: fixed d4 column, 8-strided rows
  int d4 = tid & 31;
  int row0 = tid >> 5;                                 // 0..7
  // key base (sorted-index space) per group g
  int kb[4] = {pn*64, pn*64 + 32, n*64, n*64 + 32};

  // ---- prologue: issue Q loads + K(0) loads; stage kp/qp ids ----
  float4 qreg[8];
  #pragma unroll
  for (int i = 0; i < 8; i++)
    qreg[i] = *(const float4*)(qk + base + (size_t)origp[n*64 + row0 + i*8]*DD + d4*4);

  float4 kreg[2][4]; float krn[2][4];
  #pragma unroll
  for (int i = 0; i < 4; i++) {
    int key = row0 + i*8;
    krn[0][i] = rnp[kb[0] + key];
    kreg[0][i] = *(const float4*)(qk + base + (size_t)origp[kb[0] + key]*DD + d4*4);
  }

  if (tid < 128) kp_lds[tid] = origp[(tid < 64) ? (pn*64 + tid) : (n*64 + tid - 64)];
  else if (tid < 192) qp_lds[tid - 128] = origp[n*64 + tid - 128];

  // write Q (waits only the Q loads; K0 stays in flight)
  #pragma unroll
  for (int i = 0; i < 8; i++) {
    int q = row0 + i*8;
    float4 f = qreg[i];
    f.x *= SCF; f.y *= SCF; f.z *= SCF; f.w *= SCF;
    v4h h0; h0[0]=(_Float16)f.x; h0[1]=(_Float16)f.y; h0[2]=(_Float16)f.z; h0[3]=(_Float16)f.w;
    *(v4h*)(QP + q*136 + d4*4) = h0;
    if (PL == 2) {
      v4h h1; h1[0]=(_Float16)(f.x-(float)h0[0]); h1[1]=(_Float16)(f.y-(float)h0[1]);
      h1[2]=(_Float16)(f.z-(float)h0[2]); h1[3]=(_Float16)(f.w-(float)h0[3]);
      *(v4h*)(QP + QPs + q*136 + d4*4) = h1;
    }
  }
  asm volatile("s_waitcnt lgkmcnt(0)" ::: "memory");   // publish Q + kp/qp ids

  v4f sc[8];
  #pragma unroll
  for (int j = 0; j < 8; j++) sc[j] = (v4f)0.0f;

  // --- scores: 4 key-groups of 32, software-pipelined ---
  #pragma unroll
  for (int g = 0; g < 4; g++) {
    __builtin_amdgcn_s_barrier();                      // prev readers done / pub
    int cur = g & 1;
    // write K(g) from regs
    #pragma unroll
    for (int i = 0; i < 4; i++) {
      int key = row0 + i*8;
      float rn = krn[cur][i] * SCF;
      float4 f = kreg[cur][i];
      f.x *= rn; f.y *= rn; f.z *= rn; f.w *= rn;
      v4h h0; h0[0]=(_Float16)f.x; h0[1]=(_Float16)f.y; h0[2]=(_Float16)f.z; h0[3]=(_Float16)f.w;
      *(v4h*)(KV + key*136 + d4*4) = h0;
      if (PL == 2) {
        v4h h1; h1[0]=(_Float16)(f.x-(float)h0[0]); h1[1]=(_Float16)(f.y-(float)h0[1]);
        h1[2]=(_Float16)(f.z-(float)h0[2]); h1[3]=(_Float16)(f.w-(float)h0[3]);
        *(v4h*)(KV + Kps + key*136 + d4*4) = h1;
      }
    }
    // issue K(g+1): row ids from LDS (fast), then gathered float4
    if (g < 3) {
      #pragma unroll
      for (int i = 0; i < 4; i++) {
        int key = row0 + i*8;
        int rowid = kp_lds[(g+1)*32 + key];
        krn[cur^1][i] = rnp[kb[g+1] + key];
        kreg[cur^1][i] = *(const float4*)(qk + base + (size_t)rowid*DD + d4*4);
      }
    }
    asm volatile("s_waitcnt lgkmcnt(0)" ::: "memory"); // K(g) writes done
    __builtin_amdgcn_s_barrier();
    __builtin_amdgcn_s_setprio(1);
    #pragma unroll
    for (int ni = 0; ni < 2; ni++) {
      v4f c0 = sc[g*2 + ni];
      #pragma unroll
      for (int ks = 0; ks < 4; ks++) {
        v8h a0 = *(const v8h*)(QP + (wave*16 + lm)*136 + ks*32 + quad*8);
        v8h b0 = *(const v8h*)(KV + (ni*16 + lm)*136 + ks*32 + quad*8);
        c0 = __builtin_amdgcn_mfma_f32_16x16x32_f16(a0, b0, c0, 0, 0, 0);
        if (PL == 2) {
          v8h a1 = *(const v8h*)(QP + QPs + (wave*16 + lm)*136 + ks*32 + quad*8);
          v8h b1 = *(const v8h*)(KV + Kps + (ni*16 + lm)*136 + ks*32 + quad*8);
          c0 = __builtin_amdgcn_mfma_f32_16x16x32_f16(a0, b1, c0, 0, 0, 0);
          c0 = __builtin_amdgcn_mfma_f32_16x16x32_f16(a1, b0, c0, 0, 0, 0);
          c0 = __builtin_amdgcn_mfma_f32_16x16x32_f16(a1, b1, c0, 0, 0, 0);
        }
      }
      sc[g*2 + ni] = c0;
    }
    __builtin_amdgcn_s_setprio(0);
  }

  // issue V(0) loads NOW -- they fly under the softmax
  float4 vreg[2][4];
  #pragma unroll
  for (int i = 0; i < 4; i++) {
    int key = row0 + i*8;
    int rowid = kp_lds[key];                           // group 0 rows
    vreg[0][i] = *(const float4*)(v + base + (size_t)rowid*DD + d4*4);
  }

  __builtin_amdgcn_s_barrier();                        // score reads of QP done

  int kp_l[8];
  #pragma unroll
  for (int j = 0; j < 8; j++) kp_l[j] = kp_lds[j*16 + lm];

  // --- masked softmax per row; write scaled-split probs into QP ---
  #pragma unroll
  for (int rr = 0; rr < 4; rr++) {
    int row = wave*16 + quad*4 + rr;
    int qp = qp_lds[row];
    float sv[8];
    #pragma unroll
    for (int j = 0; j < 8; j++) {
      float s = sc[j][rr] * DSCF;
      int kp = kp_l[j];
      sv[j] = (kp > qp) ? -1000000000.0f : ((kp == qp) ? -100000.0f : s);
    }
    float m = sv[0];
    #pragma unroll
    for (int j = 1; j < 8; j++) m = fmaxf(m, sv[j]);
    #pragma unroll
    for (int o = 1; o < 16; o <<= 1) m = fmaxf(m, __shfl_xor(m, o));
    float es[8], S = 0.0f;
    #pragma unroll
    for (int j = 0; j < 8; j++) { es[j] = __expf(sv[j] - m); S += es[j]; }
    #pragma unroll
    for (int o = 1; o < 16; o <<= 1) S += __shfl_xor(S, o);
    float inv = 1.0f / S;
    if (lm == 0) lg[(size_t)bh * RS + n*64 + row] = m + __logf(S);
    #pragma unroll
    for (int j = 0; j < 8; j++) {
      float p = es[j] * inv * SCF;
      _Float16 p0 = (_Float16)p;
      QP[row*136 + j*16 + lm] = p0;
      if (PL == 2) QP[QPs + row*136 + j*16 + lm] = (_Float16)(p - (float)p0);
    }
  }

  // --- PV: 4 key-groups, V transposed into [d][key^swz] (stride 36) ---
  v4f oacc[8];
  #pragma unroll
  for (int j = 0; j < 8; j++) oacc[j] = (v4f)0.0f;
  #pragma unroll
  for (int g = 0; g < 4; g++) {
    __builtin_amdgcn_s_barrier();                      // prev V readers done
    int cur = g & 1;
    int xbs = (d4 & 7) << 2;
    // write V(g) from regs (swizzled)
    #pragma unroll
    for (int i = 0; i < 4; i++) {
      int keyS = (row0 + i*8) ^ xbs;
      float4 f = vreg[cur][i];
      float fs[4] = {f.x*SCF, f.y*SCF, f.z*SCF, f.w*SCF};
      #pragma unroll
      for (int j = 0; j < 4; j++) {
        int d = d4*4 + j;
        _Float16 p0 = (_Float16)fs[j];
        KV[d*36 + keyS] = p0;
        if (PL == 2) KV[Vps + d*36 + keyS] = (_Float16)(fs[j] - (float)p0);
      }
    }
    // issue V(g+1)
    if (g < 3) {
      #pragma unroll
      for (int i = 0; i < 4; i++) {
        int key = row0 + i*8;
        int rowid = kp_lds[(g+1)*32 + key];
        vreg[cur^1][i] = *(const float4*)(v + base + (size_t)rowid*DD + d4*4);
      }
    }
    asm volatile("s_waitcnt lgkmcnt(0)" ::: "memory"); // V(g) + P writes done
    __builtin_amdgcn_s_barrier();
    __builtin_amdgcn_s_setprio(1);
    v8h a0 = *(const v8h*)(QP + (wave*16 + lm)*136 + g*32 + quad*8);
    v8h a1;
    if (PL == 2) a1 = *(const v8h*)(QP + QPs + (wave*16 + lm)*136 + g*32 + quad*8);
    #pragma unroll
    for (int dn = 0; dn < 8; dn++) {
      int d = dn*16 + lm;
      int klo = (quad*8) ^ (((d >> 2) & 7) << 2);      // 4-aligned block
      v4h lo0 = *(const v4h*)(KV + d*36 + klo);
      v4h hi0 = *(const v4h*)(KV + d*36 + (klo ^ 4));
      v8h b0 = __builtin_shufflevector(lo0, hi0, 0,1,2,3,4,5,6,7);
      v4f c0 = oacc[dn];
      c0 = __builtin_amdgcn_mfma_f32_16x16x32_f16(a0, b0, c0, 0, 0, 0);
      if (PL == 2) {
        v4h lo1 = *(const v4h*)(KV + Vps + d*36 + klo);
        v4h hi1 = *(const v4h*)(KV + Vps + d*36 + (klo ^ 4));
        v8h b1 = __builtin_shufflevector(lo1, hi1, 0,1,2,3,4,5,6,7);
        c0 = __builtin_amdgcn_mfma_f32_16x16x32_f16(a0, b1, c0, 0, 0, 0);
        c0 = __builtin_amdgcn_mfma_f32_16x16x32_f16(a1, b0, c0, 0, 0, 0);
        c0 = __builtin_amdgcn_mfma_f32_16x16x32_f16(a1, b1, c0, 0, 0, 0);
      }
      oacc[dn] = c0;
    }
    __builtin_amdgcn_s_setprio(0);
  }

  // epilogue: O -> osort fp32
  #pragma unroll
  for (int dn = 0; dn < 8; dn++) {
    #pragma unroll
    for (int rr = 0; rr < 4; rr++) {
      int row = wave*16 + quad*4 + rr;
      osort[((size_t)bh * RS + n*64 + row) * DH + dn*16 + lm] = oacc[dn][rr] * DSCF;
    }
  }
}

// ---------------------------------------------------------------------------
// unsort + round-combine -> scaled fp16 2-plane split in h region
__global__ __launch_bounds__(256) void unsort_split_kernel(const float* __restrict__ osort,
                                                           const float* __restrict__ lg,
                                                           const int* __restrict__ undo,
                                                           _Float16* __restrict__ attn) {
  int gid = blockIdx.x * 4 + (threadIdx.x >> 6);
  int lane = threadIdx.x & 63;
  int bh = gid >> 12;
  int s = gid & (SS - 1);
  int b = bh >> 3, h = bh & 7;
  int k0 = undo[(size_t)bh * RS + s];
  int k1 = undo[(size_t)bh * RS + SS + s];
  float l0 = lg[(size_t)bh * RS + k0], l1 = lg[(size_t)bh * RS + k1];
  float m = fmaxf(l0, l1);
  float e0 = __expf(l0 - m), e1 = __expf(l1 - m);
  float inv = 1.0f / (e0 + e1);
  float w0 = e0 * inv, w1 = e1 * inv;
  const float* r0 = osort + ((size_t)bh * RS + k0) * DH;
  const float* r1 = osort + ((size_t)bh * RS + k1) * DH;
  const size_t PLN = (size_t)MROWS * DD;
  _Float16* outp = attn + ((size_t)(b * SS + s)) * DD + h * DH;
  float sA = (w0 * r0[lane]      + w1 * r1[lane])      * SCF;
  float sB = (w0 * r0[lane + 64] + w1 * r1[lane + 64]) * SCF;
  _Float16 a0 = (_Float16)sA, b0 = (_Float16)sB;
  outp[lane] = a0;                 outp[lane + 64] = b0;
  outp[PLN + lane] = (_Float16)(sA - (float)a0);
  outp[PLN + lane + 64] = (_Float16)(sB - (float)b0);
}

// ---------------------------------------------------------------------------
__global__ __launch_bounds__(256) void softmax_b_kernel(const float* __restrict__ logits,
                                                        const float* __restrict__ bout,
                                                        float* __restrict__ out) {
  int i = blockIdx.x * 256 + threadIdx.x;
  if (i >= SS * VV) return;
  int s = i / VV, vv = i - s * VV;
  float bvv = bout[vv];
  float l0 = logits[(size_t)s * VP + vv] + bvv;
  float l1 = logits[(size_t)(SS + s) * VP + vv] + bvv;
  float m = fmaxf(l0, l1);
  float e0 = __expf(l0 - m), e1 = __expf(l1 - m);
  float inv = 1.0f / (e0 + e1);
  out[(size_t)s * VV + vv] = e0 * inv;
  out[(size_t)(SS + s) * VV + vv] = e1 * inv;
}

// ---------------------------------------------------------------------------
// Workspace: extent 237,502,464 B (proven). pool[2NX..4NX) = osort region,
// time-shared: weights wt at +0, counts at +8MB, rotT at +10MB — all dead
// before attn writes osort and before FFN reuses [0,16MB).
extern "C" void kernel_launch(void* const* d_in, const int* in_sizes, int n_in,
                              void* d_out, int out_size, void* d_ws, size_t ws_size,
                              hipStream_t stream) {
  (void)in_sizes; (void)n_in; (void)out_size; (void)ws_size;
  const float* x     = (const float*)d_in[0];
  const float* ln1_g = (const float*)d_in[1];
  const float* ln1_b = (const float*)d_in[2];
  const float* Wqk   = (const float*)d_in[3];
  const float* Wv    = (const float*)d_in[4];
  const float* Wo    = (const float*)d_in[5];
  const float* rot   = (const float*)d_in[6];
  const float* ln2_g = (const float*)d_in[7];
  const float* ln2_b = (const float*)d_in[8];
  const float* W1    = (const float*)d_in[9];
  const float* b1    = (const float*)d_in[10];
  const float* W2    = (const float*)d_in[11];
  const float* b2    = (const float*)d_in[12];
  const float* lnf_g = (const float*)d_in[13];
  const float* lnf_b = (const float*)d_in[14];
  const float* Wout  = (const float*)d_in[15];
  const float* bout  = (const float*)d_in[16];

  const size_t NX = (size_t)MROWS * DD;            // 8,388,608
  float* x1 = (float*)d_ws;
  float* x2 = x1 + NX;
  float* h  = x2 + NX;
  _Float16* hs = (_Float16*)h;                     // [2][M][1024] fp16
  float* pool = h + NX;
  float* qkb   = pool;
  float* vb    = pool + NX;
  float* osort = pool + 2*NX;
  _Float16* ffh = (_Float16*)pool;                 // [2][M][2048] fp16
  _Float16* hcs = (_Float16*)pool;                 // head phase
  char* wbase = (char*)(pool + 2*NX);
  _Float16* wt = (_Float16*)wbase;                 // weight squat region
  int* counts = (int*)(wbase + (8u<<20));          // 1 MB
  _Float16* rotTs = (_Float16*)(wbase + (10u<<20));// 512 KB
  float* after = pool + 4*NX;
  float* lgb = after;
  float* rno = lgb + (size_t)BH * RS;
  int* orig = (int*)(rno + (size_t)BH * RS);
  int* undo = orig + (size_t)BH * RS;
  int* ids  = undo + (size_t)BH * RS;
  float* logitsP = h;                              // head phase

  const size_t AP_D  = NX;
  const size_t AP_FF = (size_t)MROWS * 2048;
  const size_t BP_D  = (size_t)DD * DD;
  const size_t BP_W1 = (size_t)2048 * DD;
  const size_t BP_W2 = (size_t)DD * 2048;
  const size_t BP_HD = (size_t)VP * 2048;

  init_x_kernel<<<(int)(NX / 256), 256, 0, stream>>>(x, x1, x2);

  for (int l = 0; l < LL; l++) {
    // --- attention ---
    ln_split_kernel<<<MROWS, 256, 0, stream>>>(x2, ln1_g + l*DD, ln1_b + l*DD, hs);

    wconv_kernel<<<dim3(32, 32), 256, 0, stream>>>(Wqk + (size_t)l*DD*DD, wt, DD, DD, DD, DD);
    qgemm_kernel<2,0,false,false,4><<<dim3(8, 64), 256, 0, stream>>>(
        hs, wt, nullptr, qkb, MROWS, DD, DD, AP_D, BP_D);

    wconv_kernel<<<dim3(32, 32), 256, 0, stream>>>(Wv + (size_t)l*DD*DD, wt, DD, DD, DD, DD);
    if (l == 0)
      qgemm_kernel<2,0,false,false,3><<<dim3(8, 64), 256, 0, stream>>>(
          hs, wt, nullptr, vb, MROWS, DD, DD, AP_D, BP_D);
    else
      qgemm_kernel<1,0,false,false,3><<<dim3(8, 64), 256, 0, stream>>>(
          hs, wt, nullptr, vb, MROWS, DD, DD, AP_D, BP_D);

    rott_kernel<<<dim3(8, 8), 256, 0, stream>>>(rot + (size_t)l*HH*DH*RR*64, rotTs);
    bucket_mfma_kernel<<<dim3(32, 16), 256, 0, stream>>>(qkb, rotTs, ids);

    hipMemsetAsync(counts, 0, (size_t)BH * RR * 64 * 128 * sizeof(int), stream);
    sort_count_kernel<<<512, 256, 0, stream>>>(ids, counts);
    sort_prefix_kernel<<<BH*RR, 128, 0, stream>>>(counts);
    sort_scatter_kernel<<<512, 256, 0, stream>>>(ids, counts, orig, undo);

    rnorm_kernel<<<BH*RS/4, 256, 0, stream>>>(qkb, orig, rno);
    if (l == 0)
      attn_mfma_kernel<2><<<BH*NC, 256, 0, stream>>>(qkb, vb, orig, rno, osort, lgb);
    else
      attn_mfma_kernel<1><<<BH*NC, 256, 0, stream>>>(qkb, vb, orig, rno, osort, lgb);
    unsort_split_kernel<<<BH*SS/4, 256, 0, stream>>>(osort, lgb, undo, hs);   // osort dead

    wconv_kernel<<<dim3(32, 32), 256, 0, stream>>>(Wo + (size_t)l*DD*DD, wt, DD, DD, DD, DD);
    if (l == 0)
      qgemm_kernel<2,1,false,false,3><<<dim3(8, 64), 256, 0, stream>>>(
          hs, wt, nullptr, x1, MROWS, DD, DD, AP_D, BP_D);
    else
      qgemm_kernel<1,1,false,false,3><<<dim3(8, 64), 256, 0, stream>>>(
          hs, wt, nullptr, x1, MROWS, DD, DD, AP_D, BP_D);

    // --- FFN, two FF-halves of 2048 ---
    ln_split_kernel<<<MROWS, 256, 0, stream>>>(x1, ln2_g + l*DD, ln2_b + l*DD, hs);
    for (int hf = 0; hf < 2; hf++) {
      const float* W1h = W1 + (size_t)l*DD*FFD + (size_t)hf*2048;
      const float* W2h = W2 + (size_t)l*FFD*DD + (size_t)hf*2048*DD;
      _Float16* wt1 = wt;
      _Float16* wt2 = wt + 2u*2097152u;
      wconv_kernel<<<dim3(64, 32), 256, 0, stream>>>(W1h, wt1, DD, 2048, 2048, FFD);
      wconv_kernel<<<dim3(32, 64), 256, 0, stream>>>(W2h, wt2, 2048, DD, DD, DD);
      if (l == 0) {
        qgemm_kernel<2,2,true,true,3><<<dim3(16, 64), 256, 0, stream>>>(
            hs, wt1, b1 + (size_t)l*FFD + hf*2048, ffh, MROWS, 2048, DD, AP_D, BP_W1);
        if (hf == 0)
          qgemm_kernel<2,1,true,false,3><<<dim3(8, 64), 256, 0, stream>>>(
              ffh, wt2, b2 + (size_t)l*DD, x2, MROWS, DD, 2048, AP_FF, BP_W2);
        else
          qgemm_kernel<2,1,false,false,3><<<dim3(8, 64), 256, 0, stream>>>(
              ffh, wt2, nullptr, x2, MROWS, DD, 2048, AP_FF, BP_W2);
      } else {
        qgemm_kernel<1,2,true,true,3><<<dim3(16, 64), 256, 0, stream>>>(
            hs, wt1, b1 + (size_t)l*FFD + hf*2048, ffh, MROWS, 2048, DD, AP_D, BP_W1);
        if (hf == 0)
          qgemm_kernel<1,1,true,false,3><<<dim3(8, 64), 256, 0, stream>>>(
              ffh, wt2, b2 + (size_t)l*DD, x2, MROWS, DD, 2048, AP_FF, BP_W2);
        else
          qgemm_kernel<1,1,false,false,3><<<dim3(8, 64), 256, 0, stream>>>(
              ffh, wt2, nullptr, x2, MROWS, DD, 2048, AP_FF, BP_W2);
      }
    }
  }

  // --- head ---
  ln_concat_split_kernel<<<MROWS, 256, 0, stream>>>(x1, x2, lnf_g, lnf_b, hcs);
  wconv_kernel<<<dim3(12, 64), 256, 0, stream>>>(Wout, wt, 2*DD, VV, VP, VV);
  qgemm_kernel<1,0,false,false,3><<<dim3(3, 64), 256, 0, stream>>>(
      hcs, wt, nullptr, logitsP, MROWS, VP, 2*DD, AP_FF, BP_HD);
  softmax_b_kernel<<<(SS*VV + 255)/256, 256, 0, stream>>>(logitsP, bout, (float*)d_out);
}

// Round 7
// 1633.658 us; speedup vs baseline: 1.1008x; 1.0202x over previous
//
#include <hip/hip_runtime.h>
#include <hip/hip_fp16.h>
#include <math.h>

#define BB 2
#define SS 4096
#define DD 1024
#define HH 8
#define DH 128
#define RR 2
#define CC 64
#define NBUCK 128
#define LL 2
#define FFD 4096
#define VV 258
#define VP 384            // padded vocab for head GEMM (multiple of 128)
#define RS (RR*SS)        // 8192
#define NC (RS/CC)        // 128
#define BH (BB*HH)        // 16
#define MROWS (BB*SS)     // 8192

// scale 2^8 on both operand splits; descale 2^-16 in epilogue (fp16 denorm guard)
#define SCF 256.0f
#define DSCF (1.0f/65536.0f)

typedef __attribute__((ext_vector_type(8))) _Float16 v8h;
typedef __attribute__((ext_vector_type(4))) _Float16 v4h;
typedef __attribute__((ext_vector_type(4))) float v4f;

// ---------------------------------------------------------------------------
__device__ __forceinline__ void gld16(const void* g, void* l) {
  __builtin_amdgcn_global_load_lds((const __attribute__((address_space(1))) void*)g,
                                   (__attribute__((address_space(3))) void*)l, 16, 0, 0);
}

// ---------------------------------------------------------------------------
__device__ __forceinline__ void block_sum2(float& s, float& s2) {
  #pragma unroll
  for (int o = 1; o < 64; o <<= 1) { s += __shfl_xor(s, o); s2 += __shfl_xor(s2, o); }
  __shared__ float rs[4], rq[4];
  int wave = threadIdx.x >> 6;
  if ((threadIdx.x & 63) == 0) { rs[wave] = s; rq[wave] = s2; }
  __syncthreads();
  s  = rs[0] + rs[1] + rs[2] + rs[3];
  s2 = rq[0] + rq[1] + rq[2] + rq[3];
}

// half-wave (32-lane) sum; xor offsets <32 stay within each 32-lane half
__device__ __forceinline__ float half_wave_sum32(float v) {
  #pragma unroll
  for (int o = 1; o < 32; o <<= 1) v += __shfl_xor(v, o);
  return v;
}

// ---------------------------------------------------------------------------
__global__ __launch_bounds__(256) void init_x_kernel(const float* __restrict__ x,
                                                     float* __restrict__ x1,
                                                     float* __restrict__ x2) {
  size_t i = (size_t)blockIdx.x * 256 + threadIdx.x;
  float v = x[i];
  x1[i] = v; x2[i] = v;
}

// ---------------------------------------------------------------------------
// LayerNorm over D=1024 -> scaled fp16 2-plane split (plane stride MROWS*DD)
__global__ __launch_bounds__(256) void ln_split_kernel(const float* __restrict__ x,
                                                       const float* __restrict__ g,
                                                       const float* __restrict__ bta,
                                                       _Float16* __restrict__ out) {
  int row = blockIdx.x;
  int t = threadIdx.x;
  float4 xv = ((const float4*)(x + (size_t)row * DD))[t];
  float s  = xv.x + xv.y + xv.z + xv.w;
  float s2 = xv.x*xv.x + xv.y*xv.y + xv.z*xv.z + xv.w*xv.w;
  block_sum2(s, s2);
  float mu   = s * (1.0f / DD);
  float var  = fmaxf(s2 * (1.0f / DD) - mu * mu, 0.0f);
  float rstd = rsqrtf(var + 1e-12f);
  float4 gv = ((const float4*)g)[t];
  float4 bv = ((const float4*)bta)[t];
  float4 sv;
  sv.x = ((xv.x - mu) * rstd * gv.x + bv.x) * SCF;
  sv.y = ((xv.y - mu) * rstd * gv.y + bv.y) * SCF;
  sv.z = ((xv.z - mu) * rstd * gv.z + bv.z) * SCF;
  sv.w = ((xv.w - mu) * rstd * gv.w + bv.w) * SCF;
  v4h h0, h1;
  h0[0]=(_Float16)sv.x; h0[1]=(_Float16)sv.y; h0[2]=(_Float16)sv.z; h0[3]=(_Float16)sv.w;
  h1[0]=(_Float16)(sv.x-(float)h0[0]); h1[1]=(_Float16)(sv.y-(float)h0[1]);
  h1[2]=(_Float16)(sv.z-(float)h0[2]); h1[3]=(_Float16)(sv.w-(float)h0[3]);
  const size_t PLN = (size_t)MROWS * DD;
  size_t base = (size_t)row * DD + t * 4;
  *(v4h*)(out + base) = h0;
  *(v4h*)(out + PLN + base) = h1;
}

// LayerNorm over concat([x1,x2]) (2048) -> scaled fp16 single plane
// (head GEMM is PL=1: plane-1 stores were dead, dropped)
__global__ __launch_bounds__(256) void ln_concat_split_kernel(const float* __restrict__ x1,
                                                              const float* __restrict__ x2,
                                                              const float* __restrict__ g,
                                                              const float* __restrict__ bta,
                                                              _Float16* __restrict__ out) {
  int row = blockIdx.x;
  int t = threadIdx.x;
  float4 a = ((const float4*)(x1 + (size_t)row * DD))[t];
  float4 b = ((const float4*)(x2 + (size_t)row * DD))[t];
  float s  = a.x + a.y + a.z + a.w + b.x + b.y + b.z + b.w;
  float s2 = a.x*a.x + a.y*a.y + a.z*a.z + a.w*a.w
           + b.x*b.x + b.y*b.y + b.z*b.z + b.w*b.w;
  block_sum2(s, s2);
  float mu   = s * (1.0f / (2*DD));
  float var  = fmaxf(s2 * (1.0f / (2*DD)) - mu * mu, 0.0f);
  float rstd = rsqrtf(var + 1e-12f);
  float4 g1 = ((const float4*)g)[t];
  float4 b1v = ((const float4*)bta)[t];
  float4 g2 = ((const float4*)g)[256 + t];
  float4 b2v = ((const float4*)bta)[256 + t];
  float4 s1, s2v;
  s1.x = ((a.x-mu)*rstd*g1.x + b1v.x)*SCF;  s1.y = ((a.y-mu)*rstd*g1.y + b1v.y)*SCF;
  s1.z = ((a.z-mu)*rstd*g1.z + b1v.z)*SCF;  s1.w = ((a.w-mu)*rstd*g1.w + b1v.w)*SCF;
  s2v.x = ((b.x-mu)*rstd*g2.x + b2v.x)*SCF; s2v.y = ((b.y-mu)*rstd*g2.y + b2v.y)*SCF;
  s2v.z = ((b.z-mu)*rstd*g2.z + b2v.z)*SCF; s2v.w = ((b.w-mu)*rstd*g2.w + b2v.w)*SCF;
  v4h h0;
  size_t base = (size_t)row * (2*DD) + t * 4;
  h0[0]=(_Float16)s1.x; h0[1]=(_Float16)s1.y; h0[2]=(_Float16)s1.z; h0[3]=(_Float16)s1.w;
  *(v4h*)(out + base) = h0;
  h0[0]=(_Float16)s2v.x; h0[1]=(_Float16)s2v.y; h0[2]=(_Float16)s2v.z; h0[3]=(_Float16)s2v.w;
  *(v4h*)(out + base + DD) = h0;
}

// ---------------------------------------------------------------------------
// weight convert fp32 W[K][·] (row stride ldw) cols [0,N) -> scaled fp16
// 2-plane split Wt[2][Npad][K] (zero pad n>=N)
__global__ __launch_bounds__(256) void wconv_kernel(const float* __restrict__ W,
                                                    _Float16* __restrict__ Wt,
                                                    int K, int N, int Npad, int ldw) {
  __shared__ float tile[32][33];
  int n0 = blockIdx.x * 32, k0 = blockIdx.y * 32;
  int tid = threadIdx.x;
  #pragma unroll
  for (int i = 0; i < 4; i++) {
    int idx = i*256 + tid;
    int kk = idx >> 5, nn = idx & 31;
    float v = 0.0f;
    if (n0 + nn < N) v = W[(size_t)(k0 + kk) * ldw + n0 + nn];
    tile[kk][nn] = v;
  }
  __syncthreads();
  size_t NKs = (size_t)Npad * K;
  #pragma unroll
  for (int i = 0; i < 4; i++) {
    int idx = i*256 + tid;
    int nn = idx >> 5, kk = idx & 31;
    float s = tile[kk][nn] * SCF;
    size_t off = (size_t)(n0 + nn) * K + k0 + kk;
    _Float16 h0 = (_Float16)s;
    _Float16 h1 = (_Float16)(s - (float)h0);
    Wt[off] = h0;
    Wt[NKs + off] = h1;
  }
}

// ---------------------------------------------------------------------------
// fp16x2 MFMA GEMM, counted-vmcnt pipeline (T3+T4) + T2 XOR-swizzled LDS
// + T5 setprio around the MFMA cluster (cross-block wave-role diversity:
// one resident block MFMAs while the other stages -> arbitration matters).
// PL=2: split (fp32-equivalent); PL=1: single. NP=4 full QUAD for discrete
// consumers (bucket argmax via Wqk); NP=3 drops a1*b1 (~2^-22 rel) elsewhere.
// Numerics bit-identical across rounds (same MFMA order).
// CMODE: 0 store f32, 1 accumulate f32, 2 split-store fp16 2-plane.
template<int PL, int CMODE, bool BIAS, bool RELU, int NP>
__global__ __launch_bounds__(256) void qgemm_kernel(const _Float16* __restrict__ A,
                                                    const _Float16* __restrict__ Bt,
                                                    const float* __restrict__ bias,
                                                    void* __restrict__ Cv,
                                                    int M, int N, int K,
                                                    size_t aplane, size_t bplane) {
  __shared__ __align__(16) _Float16 As[2][PL*128*32];
  __shared__ __align__(16) _Float16 Bs[2][PL*128*32];
  int tid = threadIdx.x, lane = tid & 63, wave = tid >> 6;
  int m0 = blockIdx.y * 128, n0 = blockIdx.x * 128;
  int wm = (wave & 1) * 64, wn = (wave >> 1) * 64;
  int lm = lane & 15, quad = lane >> 4;
  const int NCH = (PL == 2) ? 8 : 4;
  const int ACH = (PL == 2) ? 16 : 8;
  v4f acc[4][4];
  #pragma unroll
  for (int i = 0; i < 4; i++)
    #pragma unroll
    for (int j = 0; j < 4; j++) acc[i][j] = (v4f)0.0f;

  // source-column swizzle: (lane>>3)&3 == (row>>1)&3 for row = q*16+(lane>>2)
  auto stage = [&](int k0, int bufi) {
    int sl = (lane >> 3) & 3;
    int col = ((lane & 3) ^ sl) * 8;
    #pragma unroll
    for (int i = 0; i < NCH; i++) {
      int c = wave * NCH + i;
      if (c < ACH) {
        int p = c >> 3, q = c & 7;
        int row = q * 16 + (lane >> 2);
        gld16(A + (size_t)p * aplane + (size_t)(m0 + row) * K + k0 + col,
              (char*)As[bufi] + (size_t)c * 1024);
      } else {
        int cb = c - ACH;
        int p = cb >> 3, q = cb & 7;
        int row = q * 16 + (lane >> 2);
        gld16(Bt + (size_t)p * bplane + (size_t)(n0 + row) * K + k0 + col,
              (char*)Bs[bufi] + (size_t)cb * 1024);
      }
    }
  };

  const int nsteps = K >> 5;   // >= 32 for all launches
  stage(0, 0);
  stage(32, 1);

  int swl = (lm >> 1) & 3;     // read-side mirror of the source swizzle

  for (int t = 0; t < nsteps; ++t) {
    int cur = t & 1;
    // wait for stage(t) only; stage(t+1)'s NCH loads remain in flight
    if (t + 1 < nsteps) {
      if (PL == 2) asm volatile("s_waitcnt vmcnt(8)" ::: "memory");
      else         asm volatile("s_waitcnt vmcnt(4)" ::: "memory");
    } else {
      asm volatile("s_waitcnt vmcnt(0)" ::: "memory");
    }
    __builtin_amdgcn_s_barrier();

    const _Float16* Ab = As[cur];
    const _Float16* Bb = Bs[cur];
    v8h a[4][2], b[4][2];
    #pragma unroll
    for (int ni = 0; ni < 4; ni++) {
      int boff = (wn + ni*16 + lm) * 32 + (quad ^ swl) * 8;
      b[ni][0] = *(const v8h*)&Bb[boff];
      if (PL == 2) b[ni][1] = *(const v8h*)&Bb[4096 + boff];
    }
    #pragma unroll
    for (int mi = 0; mi < 4; mi++) {
      int aoff = (wm + mi*16 + lm) * 32 + (quad ^ swl) * 8;
      a[mi][0] = *(const v8h*)&Ab[aoff];
      if (PL == 2) a[mi][1] = *(const v8h*)&Ab[4096 + aoff];
    }

    // MFMAs start as fragments arrive (compiler fine-grained lgkmcnt)
    __builtin_amdgcn_s_setprio(1);
    #pragma unroll
    for (int mi = 0; mi < 4; mi++) {
      #pragma unroll
      for (int ni = 0; ni < 4; ni++) {
        v4f c0 = acc[mi][ni];
        c0 = __builtin_amdgcn_mfma_f32_16x16x32_f16(a[mi][0], b[ni][0], c0, 0, 0, 0);
        if (PL == 2) {
          c0 = __builtin_amdgcn_mfma_f32_16x16x32_f16(a[mi][0], b[ni][1], c0, 0, 0, 0);
          c0 = __builtin_amdgcn_mfma_f32_16x16x32_f16(a[mi][1], b[ni][0], c0, 0, 0, 0);
          if (NP == 4)
            c0 = __builtin_amdgcn_mfma_f32_16x16x32_f16(a[mi][1], b[ni][1], c0, 0, 0, 0);
        }
        acc[mi][ni] = c0;
      }
    }
    __builtin_amdgcn_s_setprio(0);

    asm volatile("s_waitcnt lgkmcnt(0)" ::: "memory");  // all my reads executed
    __builtin_amdgcn_s_barrier();                       // all waves done with buf[cur]
    if (t + 2 < nsteps) stage((t + 2) << 5, cur);       // refill; flies under next step
  }

  float* Cf = (float*)Cv;
  _Float16* Ch = (_Float16*)Cv;
  const size_t cplane = (size_t)M * N;
  #pragma unroll
  for (int mi = 0; mi < 4; mi++) {
    int rbase = m0 + wm + mi*16 + quad*4;
    #pragma unroll
    for (int ni = 0; ni < 4; ni++) {
      int col = n0 + wn + ni*16 + lm;
      float bv = BIAS ? bias[col] : 0.0f;
      #pragma unroll
      for (int r = 0; r < 4; r++) {
        float val = acc[mi][ni][r] * DSCF + bv;
        if (RELU) val = fmaxf(val, 0.0f);
        size_t off = (size_t)(rbase + r) * N + col;
        if (CMODE == 0) Cf[off] = val;
        else if (CMODE == 1) Cf[off] += val;
        else {
          float s = val * SCF;
          _Float16 h0 = (_Float16)s;
          _Float16 h1 = (_Float16)(s - (float)h0);
          Ch[off] = h0;
          Ch[cplane + off] = h1;
        }
      }
    }
  }
}

// ---------------------------------------------------------------------------
// rot[h][d][r][n] -> rotT[h][2 planes][rcol=r*64+n][d] scaled fp16 split
__global__ __launch_bounds__(256) void rott_kernel(const float* __restrict__ rot,
                                                   _Float16* __restrict__ rotT) {
  int h = blockIdx.x, grp = blockIdx.y;    // dim3(8,8)
  const float* rh = rot + (size_t)h * (DH * RR * 64);
  for (int idx = threadIdx.x; idx < 16*128; idx += 256) {
    int rc = grp*16 + (idx >> 7), d = idx & 127;
    int r = rc >> 6, nn = rc & 63;
    float f = rh[(size_t)d * 128 + r * 64 + nn] * SCF;
    _Float16 h0 = (_Float16)f;
    rotT[(size_t)h*32768 + (size_t)rc*128 + d] = h0;
    rotT[(size_t)h*32768 + 16384 + (size_t)rc*128 + d] = (_Float16)(f - (float)h0);
  }
}

// ---------------------------------------------------------------------------
// bucket via MFMA: rotated = qk_head @ rotT^T, fused argmax epilogue.
// A: qkb fp32 (in-register QUAD split, R4-verified XOR-swizzle staging).
// B staging/reads use the same T2 source-swizzle as qgemm (bank-conflict-free).
// Each wave's 64 cols = one full hash round -> per-wave argmax, no combine.
// Kept at full 4-product QUAD: feeds discrete argmax (bucket assignment).
__global__ __launch_bounds__(256) void bucket_mfma_kernel(const float* __restrict__ qkb,
                                                          const _Float16* __restrict__ rotT,
                                                          int* __restrict__ ids) {
  __shared__ __align__(16) float Af[128*32];          // 16 KB XOR-swizzled
  __shared__ __align__(16) _Float16 Bs[2*128*32];     // 16 KB
  int mtile = blockIdx.x, bh = blockIdx.y;
  int b = bh >> 3, h = bh & 7;
  int tid = threadIdx.x, lane = tid & 63, wave = tid >> 6;
  int wm = (wave & 1) * 64;
  int r = wave >> 1;                                   // round handled by this wave
  int wn = r * 64;
  int lm = lane & 15, quad = lane >> 4;
  const float* Aq = qkb + ((size_t)b * SS + (size_t)mtile * 128) * DD + h * DH;
  const _Float16* Bq = rotT + (size_t)h * 32768;
  int swl = (lm >> 1) & 3;
  v4f acc[4][4];
  #pragma unroll
  for (int i = 0; i < 4; i++)
    #pragma unroll
    for (int j = 0; j < 4; j++) acc[i][j] = (v4f)0.0f;

  for (int k0 = 0; k0 < 128; k0 += 32) {
    #pragma unroll
    for (int i = 0; i < 8; i++) {
      int c = wave * 8 + i;
      if (c < 16) {
        int slot = c * 64 + lane;
        int row = slot >> 3;
        int c4 = (slot & 7) ^ (row & 7);
        gld16(Aq + (size_t)row * DD + k0 + c4 * 4, (char*)Af + (size_t)c * 1024);
      } else {
        int cb = c - 16;
        int p = cb >> 3, q = cb & 7;
        int row = q * 16 + (lane >> 2);
        int col = ((lane & 3) ^ ((lane >> 3) & 3)) * 8;
        gld16(Bq + (size_t)p * 16384 + (size_t)row * 128 + k0 + col,
              (char*)Bs + (size_t)p * 8192 + (size_t)q * 1024);
      }
    }
    __syncthreads();
    v8h b0[4], b1[4];
    #pragma unroll
    for (int ni = 0; ni < 4; ni++) {
      int boff = (wn + ni*16 + lm) * 32 + (quad ^ swl) * 8;
      b0[ni] = *(const v8h*)&Bs[boff];
      b1[ni] = *(const v8h*)&Bs[4096 + boff];
    }
    __builtin_amdgcn_s_setprio(1);
    #pragma unroll
    for (int mi = 0; mi < 4; mi++) {
      int arow = wm + mi*16 + lm;
      int sw = arow & 7;
      float4 fA = *(const float4*)(Af + arow*32 + (((2*quad)     ^ sw) << 2));
      float4 fB = *(const float4*)(Af + arow*32 + (((2*quad + 1) ^ sw) << 2));
      v8h a0, a1;
      float fs[8] = {fA.x*SCF, fA.y*SCF, fA.z*SCF, fA.w*SCF,
                     fB.x*SCF, fB.y*SCF, fB.z*SCF, fB.w*SCF};
      #pragma unroll
      for (int j = 0; j < 8; j++) {
        _Float16 p0 = (_Float16)fs[j];
        a0[j] = p0;
        a1[j] = (_Float16)(fs[j] - (float)p0);
      }
      #pragma unroll
      for (int ni = 0; ni < 4; ni++) {
        v4f c0 = acc[mi][ni];
        c0 = __builtin_amdgcn_mfma_f32_16x16x32_f16(a0, b0[ni], c0, 0, 0, 0);
        c0 = __builtin_amdgcn_mfma_f32_16x16x32_f16(a0, b1[ni], c0, 0, 0, 0);
        c0 = __builtin_amdgcn_mfma_f32_16x16x32_f16(a1, b0[ni], c0, 0, 0, 0);
        c0 = __builtin_amdgcn_mfma_f32_16x16x32_f16(a1, b1[ni], c0, 0, 0, 0);
        acc[mi][ni] = c0;
      }
    }
    __builtin_amdgcn_s_setprio(0);
    __syncthreads();
  }

  // argmax epilogue (scaled values; comparisons scale-invariant)
  #pragma unroll
  for (int mi = 0; mi < 4; mi++) {
    #pragma unroll
    for (int rr = 0; rr < 4; rr++) {
      float mx = acc[mi][0][rr]; int xi = lm;
      float mn = acc[mi][0][rr]; int ni_ = lm;
      #pragma unroll
      for (int ni = 1; ni < 4; ni++) {
        float vv = acc[mi][ni][rr];
        int col = ni*16 + lm;
        if (vv > mx) { mx = vv; xi = col; }
        if (vv < mn) { mn = vv; ni_ = col; }
      }
      #pragma unroll
      for (int o = 1; o < 16; o <<= 1) {
        float ox = __shfl_xor(mx, o); int oxi = __shfl_xor(xi, o);
        if (ox > mx || (ox == mx && oxi < xi)) { mx = ox; xi = oxi; }
        float on = __shfl_xor(mn, o); int oni = __shfl_xor(ni_, o);
        if (on < mn || (on == mn && oni < ni_)) { mn = on; ni_ = oni; }
      }
      if (lm == 0) {
        int bi = (mx >= -mn) ? xi : 64 + ni_;
        int s = mtile*128 + wm + mi*16 + quad*4 + rr;
        ids[((size_t)bh * RR + r) * SS + s] = bi + r * NBUCK;
      }
    }
  }
}

// ---------------------------------------------------------------------------
// Parallel stable counting sort (R5-verified, bit-exact vs argsort)
__global__ __launch_bounds__(256) void sort_count_kernel(const int* __restrict__ ids,
                                                         int* __restrict__ counts) {
  int w = blockIdx.x * 4 + (threadIdx.x >> 6);
  int lane = threadIdx.x & 63;
  int bhr = w >> 6, seg = w & 63;
  int id = ids[(size_t)bhr * SS + seg * 64 + lane];
  int bin = id & 127;
  unsigned long long eq = ~0ull;
  #pragma unroll
  for (int bit = 0; bit < 7; bit++) {
    unsigned long long bal = __ballot((bin >> bit) & 1);
    eq &= ((bin >> bit) & 1) ? bal : ~bal;
  }
  int rank = __popcll(eq & ((1ull << lane) - 1ull));
  if (rank == 0)
    counts[((size_t)bhr * 64 + seg) * 128 + bin] = __popcll(eq);
}

__global__ __launch_bounds__(128) void sort_prefix_kernel(int* __restrict__ counts) {
  int bhr = blockIdx.x;
  int bin = threadIdx.x;
  int r = bhr & 1;
  int* cp = counts + (size_t)bhr * 64 * 128;
  int total = 0;
  for (int seg = 0; seg < 64; seg++) total += cp[seg * 128 + bin];
  __shared__ int tot[128];
  tot[bin] = total;
  __syncthreads();
  for (int off = 1; off < 128; off <<= 1) {
    int t = (bin >= off) ? tot[bin - off] : 0;
    __syncthreads();
    tot[bin] += t;
    __syncthreads();
  }
  int run = tot[bin] - total + r * SS;
  for (int seg = 0; seg < 64; seg++) {
    int c = cp[seg * 128 + bin];
    cp[seg * 128 + bin] = run;
    run += c;
  }
}

__global__ __launch_bounds__(256) void sort_scatter_kernel(const int* __restrict__ ids,
                                                           const int* __restrict__ offs,
                                                           int* __restrict__ orig,
                                                           int* __restrict__ undo) {
  int w = blockIdx.x * 4 + (threadIdx.x >> 6);
  int lane = threadIdx.x & 63;
  int bhr = w >> 6, seg = w & 63;
  int s = seg * 64 + lane;
  int id = ids[(size_t)bhr * SS + s];
  int bin = id & 127;
  unsigned long long eq = ~0ull;
  #pragma unroll
  for (int bit = 0; bit < 7; bit++) {
    unsigned long long bal = __ballot((bin >> bit) & 1);
    eq &= ((bin >> bit) & 1) ? bal : ~bal;
  }
  int rank = __popcll(eq & ((1ull << lane) - 1ull));
  int o = offs[((size_t)bhr * 64 + seg) * 128 + bin] + rank;
  int bh = bhr >> 1, r = bhr & 1;
  orig[(size_t)bh * RS + o] = s;
  undo[(size_t)bh * RS + r * SS + s] = o;
}

// ---------------------------------------------------------------------------
// MFMA chunked attention, T14 async-stage version (raw s_barrier, no vmcnt
// drain at barriers). Q/K/V gathered fp32 -> scaled fp16 PL-plane split.
// PL=2 (layer 0): fp32-equivalent QUAD; PL=1 (layer 1): single product.
// rnorm FUSED: each K row's 128 dims live across the 32 staging lanes of a
// half-wave; rn = rsqrt(mean(k^2)+1e-6)/sqrt(128) via 5-shfl reduce at
// K-write time (kills the separate rnorm pass + rno round-trip; post-bucket
// continuous path, no discrete hazard).
// V layout XOR-swizzled: KV[d*36 + (key ^ ((d>>2 &7)<<2))]; reads mirror it.
template<int PL>
__global__ __launch_bounds__(256) void attn_mfma_kernel(const float* __restrict__ qk,
                                                        const float* __restrict__ v,
                                                        const int* __restrict__ orig,
                                                        float* __restrict__ osort,
                                                        float* __restrict__ lg) {
  constexpr int QPs = 64*136, Kps = 32*136, Vps = 128*36;
  constexpr size_t QPB = (size_t)PL * QPs * 2;       // Q/P region bytes
  constexpr size_t KVB = (size_t)PL * Vps * 2;       // K/V region bytes (V is larger)
  __shared__ __align__(16) char smem[QPB + KVB + 1024];
  _Float16* QP = (_Float16*)smem;                     // [PL][64][136]
  _Float16* KV = (_Float16*)(smem + QPB);             // K: [PL][32][136] / V: [PL][128][36]
  int* kp_lds = (int*)(smem + QPB + KVB);
  int* qp_lds = kp_lds + 128;

  int blk = blockIdx.x;
  int n = blk & (NC - 1), bh = blk >> 7;
  int b = bh >> 3, h = bh & 7;
  int pn = (n + NC - 1) & (NC - 1);
  int tid = threadIdx.x, lane = tid & 63, wave = tid >> 6;
  int lm = lane & 15, quad = lane >> 4;
  const int* origp = orig + (size_t)bh * RS;
  const size_t base = (size_t)b * SS * DD + (size_t)h * DH;

  // per-thread staging geometry: fixed d4 column, 8-strided rows
  int d4 = tid & 31;
  int row0 = tid >> 5;                                 // 0..7

  // ---- prologue: issue Q loads + K(0) loads; stage kp/qp ids ----
  float4 qreg[8];
  #pragma unroll
  for (int i = 0; i < 8; i++)
    qreg[i] = *(const float4*)(qk + base + (size_t)origp[n*64 + row0 + i*8]*DD + d4*4);

  float4 kreg[2][4];
  #pragma unroll
  for (int i = 0; i < 4; i++) {
    int key = row0 + i*8;
    kreg[0][i] = *(const float4*)(qk + base + (size_t)origp[pn*64 + key]*DD + d4*4);
  }

  if (tid < 128) kp_lds[tid] = origp[(tid < 64) ? (pn*64 + tid) : (n*64 + tid - 64)];
  else if (tid < 192) qp_lds[tid - 128] = origp[n*64 + tid - 128];

  // write Q (waits only the Q loads; K0 stays in flight)
  #pragma unroll
  for (int i = 0; i < 8; i++) {
    int q = row0 + i*8;
    float4 f = qreg[i];
    f.x *= SCF; f.y *= SCF; f.z *= SCF; f.w *= SCF;
    v4h h0; h0[0]=(_Float16)f.x; h0[1]=(_Float16)f.y; h0[2]=(_Float16)f.z; h0[3]=(_Float16)f.w;
    *(v4h*)(QP + q*136 + d4*4) = h0;
    if (PL == 2) {
      v4h h1; h1[0]=(_Float16)(f.x-(float)h0[0]); h1[1]=(_Float16)(f.y-(float)h0[1]);
      h1[2]=(_Float16)(f.z-(float)h0[2]); h1[3]=(_Float16)(f.w-(float)h0[3]);
      *(v4h*)(QP + QPs + q*136 + d4*4) = h1;
    }
  }
  asm volatile("s_waitcnt lgkmcnt(0)" ::: "memory");   // publish Q + kp/qp ids

  v4f sc[8];
  #pragma unroll
  for (int j = 0; j < 8; j++) sc[j] = (v4f)0.0f;

  // --- scores: 4 key-groups of 32, software-pipelined ---
  #pragma unroll
  for (int g = 0; g < 4; g++) {
    __builtin_amdgcn_s_barrier();                      // prev readers done / pub
    int cur = g & 1;
    // write K(g) from regs; rn computed in-wave (fused rnorm)
    #pragma unroll
    for (int i = 0; i < 4; i++) {
      int key = row0 + i*8;
      float4 f = kreg[cur][i];
      float ss = half_wave_sum32(f.x*f.x + f.y*f.y + f.z*f.z + f.w*f.w);
      float rn = rsqrtf(ss * (1.0f / DH) + 1e-6f) * 0.08838834764831845f * SCF;
      f.x *= rn; f.y *= rn; f.z *= rn; f.w *= rn;
      v4h h0; h0[0]=(_Float16)f.x; h0[1]=(_Float16)f.y; h0[2]=(_Float16)f.z; h0[3]=(_Float16)f.w;
      *(v4h*)(KV + key*136 + d4*4) = h0;
      if (PL == 2) {
        v4h h1; h1[0]=(_Float16)(f.x-(float)h0[0]); h1[1]=(_Float16)(f.y-(float)h0[1]);
        h1[2]=(_Float16)(f.z-(float)h0[2]); h1[3]=(_Float16)(f.w-(float)h0[3]);
        *(v4h*)(KV + Kps + key*136 + d4*4) = h1;
      }
    }
    // issue K(g+1): row ids from LDS (fast), then gathered float4
    if (g < 3) {
      #pragma unroll
      for (int i = 0; i < 4; i++) {
        int key = row0 + i*8;
        int rowid = kp_lds[(g+1)*32 + key];
        kreg[cur^1][i] = *(const float4*)(qk + base + (size_t)rowid*DD + d4*4);
      }
    }
    asm volatile("s_waitcnt lgkmcnt(0)" ::: "memory"); // K(g) writes done
    __builtin_amdgcn_s_barrier();
    __builtin_amdgcn_s_setprio(1);
    #pragma unroll
    for (int ni = 0; ni < 2; ni++) {
      v4f c0 = sc[g*2 + ni];
      #pragma unroll
      for (int ks = 0; ks < 4; ks++) {
        v8h a0 = *(const v8h*)(QP + (wave*16 + lm)*136 + ks*32 + quad*8);
        v8h b0 = *(const v8h*)(KV + (ni*16 + lm)*136 + ks*32 + quad*8);
        c0 = __builtin_amdgcn_mfma_f32_16x16x32_f16(a0, b0, c0, 0, 0, 0);
        if (PL == 2) {
          v8h a1 = *(const v8h*)(QP + QPs + (wave*16 + lm)*136 + ks*32 + quad*8);
          v8h b1 = *(const v8h*)(KV + Kps + (ni*16 + lm)*136 + ks*32 + quad*8);
          c0 = __builtin_amdgcn_mfma_f32_16x16x32_f16(a0, b1, c0, 0, 0, 0);
          c0 = __builtin_amdgcn_mfma_f32_16x16x32_f16(a1, b0, c0, 0, 0, 0);
          c0 = __builtin_amdgcn_mfma_f32_16x16x32_f16(a1, b1, c0, 0, 0, 0);
        }
      }
      sc[g*2 + ni] = c0;
    }
    __builtin_amdgcn_s_setprio(0);
  }

  // issue V(0) loads NOW -- they fly under the softmax
  float4 vreg[2][4];
  #pragma unroll
  for (int i = 0; i < 4; i++) {
    int key = row0 + i*8;
    int rowid = kp_lds[key];                           // group 0 rows
    vreg[0][i] = *(const float4*)(v + base + (size_t)rowid*DD + d4*4);
  }

  __builtin_amdgcn_s_barrier();                        // score reads of QP done

  int kp_l[8];
  #pragma unroll
  for (int j = 0; j < 8; j++) kp_l[j] = kp_lds[j*16 + lm];

  // --- masked softmax per row; write scaled-split probs into QP ---
  #pragma unroll
  for (int rr = 0; rr < 4; rr++) {
    int row = wave*16 + quad*4 + rr;
    int qp = qp_lds[row];
    float sv[8];
    #pragma unroll
    for (int j = 0; j < 8; j++) {
      float s = sc[j][rr] * DSCF;
      int kp = kp_l[j];
      sv[j] = (kp > qp) ? -1000000000.0f : ((kp == qp) ? -100000.0f : s);
    }
    float m = sv[0];
    #pragma unroll
    for (int j = 1; j < 8; j++) m = fmaxf(m, sv[j]);
    #pragma unroll
    for (int o = 1; o < 16; o <<= 1) m = fmaxf(m, __shfl_xor(m, o));
    float es[8], S = 0.0f;
    #pragma unroll
    for (int j = 0; j < 8; j++) { es[j] = __expf(sv[j] - m); S += es[j]; }
    #pragma unroll
    for (int o = 1; o < 16; o <<= 1) S += __shfl_xor(S, o);
    float inv = 1.0f / S;
    if (lm == 0) lg[(size_t)bh * RS + n*64 + row] = m + __logf(S);
    #pragma unroll
    for (int j = 0; j < 8; j++) {
      float p = es[j] * inv * SCF;
      _Float16 p0 = (_Float16)p;
      QP[row*136 + j*16 + lm] = p0;
      if (PL == 2) QP[QPs + row*136 + j*16 + lm] = (_Float16)(p - (float)p0);
    }
  }

  // --- PV: 4 key-groups, V transposed into [d][key^swz] (stride 36) ---
  v4f oacc[8];
  #pragma unroll
  for (int j = 0; j < 8; j++) oacc[j] = (v4f)0.0f;
  #pragma unroll
  for (int g = 0; g < 4; g++) {
    __builtin_amdgcn_s_barrier();                      // prev V readers done
    int cur = g & 1;
    int xbs = (d4 & 7) << 2;
    // write V(g) from regs (swizzled)
    #pragma unroll
    for (int i = 0; i < 4; i++) {
      int keyS = (row0 + i*8) ^ xbs;
      float4 f = vreg[cur][i];
      float fs[4] = {f.x*SCF, f.y*SCF, f.z*SCF, f.w*SCF};
      #pragma unroll
      for (int j = 0; j < 4; j++) {
        int d = d4*4 + j;
        _Float16 p0 = (_Float16)fs[j];
        KV[d*36 + keyS] = p0;
        if (PL == 2) KV[Vps + d*36 + keyS] = (_Float16)(fs[j] - (float)p0);
      }
    }
    // issue V(g+1)
    if (g < 3) {
      #pragma unroll
      for (int i = 0; i < 4; i++) {
        int key = row0 + i*8;
        int rowid = kp_lds[(g+1)*32 + key];
        vreg[cur^1][i] = *(const float4*)(v + base + (size_t)rowid*DD + d4*4);
      }
    }
    asm volatile("s_waitcnt lgkmcnt(0)" ::: "memory"); // V(g) + P writes done
    __builtin_amdgcn_s_barrier();
    __builtin_amdgcn_s_setprio(1);
    v8h a0 = *(const v8h*)(QP + (wave*16 + lm)*136 + g*32 + quad*8);
    v8h a1;
    if (PL == 2) a1 = *(const v8h*)(QP + QPs + (wave*16 + lm)*136 + g*32 + quad*8);
    #pragma unroll
    for (int dn = 0; dn < 8; dn++) {
      int d = dn*16 + lm;
      int klo = (quad*8) ^ (((d >> 2) & 7) << 2);      // 4-aligned block
      v4h lo0 = *(const v4h*)(KV + d*36 + klo);
      v4h hi0 = *(const v4h*)(KV + d*36 + (klo ^ 4));
      v8h b0 = __builtin_shufflevector(lo0, hi0, 0,1,2,3,4,5,6,7);
      v4f c0 = oacc[dn];
      c0 = __builtin_amdgcn_mfma_f32_16x16x32_f16(a0, b0, c0, 0, 0, 0);
      if (PL == 2) {
        v4h lo1 = *(const v4h*)(KV + Vps + d*36 + klo);
        v4h hi1 = *(const v4h*)(KV + Vps + d*36 + (klo ^ 4));
        v8h b1 = __builtin_shufflevector(lo1, hi1, 0,1,2,3,4,5,6,7);
        c0 = __builtin_amdgcn_mfma_f32_16x16x32_f16(a0, b1, c0, 0, 0, 0);
        c0 = __builtin_amdgcn_mfma_f32_16x16x32_f16(a1, b0, c0, 0, 0, 0);
        c0 = __builtin_amdgcn_mfma_f32_16x16x32_f16(a1, b1, c0, 0, 0, 0);
      }
      oacc[dn] = c0;
    }
    __builtin_amdgcn_s_setprio(0);
  }

  // epilogue: O -> osort fp32
  #pragma unroll
  for (int dn = 0; dn < 8; dn++) {
    #pragma unroll
    for (int rr = 0; rr < 4; rr++) {
      int row = wave*16 + quad*4 + rr;
      osort[((size_t)bh * RS + n*64 + row) * DH + dn*16 + lm] = oacc[dn][rr] * DSCF;
    }
  }
}

// ---------------------------------------------------------------------------
// unsort + round-combine -> scaled fp16 2-plane split in h region
__global__ __launch_bounds__(256) void unsort_split_kernel(const float* __restrict__ osort,
                                                           const float* __restrict__ lg,
                                                           const int* __restrict__ undo,
                                                           _Float16* __restrict__ attn) {
  int gid = blockIdx.x * 4 + (threadIdx.x >> 6);
  int lane = threadIdx.x & 63;
  int bh = gid >> 12;
  int s = gid & (SS - 1);
  int b = bh >> 3, h = bh & 7;
  int k0 = undo[(size_t)bh * RS + s];
  int k1 = undo[(size_t)bh * RS + SS + s];
  float l0 = lg[(size_t)bh * RS + k0], l1 = lg[(size_t)bh * RS + k1];
  float m = fmaxf(l0, l1);
  float e0 = __expf(l0 - m), e1 = __expf(l1 - m);
  float inv = 1.0f / (e0 + e1);
  float w0 = e0 * inv, w1 = e1 * inv;
  const float* r0 = osort + ((size_t)bh * RS + k0) * DH;
  const float* r1 = osort + ((size_t)bh * RS + k1) * DH;
  const size_t PLN = (size_t)MROWS * DD;
  _Float16* outp = attn + ((size_t)(b * SS + s)) * DD + h * DH;
  float sA = (w0 * r0[lane]      + w1 * r1[lane])      * SCF;
  float sB = (w0 * r0[lane + 64] + w1 * r1[lane + 64]) * SCF;
  _Float16 a0 = (_Float16)sA, b0 = (_Float16)sB;
  outp[lane] = a0;                 outp[lane + 64] = b0;
  outp[PLN + lane] = (_Float16)(sA - (float)a0);
  outp[PLN + lane + 64] = (_Float16)(sB - (float)b0);
}

// ---------------------------------------------------------------------------
__global__ __launch_bounds__(256) void softmax_b_kernel(const float* __restrict__ logits,
                                                        const float* __restrict__ bout,
                                                        float* __restrict__ out) {
  int i = blockIdx.x * 256 + threadIdx.x;
  if (i >= SS * VV) return;
  int s = i / VV, vv = i - s * VV;
  float bvv = bout[vv];
  float l0 = logits[(size_t)s * VP + vv] + bvv;
  float l1 = logits[(size_t)(SS + s) * VP + vv] + bvv;
  float m = fmaxf(l0, l1);
  float e0 = __expf(l0 - m), e1 = __expf(l1 - m);
  float inv = 1.0f / (e0 + e1);
  out[(size_t)s * VV + vv] = e0 * inv;
  out[(size_t)(SS + s) * VV + vv] = e1 * inv;
}

// ---------------------------------------------------------------------------
// Workspace: extent 237,502,464 B (proven). pool[2NX..4NX) = osort region,
// time-shared: weights wt at +0, counts at +8MB, rotT at +10MB — all dead
// before attn writes osort and before FFN reuses [0,16MB).
extern "C" void kernel_launch(void* const* d_in, const int* in_sizes, int n_in,
                              void* d_out, int out_size, void* d_ws, size_t ws_size,
                              hipStream_t stream) {
  (void)in_sizes; (void)n_in; (void)out_size; (void)ws_size;
  const float* x     = (const float*)d_in[0];
  const float* ln1_g = (const float*)d_in[1];
  const float* ln1_b = (const float*)d_in[2];
  const float* Wqk   = (const float*)d_in[3];
  const float* Wv    = (const float*)d_in[4];
  const float* Wo    = (const float*)d_in[5];
  const float* rot   = (const float*)d_in[6];
  const float* ln2_g = (const float*)d_in[7];
  const float* ln2_b = (const float*)d_in[8];
  const float* W1    = (const float*)d_in[9];
  const float* b1    = (const float*)d_in[10];
  const float* W2    = (const float*)d_in[11];
  const float* b2    = (const float*)d_in[12];
  const float* lnf_g = (const float*)d_in[13];
  const float* lnf_b = (const float*)d_in[14];
  const float* Wout  = (const float*)d_in[15];
  const float* bout  = (const float*)d_in[16];

  const size_t NX = (size_t)MROWS * DD;            // 8,388,608
  float* x1 = (float*)d_ws;
  float* x2 = x1 + NX;
  float* h  = x2 + NX;
  _Float16* hs = (_Float16*)h;                     // [2][M][1024] fp16
  float* pool = h + NX;
  float* qkb   = pool;
  float* vb    = pool + NX;
  float* osort = pool + 2*NX;
  _Float16* ffh = (_Float16*)pool;                 // [2][M][2048] fp16
  _Float16* hcs = (_Float16*)pool;                 // head phase
  char* wbase = (char*)(pool + 2*NX);
  _Float16* wt = (_Float16*)wbase;                 // weight squat region
  int* counts = (int*)(wbase + (8u<<20));          // 1 MB
  _Float16* rotTs = (_Float16*)(wbase + (10u<<20));// 512 KB
  float* after = pool + 4*NX;
  float* lgb = after;
  float* rno = lgb + (size_t)BH * RS;              // slot kept (rnorm fused away)
  int* orig = (int*)(rno + (size_t)BH * RS);
  int* undo = orig + (size_t)BH * RS;
  int* ids  = undo + (size_t)BH * RS;
  float* logitsP = h;                              // head phase

  const size_t AP_D  = NX;
  const size_t AP_FF = (size_t)MROWS * 2048;
  const size_t BP_D  = (size_t)DD * DD;
  const size_t BP_W1 = (size_t)2048 * DD;
  const size_t BP_W2 = (size_t)DD * 2048;
  const size_t BP_HD = (size_t)VP * 2048;

  init_x_kernel<<<(int)(NX / 256), 256, 0, stream>>>(x, x1, x2);

  for (int l = 0; l < LL; l++) {
    // --- attention ---
    ln_split_kernel<<<MROWS, 256, 0, stream>>>(x2, ln1_g + l*DD, ln1_b + l*DD, hs);

    wconv_kernel<<<dim3(32, 32), 256, 0, stream>>>(Wqk + (size_t)l*DD*DD, wt, DD, DD, DD, DD);
    qgemm_kernel<2,0,false,false,4><<<dim3(8, 64), 256, 0, stream>>>(
        hs, wt, nullptr, qkb, MROWS, DD, DD, AP_D, BP_D);

    wconv_kernel<<<dim3(32, 32), 256, 0, stream>>>(Wv + (size_t)l*DD*DD, wt, DD, DD, DD, DD);
    if (l == 0)
      qgemm_kernel<2,0,false,false,3><<<dim3(8, 64), 256, 0, stream>>>(
          hs, wt, nullptr, vb, MROWS, DD, DD, AP_D, BP_D);
    else
      qgemm_kernel<1,0,false,false,3><<<dim3(8, 64), 256, 0, stream>>>(
          hs, wt, nullptr, vb, MROWS, DD, DD, AP_D, BP_D);

    rott_kernel<<<dim3(8, 8), 256, 0, stream>>>(rot + (size_t)l*HH*DH*RR*64, rotTs);
    bucket_mfma_kernel<<<dim3(32, 16), 256, 0, stream>>>(qkb, rotTs, ids);

    hipMemsetAsync(counts, 0, (size_t)BH * RR * 64 * 128 * sizeof(int), stream);
    sort_count_kernel<<<512, 256, 0, stream>>>(ids, counts);
    sort_prefix_kernel<<<BH*RR, 128, 0, stream>>>(counts);
    sort_scatter_kernel<<<512, 256, 0, stream>>>(ids, counts, orig, undo);

    if (l == 0)
      attn_mfma_kernel<2><<<BH*NC, 256, 0, stream>>>(qkb, vb, orig, osort, lgb);
    else
      attn_mfma_kernel<1><<<BH*NC, 256, 0, stream>>>(qkb, vb, orig, osort, lgb);
    unsort_split_kernel<<<BH*SS/4, 256, 0, stream>>>(osort, lgb, undo, hs);   // osort dead

    wconv_kernel<<<dim3(32, 32), 256, 0, stream>>>(Wo + (size_t)l*DD*DD, wt, DD, DD, DD, DD);
    if (l == 0)
      qgemm_kernel<2,1,false,false,3><<<dim3(8, 64), 256, 0, stream>>>(
          hs, wt, nullptr, x1, MROWS, DD, DD, AP_D, BP_D);
    else
      qgemm_kernel<1,1,false,false,3><<<dim3(8, 64), 256, 0, stream>>>(
          hs, wt, nullptr, x1, MROWS, DD, DD, AP_D, BP_D);

    // --- FFN, two FF-halves of 2048 ---
    ln_split_kernel<<<MROWS, 256, 0, stream>>>(x1, ln2_g + l*DD, ln2_b + l*DD, hs);
    for (int hf = 0; hf < 2; hf++) {
      const float* W1h = W1 + (size_t)l*DD*FFD + (size_t)hf*2048;
      const float* W2h = W2 + (size_t)l*FFD*DD + (size_t)hf*2048*DD;
      _Float16* wt1 = wt;
      _Float16* wt2 = wt + 2u*2097152u;
      wconv_kernel<<<dim3(64, 32), 256, 0, stream>>>(W1h, wt1, DD, 2048, 2048, FFD);
      wconv_kernel<<<dim3(32, 64), 256, 0, stream>>>(W2h, wt2, 2048, DD, DD, DD);
      if (l == 0) {
        qgemm_kernel<2,2,true,true,3><<<dim3(16, 64), 256, 0, stream>>>(
            hs, wt1, b1 + (size_t)l*FFD + hf*2048, ffh, MROWS, 2048, DD, AP_D, BP_W1);
        if (hf == 0)
          qgemm_kernel<2,1,true,false,3><<<dim3(8, 64), 256, 0, stream>>>(
              ffh, wt2, b2 + (size_t)l*DD, x2, MROWS, DD, 2048, AP_FF, BP_W2);
        else
          qgemm_kernel<2,1,false,false,3><<<dim3(8, 64), 256, 0, stream>>>(
              ffh, wt2, nullptr, x2, MROWS, DD, 2048, AP_FF, BP_W2);
      } else {
        qgemm_kernel<1,2,true,true,3><<<dim3(16, 64), 256, 0, stream>>>(
            hs, wt1, b1 + (size_t)l*FFD + hf*2048, ffh, MROWS, 2048, DD, AP_D, BP_W1);
        if (hf == 0)
          qgemm_kernel<1,1,true,false,3><<<dim3(8, 64), 256, 0, stream>>>(
              ffh, wt2, b2 + (size_t)l*DD, x2, MROWS, DD, 2048, AP_FF, BP_W2);
        else
          qgemm_kernel<1,1,false,false,3><<<dim3(8, 64), 256, 0, stream>>>(
              ffh, wt2, nullptr, x2, MROWS, DD, 2048, AP_FF, BP_W2);
      }
    }
  }

  // --- head ---
  ln_concat_split_kernel<<<MROWS, 256, 0, stream>>>(x1, x2, lnf_g, lnf_b, hcs);
  wconv_kernel<<<dim3(12, 64), 256, 0, stream>>>(Wout, wt, 2*DD, VV, VP, VV);
  qgemm_kernel<1,0,false,false,3><<<dim3(3, 64), 256, 0, stream>>>(
      hcs, wt, nullptr, logitsP, MROWS, VP, 2*DD, AP_FF, BP_HD);
  softmax_b_kernel<<<(SS*VV + 255)/256, 256, 0, stream>>>(logitsP, bout, (float*)d_out);
}